// Round 11
// baseline (922.707 us; speedup 1.0000x reference)
//
#include <hip/hip_runtime.h>
#include <cstdint>
#include <cmath>

#define BATCH 64

typedef __attribute__((ext_vector_type(8))) __bf16 bf16x8;
typedef __attribute__((ext_vector_type(16))) float f32x16;

// ---------------------------------------------------------------------------
// Spline + silu expansion: x -> [silu(x), B_0(x) .. B_7(x)]
// ---------------------------------------------------------------------------
__device__ __forceinline__ void expand9(float x, float* e) {
  float t = __expf(-x);
  e[0] = __fdividef(x, 1.f + t);  // silu
  float b[11];
#pragma unroll
  for (int j = 0; j < 11; ++j) {
    float gj  = 0.4f * (float)j - 2.2f;
    float gj1 = 0.4f * (float)(j + 1) - 2.2f;
    b[j] = (x >= gj && x < gj1) ? 1.f : 0.f;
  }
#pragma unroll
  for (int k = 1; k <= 3; ++k) {
    float inv = 1.f / (0.4f * (float)k);
#pragma unroll
    for (int j = 0; j < 11 - k; ++j) {
      float gj   = 0.4f * (float)j - 2.2f;
      float gjk1 = 0.4f * (float)(j + k + 1) - 2.2f;
      b[j] = ((x - gj) * b[j] + (gjk1 - x) * b[j + 1]) * inv;
    }
  }
#pragma unroll
  for (int v = 0; v < 8; ++v) e[v + 1] = b[v];
}

// bf16 split helpers (round-to-nearest-even)
__device__ __forceinline__ unsigned short f2bf(float x) {
  uint32_t u = __float_as_uint(x);
  uint32_t r = u + 0x7fffu + ((u >> 16) & 1u);
  return (unsigned short)(r >> 16);
}
__device__ __forceinline__ float bf2f(unsigned short h) {
  return __uint_as_float(((uint32_t)h) << 16);
}
__device__ __forceinline__ uint32_t packsplit(float x) {
  unsigned short hi = f2bf(x);
  unsigned short lo = f2bf(x - bf2f(hi));
  return (uint32_t)hi | ((uint32_t)lo << 16);
}

// ---------------------------------------------------------------------------
// h = relu(x @ lin_w^T + lin_b); also writes packed expansion E (main path)
// ---------------------------------------------------------------------------
__global__ __launch_bounds__(256) void linear_pack_kernel(
    const float* __restrict__ x, const float* __restrict__ w,
    const float* __restrict__ bias, float* __restrict__ h,
    uint32_t* __restrict__ E, int writeE) {
  int idx = blockIdx.x * 256 + threadIdx.x;  // 64*2048
  int b = idx >> 11, o = idx & 2047;
  const float* xr = x + b * 100;
  const float* wr = w + o * 100;
  float acc = bias[o];
#pragma unroll 4
  for (int k = 0; k < 100; ++k) acc += xr[k] * wr[k];
  float hv = fmaxf(acc, 0.f);
  h[idx] = hv;
  if (writeE) {
    float e[9];
    expand9(hv, e);
    uint32_t* p = E + (size_t)idx * 9;
#pragma unroll
    for (int v = 0; v < 9; ++v) p[v] = packsplit(e[v]);
  }
}

// ---------------------------------------------------------------------------
// Pack expanded weights into MFMA-staging layout:
// Bg[kc][plane(hi=0,lo=1)][v(9)][n(N)][fl(16)]  (bf16)
// ---------------------------------------------------------------------------
template <int F, int N>
__global__ __launch_bounds__(256) void prep_bpack(
    const float* __restrict__ bw, const float* __restrict__ sw,
    const float* __restrict__ ss, unsigned short* __restrict__ Bg) {
  int idx = blockIdx.x * 256 + threadIdx.x;  // over (F/16)*9*N*16
  int fl = idx & 15;
  int n = (idx >> 4) & (N - 1);
  int rest = idx >> 4;
  rest /= N;
  int v = rest % 9;
  int kc = rest / 9;
  int f = kc * 16 + fl;
  size_t src = (size_t)n * F + f;
  float wv = (v == 0) ? bw[src] : sw[src * 8 + (v - 1)] * ss[src];
  unsigned short hi = f2bf(wv);
  unsigned short lo = f2bf(wv - bf2f(hi));
  size_t base = ((size_t)kc * 2 * 9 + v) * N * 16 + (size_t)n * 16 + fl;
  Bg[base] = hi;                          // plane 0
  Bg[base + (size_t)9 * N * 16] = lo;     // plane 1
}

// ---------------------------------------------------------------------------
// Split-bf16 MFMA GEMM, 2-phase reg-staged pipeline (round 11):
//  loop: barrier; WRITE staged regs->LDS; barrier; GLOAD(next)->regs;
//        frag reads + 27 MFMA.
// GLOAD(next) is issued AFTER the write barrier so the compiler's vmcnt(0)
// drain for it lands at the NEXT iteration's WRITE — latency hides under
// the MFMA+frag-read block. A-staging: 1 task/thread (4 consecutive fl),
// hi/lo pairs packed in regs, 18 ds_write_b64 (was 72 ds_write_u16).
// LDS layout and MFMA code identical to the round-6 proven kernel.
// ---------------------------------------------------------------------------
template <int CIN, int COUT, int HO, int WO, int SK>
__global__ __launch_bounds__(256, 2) void gemm_mfma(
    const uint32_t* __restrict__ E, const unsigned short* __restrict__ Bg,
    float* __restrict__ part) {
  constexpr int F = CIN * 9;
  constexpr int NKC = F / 16;
  constexpr int HI = HO / 2, WI = WO / 2;
  constexpr int M = BATCH * HO * WO;
  constexpr int CPB = NKC / SK;
  static_assert(NKC % SK == 0, "sk");

  __shared__ __align__(16) unsigned short lds[4 * 9216];

  const int t = threadIdx.x;
  const int mbase = blockIdx.x * 64;
  const int nb = blockIdx.y;
  const int kc0 = blockIdx.z * CPB;

  uint32_t ez[9];
  {
    float e0[9];
    expand9(0.f, e0);
#pragma unroll
    for (int v = 0; v < 9; ++v) ez[v] = packsplit(e0[v]);
  }

  const int lane = t & 63, wv_ = t >> 6;
  const int wm = wv_ >> 1, wn = wv_ & 1;
  const int frow = lane & 31, fkg = lane >> 5;
  const int aoff = ((wm * 32 + frow) * 16 + fkg * 8) * 2;  // bytes
  const int boff = ((wn * 32 + frow) * 16 + fkg * 8) * 2;

  // A-task geometry: thread covers row ml, fl = flq*4 .. flq*4+3
  const int ml = t >> 2, flq = t & 3;
  const int am = mbase + ml;
  const int ab = am / (HO * WO), ahw = am % (HO * WO);
  const int ahh = ahw / WO, aww = ahw % WO;

  // staged registers
  uint32_t uvA[4][9];
  uint4 bv[9];

  auto gload = [&](int kc) {
#pragma unroll
    for (int p4i = 0; p4i < 4; ++p4i) {
      int f = kc * 16 + flq * 4 + p4i;
      int c = f / 9, r = f - 9 * c;
      int kh = r / 3, kw = r - kh * 3;
      int hp = ahh + kh - 1, wp = aww + kw - 1;
      bool ok = (unsigned)hp < (unsigned)HO && (unsigned)wp < (unsigned)WO;
      if (ok) {
        const uint32_t* ep =
            E +
            (size_t)(((ab * CIN + c) * HI + (hp >> 1)) * WI + (wp >> 1)) * 9;
#pragma unroll
        for (int v = 0; v < 9; ++v) uvA[p4i][v] = ep[v];
      } else {
#pragma unroll
        for (int v = 0; v < 9; ++v) uvA[p4i][v] = ez[v];
      }
    }
    const unsigned short* bsrc = Bg + (size_t)kc * (2 * 9 * COUT * 16);
#pragma unroll
    for (int g = 0; g < 9; ++g) {
      int u = g * 256 + t;
      int pl = (u >= 1152) ? 1 : 0;
      int rr = u - pl * 1152;
      int v = rr >> 7, q = rr & 127;
      int nl = q >> 1, half = q & 1;
      size_t srcE = (size_t)pl * (9 * COUT * 16) + (size_t)v * (COUT * 16) +
                    (size_t)(nb * 64 + nl) * 16 + half * 8;
      bv[g] = *reinterpret_cast<const uint4*>(&bsrc[srcE]);
    }
  };

  f32x16 acc;
#pragma unroll
  for (int i = 0; i < 16; ++i) acc[i] = 0.f;

  gload(kc0);

  for (int ci = 0; ci < CPB; ++ci) {
    __syncthreads();  // previous chunk's frag reads done

    // ---- WRITE staged regs -> LDS ----
    char* lb = reinterpret_cast<char*>(lds);
#pragma unroll
    for (int v = 0; v < 9; ++v) {
      uint32_t hi01 = (uvA[0][v] & 0xffffu) | (uvA[1][v] << 16);
      uint32_t hi23 = (uvA[2][v] & 0xffffu) | (uvA[3][v] << 16);
      uint32_t lo01 = (uvA[0][v] >> 16) | (uvA[1][v] & 0xffff0000u);
      uint32_t lo23 = (uvA[2][v] >> 16) | (uvA[3][v] & 0xffff0000u);
      *reinterpret_cast<uint2*>(lb + v * 2048 + 8 * t) =
          make_uint2(hi01, hi23);
      *reinterpret_cast<uint2*>(lb + 18432 + v * 2048 + 8 * t) =
          make_uint2(lo01, lo23);
    }
#pragma unroll
    for (int g = 0; g < 9; ++g) {
      int u = g * 256 + t;
      int pl = (u >= 1152) ? 1 : 0;
      int rr = u - pl * 1152;
      int v = rr >> 7, q = rr & 127;
      int nl = q >> 1, half = q & 1;
      int dst = (2 + pl) * 9216 + v * 1024 + nl * 16 + half * 8;
      *reinterpret_cast<uint4*>(&lds[dst]) = bv[g];
    }
    __syncthreads();  // writes visible

    // ---- prefetch next chunk (after barrier: drain lands next iter) ----
    if (ci + 1 < CPB) gload(kc0 + ci + 1);

    // ---- compute: 9 v-steps x 3 split-products ----
#pragma unroll
    for (int v = 0; v < 9; ++v) {
      const char* lbc = reinterpret_cast<const char*>(lds);
      bf16x8 ah = *reinterpret_cast<const bf16x8*>(lbc + v * 2048 + aoff);
      bf16x8 al =
          *reinterpret_cast<const bf16x8*>(lbc + 18432 + v * 2048 + aoff);
      bf16x8 bh =
          *reinterpret_cast<const bf16x8*>(lbc + 36864 + v * 2048 + boff);
      bf16x8 bl =
          *reinterpret_cast<const bf16x8*>(lbc + 55296 + v * 2048 + boff);
      acc = __builtin_amdgcn_mfma_f32_32x32x16_bf16(ah, bh, acc, 0, 0, 0);
      acc = __builtin_amdgcn_mfma_f32_32x32x16_bf16(ah, bl, acc, 0, 0, 0);
      acc = __builtin_amdgcn_mfma_f32_32x32x16_bf16(al, bh, acc, 0, 0, 0);
    }
  }

  // ---- epilogue: C/D layout col=lane&31, row=(reg&3)+8*(reg>>2)+4*(lane>>5)
  float* p = part + (size_t)blockIdx.z * M * COUT;
  const int gn = nb * 64 + wn * 32 + frow;
#pragma unroll
  for (int r = 0; r < 16; ++r) {
    int mlocal = (r & 3) + 8 * (r >> 2) + 4 * fkg;
    int gm = mbase + wm * 32 + mlocal;
    p[(size_t)gm * COUT + gn] = acc[r];
  }
}

// ---------------------------------------------------------------------------
template <int COUT, int HO, int WO>
__global__ __launch_bounds__(256) void reduce_pe_pack(
    const float* __restrict__ part, uint32_t* __restrict__ E, int SK) {
  constexpr int M = BATCH * HO * WO;
  int idx = blockIdx.x * 256 + threadIdx.x;
  int ww = idx % WO;
  int tmp = idx / WO;
  int hh = tmp % HO;
  tmp /= HO;
  int o = tmp % COUT;
  int b = tmp / COUT;
  int m = (b * HO + hh) * WO + ww;
  float s = 0.f;
  for (int k = 0; k < SK; ++k) s += part[((size_t)k * M + m) * COUT + o];
  float e[9];
  expand9(s, e);
  uint32_t* p = E + (size_t)idx * 9;
#pragma unroll
  for (int v = 0; v < 9; ++v) p[v] = packsplit(e[v]);
}

template <int COUT, int HO, int WO>
__global__ __launch_bounds__(256) void reduce_p(
    const float* __restrict__ part, float* __restrict__ act, int SK) {
  constexpr int M = BATCH * HO * WO;
  int idx = blockIdx.x * 256 + threadIdx.x;
  int ww = idx % WO;
  int tmp = idx / WO;
  int hh = tmp % HO;
  tmp /= HO;
  int o = tmp % COUT;
  int b = tmp / COUT;
  int m = (b * HO + hh) * WO + ww;
  float s = 0.f;
  for (int k = 0; k < SK; ++k) s += part[((size_t)k * M + m) * COUT + o];
  act[idx] = s;
}

// ---------------------------------------------------------------------------
// L4 weights, neighbor-pre-summed:
// Wn[c][pc][nb][v][o] = sum over taps mapping to neighbor nb under parity pc.
// ---------------------------------------------------------------------------
__global__ __launch_bounds__(256) void prep_wnl4(
    const float* __restrict__ bw, const float* __restrict__ sw,
    const float* __restrict__ ss, float* __restrict__ Wn) {
  int idx = blockIdx.x * 256 + threadIdx.x;  // 64*4*4*27 = 27648
  if (idx >= 27648) return;
  int u = idx % 27;
  int o = u % 3, v = u / 3;
  int rest = idx / 27;
  int nb = rest & 3;
  rest >>= 2;
  int pc = rest & 3;
  rest >>= 2;
  int c = rest;  // 0..63
  int PH = pc >> 1, PW = pc & 1;
  int a = nb >> 1, b2 = nb & 1;
  float s = 0.f;
#pragma unroll
  for (int kh = 0; kh < 3; ++kh) {
    if (((kh > PH) ? 1 : 0) != a) continue;
#pragma unroll
    for (int kw = 0; kw < 3; ++kw) {
      if (((kw > PW) ? 1 : 0) != b2) continue;
      int f = c * 9 + kh * 3 + kw;
      float wv = (v == 0)
                     ? bw[o * 576 + f]
                     : sw[((size_t)(o * 576 + f)) * 8 + (v - 1)] * ss[o * 576 + f];
      s += wv;
    }
  }
  Wn[idx] = s;
}

// ---------------------------------------------------------------------------
// L4 v7 (round-10 proven): spill-free skeleton + pre-summed weights.
// ---------------------------------------------------------------------------
template <int PH, int PW>
__device__ void l4v7_wave(const float* __restrict__ eLds,
                          const float* __restrict__ WnB,
                          const float* __restrict__ ez, int lane, int bb,
                          int cs, float* __restrict__ p4) {
  constexpr int PC = PH * 2 + PW;
  const int j = lane & 15;
  const int i0 = (lane >> 4) << 2;
#pragma unroll 1
  for (int q = 0; q < 4; ++q) {
    const int i = i0 + q;
    float acc[3] = {0.f, 0.f, 0.f};
#pragma unroll
    for (int a = 0; a < 2; ++a) {
      const int gi = i + PH - 1 + a;
      const bool vr = (unsigned)gi < 16u;
#pragma unroll
      for (int b2 = 0; b2 < 2; ++b2) {
        const int gj = j + PW - 1 + b2;
        const bool ok = vr && ((unsigned)gj < 16u);
        const int pp = ok ? (gi * 16 + gj) : 0;  // clamped safe address
        const int nbi = a * 2 + b2;
#pragma unroll
        for (int cl = 0; cl < 4; ++cl) {
          const float* ep = eLds + cl * 2304 + pp * 9;
          float en[9];
#pragma unroll
          for (int v = 0; v < 9; ++v) en[v] = ok ? ep[v] : ez[v];
          const float* wp = WnB + ((cl * 4 + PC) * 4 + nbi) * 27;
#pragma unroll
          for (int v = 0; v < 9; ++v) {
            acc[0] = fmaf(en[v], wp[v * 3 + 0], acc[0]);
            acc[1] = fmaf(en[v], wp[v * 3 + 1], acc[1]);
            acc[2] = fmaf(en[v], wp[v * 3 + 2], acc[2]);
          }
        }
      }
    }
    const int h = (i << 1) + PH, w = (j << 1) + PW;
#pragma unroll
    for (int o = 0; o < 3; ++o)
      p4[(size_t)cs * 196608 + ((bb * 3 + o) << 10) + (h << 5) + w] = acc[o];
  }
}

__global__ __launch_bounds__(256) void kan_l4_v7(
    const float* __restrict__ a3, const float* __restrict__ Wn,
    float* __restrict__ p4) {
  __shared__ float eLds[4 * 256 * 9];  // 36.9 KB
  const int bid = blockIdx.x;          // 64 bb x 16 cs
  const int bb = bid >> 4, cs = bid & 15;
  const int t = threadIdx.x;
  float ez[9];
  expand9(0.f, ez);
#pragma unroll
  for (int cl = 0; cl < 4; ++cl) {
    float x = a3[(size_t)(bb * 64 + cs * 4 + cl) * 256 + t];
    float ev[9];
    expand9(x, ev);
#pragma unroll
    for (int v = 0; v < 9; ++v) eLds[(cl * 256 + t) * 9 + v] = ev[v];
  }
  __syncthreads();
  const int wv_ = t >> 6, lane = t & 63;
  const float* WnB = Wn + (size_t)cs * 4 * (4 * 4 * 27);
  if (wv_ == 0)
    l4v7_wave<0, 0>(eLds, WnB, ez, lane, bb, cs, p4);
  else if (wv_ == 1)
    l4v7_wave<0, 1>(eLds, WnB, ez, lane, bb, cs, p4);
  else if (wv_ == 2)
    l4v7_wave<1, 0>(eLds, WnB, ez, lane, bb, cs, p4);
  else
    l4v7_wave<1, 1>(eLds, WnB, ez, lane, bb, cs, p4);
}

__global__ __launch_bounds__(256) void reduce_tanh_l4_16(
    const float* __restrict__ p4, float* __restrict__ out) {
  int i = blockIdx.x * 256 + threadIdx.x;  // 196608
  float s = 0.f;
#pragma unroll
  for (int k = 0; k < 16; ++k) s += p4[(size_t)k * 196608 + i];
  out[i] = tanhf(s);
}

__global__ __launch_bounds__(256) void reduce_tanh_l4(
    const float* __restrict__ p4, float* __restrict__ out) {
  int i = blockIdx.x * 256 + threadIdx.x;
  float s = p4[i] + p4[i + 196608] + p4[i + 2 * 196608] + p4[i + 3 * 196608];
  out[i] = tanhf(s);
}

// ---------------------------------------------------------------------------
// Fallback path (round-1 proven) for small workspace
// ---------------------------------------------------------------------------
template <int CIN, int COUT, int HO, int WO, int BN, int SK>
__global__ __launch_bounds__(256) void kan_gemm(
    const float* __restrict__ in, const float* __restrict__ bw,
    const float* __restrict__ sw, const float* __restrict__ ss,
    float* __restrict__ outp) {
  constexpr int BM = 64, TM = 4, TN = 4, FC = 16;
  constexpr int F = CIN * 9;
  constexpr int HI = HO / 2, WI = WO / 2;
  constexpr int M = BATCH * HO * WO;
  constexpr int FPB = F / SK;

  __shared__ float Ae[FC * 9][BM];

  const int t = threadIdx.x;
  const int mbase = blockIdx.x * BM;
  const int obase = blockIdx.y * BN;
  const int f0 = blockIdx.z * FPB;

  const int cg = t & (BN / TN - 1);
  const int rg = t / (BN / TN);
  const int m0 = rg * TM;
  const int o0 = obase + cg * TN;

  float acc[TM][TN] = {};

  for (int fc = f0; fc < f0 + FPB; fc += FC) {
#pragma unroll
    for (int j = 0; j < BM * FC / 256; ++j) {
      int p = j * 256 + t;
      int ml = p & (BM - 1);
      int df = p >> 6;
      int f = fc + df;
      int c = f / 9;
      int r = f - c * 9;
      int kh = r / 3, kw = r - kh * 3;
      int m = mbase + ml;
      int bb = m / (HO * WO);
      int rem = m % (HO * WO);
      int hh = rem / WO, ww = rem % WO;
      int hp = hh + kh - 1, wp = ww + kw - 1;
      float val = 0.f;
      if (hp >= 0 && hp < HO && wp >= 0 && wp < WO)
        val = in[((bb * CIN + c) * HI + (hp >> 1)) * WI + (wp >> 1)];
      float e[9];
      expand9(val, e);
#pragma unroll
      for (int v = 0; v < 9; ++v) Ae[df * 9 + v][ml] = e[v];
    }
    __syncthreads();

#pragma unroll 2
    for (int df = 0; df < FC; ++df) {
      int f = fc + df;
      float wb[TN], wsv[TN][8];
#pragma unroll
      for (int tn = 0; tn < TN; ++tn) {
        int i = (o0 + tn) * F + f;
        wb[tn] = bw[i];
        float sc = ss[i];
        const float4* sp = reinterpret_cast<const float4*>(sw + (size_t)i * 8);
        float4 s0 = sp[0], s1 = sp[1];
        wsv[tn][0] = s0.x * sc; wsv[tn][1] = s0.y * sc;
        wsv[tn][2] = s0.z * sc; wsv[tn][3] = s0.w * sc;
        wsv[tn][4] = s1.x * sc; wsv[tn][5] = s1.y * sc;
        wsv[tn][6] = s1.z * sc; wsv[tn][7] = s1.w * sc;
      }
      float a[9][TM];
#pragma unroll
      for (int v = 0; v < 9; ++v) {
        float4 q = *reinterpret_cast<const float4*>(&Ae[df * 9 + v][m0]);
        a[v][0] = q.x; a[v][1] = q.y; a[v][2] = q.z; a[v][3] = q.w;
      }
#pragma unroll
      for (int tm = 0; tm < TM; ++tm)
#pragma unroll
        for (int tn = 0; tn < TN; ++tn) acc[tm][tn] += a[0][tm] * wb[tn];
#pragma unroll
      for (int v = 1; v < 9; ++v)
#pragma unroll
        for (int tm = 0; tm < TM; ++tm)
#pragma unroll
          for (int tn = 0; tn < TN; ++tn)
            acc[tm][tn] += a[v][tm] * wsv[tn][v - 1];
    }
    __syncthreads();
  }

  if constexpr (SK > 1) {
    float* p = outp + (size_t)blockIdx.z * M * COUT;
#pragma unroll
    for (int tm = 0; tm < TM; ++tm) {
      int m = mbase + m0 + tm;
#pragma unroll
      for (int tn = 0; tn < TN; ++tn)
        p[(size_t)m * COUT + (o0 + tn)] = acc[tm][tn];
    }
  } else {
#pragma unroll
    for (int tm = 0; tm < TM; ++tm) {
      int m = mbase + m0 + tm;
      int bb = m / (HO * WO);
      int rem = m % (HO * WO);
      int hh = rem / WO, ww = rem % WO;
#pragma unroll
      for (int tn = 0; tn < TN; ++tn) {
        int o = o0 + tn;
        outp[((bb * COUT + o) * HO + hh) * WO + ww] = acc[tm][tn];
      }
    }
  }
}

template <int COUT, int HO, int WO, int SK>
__global__ __launch_bounds__(256) void reduce_partials_old(
    const float* __restrict__ part, float* __restrict__ act) {
  constexpr int M = BATCH * HO * WO;
  int idx = blockIdx.x * 256 + threadIdx.x;
  if (idx >= M * COUT) return;
  float s = 0.f;
#pragma unroll
  for (int k = 0; k < SK; ++k) s += part[(size_t)k * M * COUT + idx];
  int m = idx / COUT, o = idx - (idx / COUT) * COUT;
  int bb = m / (HO * WO);
  int rem = m % (HO * WO);
  int hh = rem / WO, ww = rem % WO;
  act[((bb * COUT + o) * HO + hh) * WO + ww] = s;
}

__global__ __launch_bounds__(256) void kan_l4_split(
    const float* __restrict__ a3, const float* __restrict__ bw,
    const float* __restrict__ sw, const float* __restrict__ ss,
    float* __restrict__ p4) {
  int tid = blockIdx.x * 256 + threadIdx.x;
  int cs = tid >> 16, pix = tid & 65535;
  int b = pix >> 10, rem = pix & 1023, h = rem >> 5, w = rem & 31;
  float acc[3] = {0.f, 0.f, 0.f};
  for (int c = cs * 16; c < cs * 16 + 16; ++c) {
#pragma unroll
    for (int kh = 0; kh < 3; ++kh) {
#pragma unroll
      for (int kw = 0; kw < 3; ++kw) {
        int f = (c * 3 + kh) * 3 + kw;
        int hp = h + kh - 1, wp = w + kw - 1;
        float x = 0.f;
        if ((unsigned)hp < 32u && (unsigned)wp < 32u)
          x = a3[((b * 64 + c) * 16 + (hp >> 1)) * 16 + (wp >> 1)];
        float e[9];
        expand9(x, e);
#pragma unroll
        for (int o = 0; o < 3; ++o) {
          int i = o * 576 + f;
          float d = e[1] * sw[i * 8 + 0];
#pragma unroll
          for (int v = 1; v < 8; ++v) d += e[v + 1] * sw[i * 8 + v];
          acc[o] += e[0] * bw[i] + d * ss[i];
        }
      }
    }
  }
#pragma unroll
  for (int o = 0; o < 3; ++o)
    p4[cs * 196608 + ((b * 3 + o) << 10) + (h << 5) + w] = acc[o];
}

// ---------------------------------------------------------------------------
extern "C" void kernel_launch(void* const* d_in, const int* in_sizes, int n_in,
                              void* d_out, int out_size, void* d_ws,
                              size_t ws_size, hipStream_t stream) {
  const float* x     = (const float*)d_in[0];
  const float* lin_w = (const float*)d_in[1];
  const float* lin_b = (const float*)d_in[2];
  const float* bw1 = (const float*)d_in[3];
  const float* sw1 = (const float*)d_in[4];
  const float* ss1 = (const float*)d_in[5];
  const float* bw2 = (const float*)d_in[6];
  const float* sw2 = (const float*)d_in[7];
  const float* ss2 = (const float*)d_in[8];
  const float* bw3 = (const float*)d_in[9];
  const float* sw3 = (const float*)d_in[10];
  const float* ss3 = (const float*)d_in[11];
  const float* bw4 = (const float*)d_in[12];
  const float* sw4 = (const float*)d_in[13];
  const float* ss4 = (const float*)d_in[14];

  float* wsf = (float*)d_ws;
  float* h  = wsf;                        // 131072
  float* a1 = h + 131072;                 // 262144 (fallback only)
  float* a2 = a1 + 262144;                // 524288 (fallback only)
  float* a3 = a2 + 524288;                // 1048576, ends at 1966080
  // main-path regions
  unsigned short* Bg = (unsigned short*)(wsf + 1966080);  // 10,616,832 float-slots
  float* part = wsf + 1966080 + 10616832;                 // 2,097,152
  uint32_t* Eg = (uint32_t*)(wsf + 14680064);             // 4,718,592
  float* wl4 = h;                    // h dead on main path after linear (27648 floats)
  float* p4  = wsf + 1966080;        // 16*196608 = 3.1M, reuses Bg (dead post-L3)

  const size_t baseFloats = 1966080;
  size_t availFloats = ws_size / 4 > baseFloats ? ws_size / 4 - baseFloats : 0;
  const size_t mainNeed = 10616832ull + 2097152ull + 4718592ull;  // 17.4M

  if (availFloats >= mainNeed) {
    linear_pack_kernel<<<512, 256, 0, stream>>>(x, lin_w, lin_b, h, Eg, 1);

    // L1: CIN=512 COUT=256 4x4, SK=8
    prep_bpack<4608, 256><<<41472, 256, 0, stream>>>(bw1, sw1, ss1, Bg);
    gemm_mfma<512, 256, 4, 4, 8>
        <<<dim3(16, 4, 8), 256, 0, stream>>>(Eg, Bg, part);
    reduce_pe_pack<256, 4, 4><<<1024, 256, 0, stream>>>(part, Eg, 8);

    // L2: CIN=256 COUT=128 8x8, SK=4
    prep_bpack<2304, 128><<<10368, 256, 0, stream>>>(bw2, sw2, ss2, Bg);
    gemm_mfma<256, 128, 8, 8, 4>
        <<<dim3(64, 2, 4), 256, 0, stream>>>(Eg, Bg, part);
    reduce_pe_pack<128, 8, 8><<<2048, 256, 0, stream>>>(part, Eg, 4);

    // L3: CIN=128 COUT=64 16x16, SK=2
    prep_bpack<1152, 64><<<2592, 256, 0, stream>>>(bw3, sw3, ss3, Bg);
    gemm_mfma<128, 64, 16, 16, 2>
        <<<dim3(256, 1, 2), 256, 0, stream>>>(Eg, Bg, part);
    reduce_p<64, 16, 16><<<4096, 256, 0, stream>>>(part, a3, 2);

    // L4: fused LDS expansion + pre-summed weights (round-10 proven)
    prep_wnl4<<<108, 256, 0, stream>>>(bw4, sw4, ss4, wl4);
    kan_l4_v7<<<1024, 256, 0, stream>>>(a3, wl4, p4);
    reduce_tanh_l4_16<<<768, 256, 0, stream>>>(p4, (float*)d_out);
  } else {
    // round-1 proven fallback (needs ~16.3 MB)
    float* partOld = a3 + 1048576;
    linear_pack_kernel<<<512, 256, 0, stream>>>(x, lin_w, lin_b, h, nullptr, 0);
    kan_gemm<512, 256, 4, 4, 64, 8>
        <<<dim3(16, 4, 8), 256, 0, stream>>>(h, bw1, sw1, ss1, partOld);
    reduce_partials_old<256, 4, 4, 8><<<1024, 256, 0, stream>>>(partOld, a1);
    kan_gemm<256, 128, 8, 8, 64, 2>
        <<<dim3(64, 2, 2), 256, 0, stream>>>(a1, bw2, sw2, ss2, partOld);
    reduce_partials_old<128, 8, 8, 2><<<2048, 256, 0, stream>>>(partOld, a2);
    kan_gemm<128, 64, 16, 16, 64, 1>
        <<<dim3(256, 1, 1), 256, 0, stream>>>(a2, bw3, sw3, ss3, a3);
    kan_l4_split<<<1024, 256, 0, stream>>>(a3, bw4, sw4, ss4, partOld);
    reduce_tanh_l4<<<768, 256, 0, stream>>>(partOld, (float*)d_out);
  }
}

// Round 12
// 607.296 us; speedup vs baseline: 1.5194x; 1.5194x over previous
//
#include <hip/hip_runtime.h>
#include <cstdint>
#include <cmath>

#define BATCH 64

typedef __attribute__((ext_vector_type(8))) __bf16 bf16x8;
typedef __attribute__((ext_vector_type(16))) float f32x16;

// ---------------------------------------------------------------------------
// Spline + silu expansion: x -> [silu(x), B_0(x) .. B_7(x)]
// ---------------------------------------------------------------------------
__device__ __forceinline__ void expand9(float x, float* e) {
  float t = __expf(-x);
  e[0] = __fdividef(x, 1.f + t);  // silu
  float b[11];
#pragma unroll
  for (int j = 0; j < 11; ++j) {
    float gj  = 0.4f * (float)j - 2.2f;
    float gj1 = 0.4f * (float)(j + 1) - 2.2f;
    b[j] = (x >= gj && x < gj1) ? 1.f : 0.f;
  }
#pragma unroll
  for (int k = 1; k <= 3; ++k) {
    float inv = 1.f / (0.4f * (float)k);
#pragma unroll
    for (int j = 0; j < 11 - k; ++j) {
      float gj   = 0.4f * (float)j - 2.2f;
      float gjk1 = 0.4f * (float)(j + k + 1) - 2.2f;
      b[j] = ((x - gj) * b[j] + (gjk1 - x) * b[j + 1]) * inv;
    }
  }
#pragma unroll
  for (int v = 0; v < 8; ++v) e[v + 1] = b[v];
}

// bf16 split helpers (round-to-nearest-even)
__device__ __forceinline__ unsigned short f2bf(float x) {
  uint32_t u = __float_as_uint(x);
  uint32_t r = u + 0x7fffu + ((u >> 16) & 1u);
  return (unsigned short)(r >> 16);
}
__device__ __forceinline__ float bf2f(unsigned short h) {
  return __uint_as_float(((uint32_t)h) << 16);
}
__device__ __forceinline__ uint32_t packsplit(float x) {
  unsigned short hi = f2bf(x);
  unsigned short lo = f2bf(x - bf2f(hi));
  return (uint32_t)hi | ((uint32_t)lo << 16);
}

// ---------------------------------------------------------------------------
// h = relu(x @ lin_w^T + lin_b); also writes packed expansion E (main path)
// ---------------------------------------------------------------------------
__global__ __launch_bounds__(256) void linear_pack_kernel(
    const float* __restrict__ x, const float* __restrict__ w,
    const float* __restrict__ bias, float* __restrict__ h,
    uint32_t* __restrict__ E, int writeE) {
  int idx = blockIdx.x * 256 + threadIdx.x;  // 64*2048
  int b = idx >> 11, o = idx & 2047;
  const float* xr = x + b * 100;
  const float* wr = w + o * 100;
  float acc = bias[o];
#pragma unroll 4
  for (int k = 0; k < 100; ++k) acc += xr[k] * wr[k];
  float hv = fmaxf(acc, 0.f);
  h[idx] = hv;
  if (writeE) {
    float e[9];
    expand9(hv, e);
    uint32_t* p = E + (size_t)idx * 9;
#pragma unroll
    for (int v = 0; v < 9; ++v) p[v] = packsplit(e[v]);
  }
}

// ---------------------------------------------------------------------------
// Pack expanded weights into MFMA-staging layout:
// Bg[kc][plane(hi=0,lo=1)][v(9)][n(N)][fl(16)]  (bf16)
// ---------------------------------------------------------------------------
template <int F, int N>
__global__ __launch_bounds__(256) void prep_bpack(
    const float* __restrict__ bw, const float* __restrict__ sw,
    const float* __restrict__ ss, unsigned short* __restrict__ Bg) {
  int idx = blockIdx.x * 256 + threadIdx.x;  // over (F/16)*9*N*16
  int fl = idx & 15;
  int n = (idx >> 4) & (N - 1);
  int rest = idx >> 4;
  rest /= N;
  int v = rest % 9;
  int kc = rest / 9;
  int f = kc * 16 + fl;
  size_t src = (size_t)n * F + f;
  float wv = (v == 0) ? bw[src] : sw[src * 8 + (v - 1)] * ss[src];
  unsigned short hi = f2bf(wv);
  unsigned short lo = f2bf(wv - bf2f(hi));
  size_t base = ((size_t)kc * 2 * 9 + v) * N * 16 + (size_t)n * 16 + fl;
  Bg[base] = hi;                          // plane 0
  Bg[base + (size_t)9 * N * 16] = lo;     // plane 1
}

// ---------------------------------------------------------------------------
// Split-bf16 MFMA GEMM (round-10 proven body; round-12 staging fixes):
//  - B staged via __builtin_amdgcn_global_load_lds (16B, linear dest:
//    dst_bytes = 36864 + u*16 is linear in u = g*256+t, incl. pl switch).
//  - A staged phase-locally: thread covers (ml = t>>2, 4 consecutive fl),
//    4 NAMED pointers, predicated loads vs ez, pack hi/lo, 18 ds_write_b64
//    (was 72 ds_write_u16). No aggregate lives across a phase (spill-safe).
// ---------------------------------------------------------------------------
template <int CIN, int COUT, int HO, int WO, int SK>
__global__ __launch_bounds__(256, 2) void gemm_mfma(
    const uint32_t* __restrict__ E, const unsigned short* __restrict__ Bg,
    float* __restrict__ part) {
  constexpr int F = CIN * 9;
  constexpr int NKC = F / 16;
  constexpr int HI = HO / 2, WI = WO / 2;
  constexpr int M = BATCH * HO * WO;
  constexpr int CPB = NKC / SK;
  static_assert(NKC % SK == 0, "sk");

  __shared__ __align__(16) unsigned short lds[4 * 9216];

  const int t = threadIdx.x;
  const int mbase = blockIdx.x * 64;
  const int nb = blockIdx.y;
  const int kc0 = blockIdx.z * CPB;

  uint32_t ez[9];
  {
    float e0[9];
    expand9(0.f, e0);
#pragma unroll
    for (int v = 0; v < 9; ++v) ez[v] = packsplit(e0[v]);
  }

  const int lane = t & 63, wv_ = t >> 6;
  const int wm = wv_ >> 1, wn = wv_ & 1;
  const int frow = lane & 31, fkg = lane >> 5;
  const int aoff = ((wm * 32 + frow) * 16 + fkg * 8) * 2;  // bytes
  const int boff = ((wn * 32 + frow) * 16 + fkg * 8) * 2;

  // A-staging geometry: thread covers row ml2, fl = flq*4 .. flq*4+3
  const int ml2 = t >> 2, flq = t & 3;
  const int am = mbase + ml2;
  const int ab = am / (HO * WO), ahw = am % (HO * WO);
  const int ahh = ahw / WO, aww = ahw % WO;

  f32x16 acc;
#pragma unroll
  for (int i = 0; i < 16; ++i) acc[i] = 0.f;

  for (int ci = 0; ci < CPB; ++ci) {
    const int kc = kc0 + ci;
    __syncthreads();

    // ---- stage A: 4 consecutive fl per thread, phase-local named scalars --
    {
      bool ok0, ok1, ok2, ok3;
      const uint32_t *p0, *p1, *p2, *p3;
#define MKPTR(IDX, OKV, PV)                                                  \
  {                                                                          \
    int f = kc * 16 + flq * 4 + IDX;                                         \
    int c = f / 9, r = f - 9 * c;                                            \
    int kh = r / 3, kw = r - kh * 3;                                         \
    int hp = ahh + kh - 1, wp = aww + kw - 1;                                \
    OKV = (unsigned)hp < (unsigned)HO && (unsigned)wp < (unsigned)WO;        \
    int hc = OKV ? (hp >> 1) : 0, wc = OKV ? (wp >> 1) : 0;                  \
    PV = E + (size_t)(((ab * CIN + c) * HI + hc) * WI + wc) * 9;             \
  }
      MKPTR(0, ok0, p0)
      MKPTR(1, ok1, p1)
      MKPTR(2, ok2, p2)
      MKPTR(3, ok3, p3)
#undef MKPTR
      char* lb = reinterpret_cast<char*>(lds);
#pragma unroll
      for (int v = 0; v < 9; ++v) {
        uint32_t a0 = ok0 ? p0[v] : ez[v];
        uint32_t a1 = ok1 ? p1[v] : ez[v];
        uint32_t a2 = ok2 ? p2[v] : ez[v];
        uint32_t a3 = ok3 ? p3[v] : ez[v];
        uint32_t hi01 = (a0 & 0xffffu) | (a1 << 16);
        uint32_t hi23 = (a2 & 0xffffu) | (a3 << 16);
        uint32_t lo01 = (a0 >> 16) | (a1 & 0xffff0000u);
        uint32_t lo23 = (a2 >> 16) | (a3 & 0xffff0000u);
        *reinterpret_cast<uint2*>(lb + v * 2048 + ml2 * 32 + flq * 8) =
            make_uint2(hi01, hi23);
        *reinterpret_cast<uint2*>(lb + 18432 + v * 2048 + ml2 * 32 + flq * 8) =
            make_uint2(lo01, lo23);
      }
    }

    // ---- stage B: global_load_lds, 16B per thread per g (linear dest) ----
    {
      const unsigned short* bsrc = Bg + (size_t)kc * (2 * 9 * COUT * 16);
#pragma unroll
      for (int g = 0; g < 9; ++g) {
        int u = g * 256 + t;
        int pl = (u >= 1152) ? 1 : 0;
        int rr = u - pl * 1152;
        int v = rr >> 7, q = rr & 127;
        int nl = q >> 1, half = q & 1;
        size_t srcE = (size_t)pl * (9 * COUT * 16) + (size_t)v * (COUT * 16) +
                      (size_t)(nb * 64 + nl) * 16 + half * 8;
        __builtin_amdgcn_global_load_lds(
            (const __attribute__((address_space(1))) uint32_t*)(bsrc + srcE),
            (__attribute__((address_space(3))) uint32_t*)(&lds[18432 + u * 8]),
            16, 0, 0);
      }
    }
    __syncthreads();

    // ---- compute: 9 v-steps x 3 split-products ----
#pragma unroll
    for (int v = 0; v < 9; ++v) {
      const char* lbc = reinterpret_cast<const char*>(lds);
      bf16x8 ah = *reinterpret_cast<const bf16x8*>(lbc + v * 2048 + aoff);
      bf16x8 al =
          *reinterpret_cast<const bf16x8*>(lbc + 18432 + v * 2048 + aoff);
      bf16x8 bh =
          *reinterpret_cast<const bf16x8*>(lbc + 36864 + v * 2048 + boff);
      bf16x8 bl =
          *reinterpret_cast<const bf16x8*>(lbc + 55296 + v * 2048 + boff);
      acc = __builtin_amdgcn_mfma_f32_32x32x16_bf16(ah, bh, acc, 0, 0, 0);
      acc = __builtin_amdgcn_mfma_f32_32x32x16_bf16(ah, bl, acc, 0, 0, 0);
      acc = __builtin_amdgcn_mfma_f32_32x32x16_bf16(al, bh, acc, 0, 0, 0);
    }
  }

  // ---- epilogue: C/D layout col=lane&31, row=(reg&3)+8*(reg>>2)+4*(lane>>5)
  float* p = part + (size_t)blockIdx.z * M * COUT;
  const int gn = nb * 64 + wn * 32 + frow;
#pragma unroll
  for (int r = 0; r < 16; ++r) {
    int mlocal = (r & 3) + 8 * (r >> 2) + 4 * fkg;
    int gm = mbase + wm * 32 + mlocal;
    p[(size_t)gm * COUT + gn] = acc[r];
  }
}

// ---------------------------------------------------------------------------
template <int COUT, int HO, int WO>
__global__ __launch_bounds__(256) void reduce_pe_pack(
    const float* __restrict__ part, uint32_t* __restrict__ E, int SK) {
  constexpr int M = BATCH * HO * WO;
  int idx = blockIdx.x * 256 + threadIdx.x;
  int ww = idx % WO;
  int tmp = idx / WO;
  int hh = tmp % HO;
  tmp /= HO;
  int o = tmp % COUT;
  int b = tmp / COUT;
  int m = (b * HO + hh) * WO + ww;
  float s = 0.f;
  for (int k = 0; k < SK; ++k) s += part[((size_t)k * M + m) * COUT + o];
  float e[9];
  expand9(s, e);
  uint32_t* p = E + (size_t)idx * 9;
#pragma unroll
  for (int v = 0; v < 9; ++v) p[v] = packsplit(e[v]);
}

template <int COUT, int HO, int WO>
__global__ __launch_bounds__(256) void reduce_p(
    const float* __restrict__ part, float* __restrict__ act, int SK) {
  constexpr int M = BATCH * HO * WO;
  int idx = blockIdx.x * 256 + threadIdx.x;
  int ww = idx % WO;
  int tmp = idx / WO;
  int hh = tmp % HO;
  tmp /= HO;
  int o = tmp % COUT;
  int b = tmp / COUT;
  int m = (b * HO + hh) * WO + ww;
  float s = 0.f;
  for (int k = 0; k < SK; ++k) s += part[((size_t)k * M + m) * COUT + o];
  act[idx] = s;
}

// ---------------------------------------------------------------------------
// L4 weights, neighbor-pre-summed:
// Wn[c][pc][nb][v][o] = sum over taps mapping to neighbor nb under parity pc.
// ---------------------------------------------------------------------------
__global__ __launch_bounds__(256) void prep_wnl4(
    const float* __restrict__ bw, const float* __restrict__ sw,
    const float* __restrict__ ss, float* __restrict__ Wn) {
  int idx = blockIdx.x * 256 + threadIdx.x;  // 64*4*4*27 = 27648
  if (idx >= 27648) return;
  int u = idx % 27;
  int o = u % 3, v = u / 3;
  int rest = idx / 27;
  int nb = rest & 3;
  rest >>= 2;
  int pc = rest & 3;
  rest >>= 2;
  int c = rest;  // 0..63
  int PH = pc >> 1, PW = pc & 1;
  int a = nb >> 1, b2 = nb & 1;
  float s = 0.f;
#pragma unroll
  for (int kh = 0; kh < 3; ++kh) {
    if (((kh > PH) ? 1 : 0) != a) continue;
#pragma unroll
    for (int kw = 0; kw < 3; ++kw) {
      if (((kw > PW) ? 1 : 0) != b2) continue;
      int f = c * 9 + kh * 3 + kw;
      float wv = (v == 0)
                     ? bw[o * 576 + f]
                     : sw[((size_t)(o * 576 + f)) * 8 + (v - 1)] * ss[o * 576 + f];
      s += wv;
    }
  }
  Wn[idx] = s;
}

// ---------------------------------------------------------------------------
// L4 v7 (round-10 proven): spill-free skeleton + pre-summed weights.
// ---------------------------------------------------------------------------
template <int PH, int PW>
__device__ void l4v7_wave(const float* __restrict__ eLds,
                          const float* __restrict__ WnB,
                          const float* __restrict__ ez, int lane, int bb,
                          int cs, float* __restrict__ p4) {
  constexpr int PC = PH * 2 + PW;
  const int j = lane & 15;
  const int i0 = (lane >> 4) << 2;
#pragma unroll 1
  for (int q = 0; q < 4; ++q) {
    const int i = i0 + q;
    float acc[3] = {0.f, 0.f, 0.f};
#pragma unroll
    for (int a = 0; a < 2; ++a) {
      const int gi = i + PH - 1 + a;
      const bool vr = (unsigned)gi < 16u;
#pragma unroll
      for (int b2 = 0; b2 < 2; ++b2) {
        const int gj = j + PW - 1 + b2;
        const bool ok = vr && ((unsigned)gj < 16u);
        const int pp = ok ? (gi * 16 + gj) : 0;  // clamped safe address
        const int nbi = a * 2 + b2;
#pragma unroll
        for (int cl = 0; cl < 4; ++cl) {
          const float* ep = eLds + cl * 2304 + pp * 9;
          float en[9];
#pragma unroll
          for (int v = 0; v < 9; ++v) en[v] = ok ? ep[v] : ez[v];
          const float* wp = WnB + ((cl * 4 + PC) * 4 + nbi) * 27;
#pragma unroll
          for (int v = 0; v < 9; ++v) {
            acc[0] = fmaf(en[v], wp[v * 3 + 0], acc[0]);
            acc[1] = fmaf(en[v], wp[v * 3 + 1], acc[1]);
            acc[2] = fmaf(en[v], wp[v * 3 + 2], acc[2]);
          }
        }
      }
    }
    const int h = (i << 1) + PH, w = (j << 1) + PW;
#pragma unroll
    for (int o = 0; o < 3; ++o)
      p4[(size_t)cs * 196608 + ((bb * 3 + o) << 10) + (h << 5) + w] = acc[o];
  }
}

__global__ __launch_bounds__(256) void kan_l4_v7(
    const float* __restrict__ a3, const float* __restrict__ Wn,
    float* __restrict__ p4) {
  __shared__ float eLds[4 * 256 * 9];  // 36.9 KB
  const int bid = blockIdx.x;          // 64 bb x 16 cs
  const int bb = bid >> 4, cs = bid & 15;
  const int t = threadIdx.x;
  float ez[9];
  expand9(0.f, ez);
#pragma unroll
  for (int cl = 0; cl < 4; ++cl) {
    float x = a3[(size_t)(bb * 64 + cs * 4 + cl) * 256 + t];
    float ev[9];
    expand9(x, ev);
#pragma unroll
    for (int v = 0; v < 9; ++v) eLds[(cl * 256 + t) * 9 + v] = ev[v];
  }
  __syncthreads();
  const int wv_ = t >> 6, lane = t & 63;
  const float* WnB = Wn + (size_t)cs * 4 * (4 * 4 * 27);
  if (wv_ == 0)
    l4v7_wave<0, 0>(eLds, WnB, ez, lane, bb, cs, p4);
  else if (wv_ == 1)
    l4v7_wave<0, 1>(eLds, WnB, ez, lane, bb, cs, p4);
  else if (wv_ == 2)
    l4v7_wave<1, 0>(eLds, WnB, ez, lane, bb, cs, p4);
  else
    l4v7_wave<1, 1>(eLds, WnB, ez, lane, bb, cs, p4);
}

__global__ __launch_bounds__(256) void reduce_tanh_l4_16(
    const float* __restrict__ p4, float* __restrict__ out) {
  int i = blockIdx.x * 256 + threadIdx.x;  // 196608
  float s = 0.f;
#pragma unroll
  for (int k = 0; k < 16; ++k) s += p4[(size_t)k * 196608 + i];
  out[i] = tanhf(s);
}

__global__ __launch_bounds__(256) void reduce_tanh_l4(
    const float* __restrict__ p4, float* __restrict__ out) {
  int i = blockIdx.x * 256 + threadIdx.x;
  float s = p4[i] + p4[i + 196608] + p4[i + 2 * 196608] + p4[i + 3 * 196608];
  out[i] = tanhf(s);
}

// ---------------------------------------------------------------------------
// Fallback path (round-1 proven) for small workspace
// ---------------------------------------------------------------------------
template <int CIN, int COUT, int HO, int WO, int BN, int SK>
__global__ __launch_bounds__(256) void kan_gemm(
    const float* __restrict__ in, const float* __restrict__ bw,
    const float* __restrict__ sw, const float* __restrict__ ss,
    float* __restrict__ outp) {
  constexpr int BM = 64, TM = 4, TN = 4, FC = 16;
  constexpr int F = CIN * 9;
  constexpr int HI = HO / 2, WI = WO / 2;
  constexpr int M = BATCH * HO * WO;
  constexpr int FPB = F / SK;

  __shared__ float Ae[FC * 9][BM];

  const int t = threadIdx.x;
  const int mbase = blockIdx.x * BM;
  const int obase = blockIdx.y * BN;
  const int f0 = blockIdx.z * FPB;

  const int cg = t & (BN / TN - 1);
  const int rg = t / (BN / TN);
  const int m0 = rg * TM;
  const int o0 = obase + cg * TN;

  float acc[TM][TN] = {};

  for (int fc = f0; fc < f0 + FPB; fc += FC) {
#pragma unroll
    for (int j = 0; j < BM * FC / 256; ++j) {
      int p = j * 256 + t;
      int ml = p & (BM - 1);
      int df = p >> 6;
      int f = fc + df;
      int c = f / 9;
      int r = f - c * 9;
      int kh = r / 3, kw = r - kh * 3;
      int m = mbase + ml;
      int bb = m / (HO * WO);
      int rem = m % (HO * WO);
      int hh = rem / WO, ww = rem % WO;
      int hp = hh + kh - 1, wp = ww + kw - 1;
      float val = 0.f;
      if (hp >= 0 && hp < HO && wp >= 0 && wp < WO)
        val = in[((bb * CIN + c) * HI + (hp >> 1)) * WI + (wp >> 1)];
      float e[9];
      expand9(val, e);
#pragma unroll
      for (int v = 0; v < 9; ++v) Ae[df * 9 + v][ml] = e[v];
    }
    __syncthreads();

#pragma unroll 2
    for (int df = 0; df < FC; ++df) {
      int f = fc + df;
      float wb[TN], wsv[TN][8];
#pragma unroll
      for (int tn = 0; tn < TN; ++tn) {
        int i = (o0 + tn) * F + f;
        wb[tn] = bw[i];
        float sc = ss[i];
        const float4* sp = reinterpret_cast<const float4*>(sw + (size_t)i * 8);
        float4 s0 = sp[0], s1 = sp[1];
        wsv[tn][0] = s0.x * sc; wsv[tn][1] = s0.y * sc;
        wsv[tn][2] = s0.z * sc; wsv[tn][3] = s0.w * sc;
        wsv[tn][4] = s1.x * sc; wsv[tn][5] = s1.y * sc;
        wsv[tn][6] = s1.z * sc; wsv[tn][7] = s1.w * sc;
      }
      float a[9][TM];
#pragma unroll
      for (int v = 0; v < 9; ++v) {
        float4 q = *reinterpret_cast<const float4*>(&Ae[df * 9 + v][m0]);
        a[v][0] = q.x; a[v][1] = q.y; a[v][2] = q.z; a[v][3] = q.w;
      }
#pragma unroll
      for (int tm = 0; tm < TM; ++tm)
#pragma unroll
        for (int tn = 0; tn < TN; ++tn) acc[tm][tn] += a[0][tm] * wb[tn];
#pragma unroll
      for (int v = 1; v < 9; ++v)
#pragma unroll
        for (int tm = 0; tm < TM; ++tm)
#pragma unroll
          for (int tn = 0; tn < TN; ++tn)
            acc[tm][tn] += a[v][tm] * wsv[tn][v - 1];
    }
    __syncthreads();
  }

  if constexpr (SK > 1) {
    float* p = outp + (size_t)blockIdx.z * M * COUT;
#pragma unroll
    for (int tm = 0; tm < TM; ++tm) {
      int m = mbase + m0 + tm;
#pragma unroll
      for (int tn = 0; tn < TN; ++tn)
        p[(size_t)m * COUT + (o0 + tn)] = acc[tm][tn];
    }
  } else {
#pragma unroll
    for (int tm = 0; tm < TM; ++tm) {
      int m = mbase + m0 + tm;
      int bb = m / (HO * WO);
      int rem = m % (HO * WO);
      int hh = rem / WO, ww = rem % WO;
#pragma unroll
      for (int tn = 0; tn < TN; ++tn) {
        int o = o0 + tn;
        outp[((bb * COUT + o) * HO + hh) * WO + ww] = acc[tm][tn];
      }
    }
  }
}

template <int COUT, int HO, int WO, int SK>
__global__ __launch_bounds__(256) void reduce_partials_old(
    const float* __restrict__ part, float* __restrict__ act) {
  constexpr int M = BATCH * HO * WO;
  int idx = blockIdx.x * 256 + threadIdx.x;
  if (idx >= M * COUT) return;
  float s = 0.f;
#pragma unroll
  for (int k = 0; k < SK; ++k) s += part[(size_t)k * M * COUT + idx];
  int m = idx / COUT, o = idx - (idx / COUT) * COUT;
  int bb = m / (HO * WO);
  int rem = m % (HO * WO);
  int hh = rem / WO, ww = rem % WO;
  act[((bb * COUT + o) * HO + hh) * WO + ww] = s;
}

__global__ __launch_bounds__(256) void kan_l4_split(
    const float* __restrict__ a3, const float* __restrict__ bw,
    const float* __restrict__ sw, const float* __restrict__ ss,
    float* __restrict__ p4) {
  int tid = blockIdx.x * 256 + threadIdx.x;
  int cs = tid >> 16, pix = tid & 65535;
  int b = pix >> 10, rem = pix & 1023, h = rem >> 5, w = rem & 31;
  float acc[3] = {0.f, 0.f, 0.f};
  for (int c = cs * 16; c < cs * 16 + 16; ++c) {
#pragma unroll
    for (int kh = 0; kh < 3; ++kh) {
#pragma unroll
      for (int kw = 0; kw < 3; ++kw) {
        int f = (c * 3 + kh) * 3 + kw;
        int hp = h + kh - 1, wp = w + kw - 1;
        float x = 0.f;
        if ((unsigned)hp < 32u && (unsigned)wp < 32u)
          x = a3[((b * 64 + c) * 16 + (hp >> 1)) * 16 + (wp >> 1)];
        float e[9];
        expand9(x, e);
#pragma unroll
        for (int o = 0; o < 3; ++o) {
          int i = o * 576 + f;
          float d = e[1] * sw[i * 8 + 0];
#pragma unroll
          for (int v = 1; v < 8; ++v) d += e[v + 1] * sw[i * 8 + v];
          acc[o] += e[0] * bw[i] + d * ss[i];
        }
      }
    }
  }
#pragma unroll
  for (int o = 0; o < 3; ++o)
    p4[cs * 196608 + ((b * 3 + o) << 10) + (h << 5) + w] = acc[o];
}

// ---------------------------------------------------------------------------
extern "C" void kernel_launch(void* const* d_in, const int* in_sizes, int n_in,
                              void* d_out, int out_size, void* d_ws,
                              size_t ws_size, hipStream_t stream) {
  const float* x     = (const float*)d_in[0];
  const float* lin_w = (const float*)d_in[1];
  const float* lin_b = (const float*)d_in[2];
  const float* bw1 = (const float*)d_in[3];
  const float* sw1 = (const float*)d_in[4];
  const float* ss1 = (const float*)d_in[5];
  const float* bw2 = (const float*)d_in[6];
  const float* sw2 = (const float*)d_in[7];
  const float* ss2 = (const float*)d_in[8];
  const float* bw3 = (const float*)d_in[9];
  const float* sw3 = (const float*)d_in[10];
  const float* ss3 = (const float*)d_in[11];
  const float* bw4 = (const float*)d_in[12];
  const float* sw4 = (const float*)d_in[13];
  const float* ss4 = (const float*)d_in[14];

  float* wsf = (float*)d_ws;
  float* h  = wsf;                        // 131072
  float* a1 = h + 131072;                 // 262144 (fallback only)
  float* a2 = a1 + 262144;                // 524288 (fallback only)
  float* a3 = a2 + 524288;                // 1048576, ends at 1966080
  // main-path regions
  unsigned short* Bg = (unsigned short*)(wsf + 1966080);  // 10,616,832 float-slots
  float* part = wsf + 1966080 + 10616832;                 // 2,097,152
  uint32_t* Eg = (uint32_t*)(wsf + 14680064);             // 4,718,592
  float* wl4 = h;                    // h dead on main path after linear (27648 floats)
  float* p4  = wsf + 1966080;        // 16*196608 = 3.1M, reuses Bg (dead post-L3)

  const size_t baseFloats = 1966080;
  size_t availFloats = ws_size / 4 > baseFloats ? ws_size / 4 - baseFloats : 0;
  const size_t mainNeed = 10616832ull + 2097152ull + 4718592ull;  // 17.4M

  if (availFloats >= mainNeed) {
    linear_pack_kernel<<<512, 256, 0, stream>>>(x, lin_w, lin_b, h, Eg, 1);

    // L1: CIN=512 COUT=256 4x4, SK=8
    prep_bpack<4608, 256><<<41472, 256, 0, stream>>>(bw1, sw1, ss1, Bg);
    gemm_mfma<512, 256, 4, 4, 8>
        <<<dim3(16, 4, 8), 256, 0, stream>>>(Eg, Bg, part);
    reduce_pe_pack<256, 4, 4><<<1024, 256, 0, stream>>>(part, Eg, 8);

    // L2: CIN=256 COUT=128 8x8, SK=4
    prep_bpack<2304, 128><<<10368, 256, 0, stream>>>(bw2, sw2, ss2, Bg);
    gemm_mfma<256, 128, 8, 8, 4>
        <<<dim3(64, 2, 4), 256, 0, stream>>>(Eg, Bg, part);
    reduce_pe_pack<128, 8, 8><<<2048, 256, 0, stream>>>(part, Eg, 4);

    // L3: CIN=128 COUT=64 16x16, SK=2
    prep_bpack<1152, 64><<<2592, 256, 0, stream>>>(bw3, sw3, ss3, Bg);
    gemm_mfma<128, 64, 16, 16, 2>
        <<<dim3(256, 1, 2), 256, 0, stream>>>(Eg, Bg, part);
    reduce_p<64, 16, 16><<<4096, 256, 0, stream>>>(part, a3, 2);

    // L4: fused LDS expansion + pre-summed weights (round-10 proven)
    prep_wnl4<<<108, 256, 0, stream>>>(bw4, sw4, ss4, wl4);
    kan_l4_v7<<<1024, 256, 0, stream>>>(a3, wl4, p4);
    reduce_tanh_l4_16<<<768, 256, 0, stream>>>(p4, (float*)d_out);
  } else {
    // round-1 proven fallback (needs ~16.3 MB)
    float* partOld = a3 + 1048576;
    linear_pack_kernel<<<512, 256, 0, stream>>>(x, lin_w, lin_b, h, nullptr, 0);
    kan_gemm<512, 256, 4, 4, 64, 8>
        <<<dim3(16, 4, 8), 256, 0, stream>>>(h, bw1, sw1, ss1, partOld);
    reduce_partials_old<256, 4, 4, 8><<<1024, 256, 0, stream>>>(partOld, a1);
    kan_gemm<256, 128, 8, 8, 64, 2>
        <<<dim3(64, 2, 2), 256, 0, stream>>>(a1, bw2, sw2, ss2, partOld);
    reduce_partials_old<128, 8, 8, 2><<<2048, 256, 0, stream>>>(partOld, a2);
    kan_gemm<128, 64, 16, 16, 64, 1>
        <<<dim3(256, 1, 1), 256, 0, stream>>>(a2, bw3, sw3, ss3, a3);
    kan_l4_split<<<1024, 256, 0, stream>>>(a3, bw4, sw4, ss4, partOld);
    reduce_tanh_l4<<<768, 256, 0, stream>>>(partOld, (float*)d_out);
  }
}

// Round 13
// 575.037 us; speedup vs baseline: 1.6046x; 1.0561x over previous
//
#include <hip/hip_runtime.h>
#include <cstdint>
#include <cmath>

#define BATCH 64

typedef __attribute__((ext_vector_type(8))) __bf16 bf16x8;
typedef __attribute__((ext_vector_type(16))) float f32x16;

// ---------------------------------------------------------------------------
// Spline + silu expansion: x -> [silu(x), B_0(x) .. B_7(x)]
// ---------------------------------------------------------------------------
__device__ __forceinline__ void expand9(float x, float* e) {
  float t = __expf(-x);
  e[0] = __fdividef(x, 1.f + t);  // silu
  float b[11];
#pragma unroll
  for (int j = 0; j < 11; ++j) {
    float gj  = 0.4f * (float)j - 2.2f;
    float gj1 = 0.4f * (float)(j + 1) - 2.2f;
    b[j] = (x >= gj && x < gj1) ? 1.f : 0.f;
  }
#pragma unroll
  for (int k = 1; k <= 3; ++k) {
    float inv = 1.f / (0.4f * (float)k);
#pragma unroll
    for (int j = 0; j < 11 - k; ++j) {
      float gj   = 0.4f * (float)j - 2.2f;
      float gjk1 = 0.4f * (float)(j + k + 1) - 2.2f;
      b[j] = ((x - gj) * b[j] + (gjk1 - x) * b[j + 1]) * inv;
    }
  }
#pragma unroll
  for (int v = 0; v < 8; ++v) e[v + 1] = b[v];
}

// bf16 split helpers (round-to-nearest-even)
__device__ __forceinline__ unsigned short f2bf(float x) {
  uint32_t u = __float_as_uint(x);
  uint32_t r = u + 0x7fffu + ((u >> 16) & 1u);
  return (unsigned short)(r >> 16);
}
__device__ __forceinline__ float bf2f(unsigned short h) {
  return __uint_as_float(((uint32_t)h) << 16);
}
__device__ __forceinline__ uint32_t packsplit(float x) {
  unsigned short hi = f2bf(x);
  unsigned short lo = f2bf(x - bf2f(hi));
  return (uint32_t)hi | ((uint32_t)lo << 16);
}

// ---------------------------------------------------------------------------
// h = relu(x @ lin_w^T + lin_b); also writes packed expansion E (main path)
// ---------------------------------------------------------------------------
__global__ __launch_bounds__(256) void linear_pack_kernel(
    const float* __restrict__ x, const float* __restrict__ w,
    const float* __restrict__ bias, float* __restrict__ h,
    uint32_t* __restrict__ E, int writeE) {
  int idx = blockIdx.x * 256 + threadIdx.x;  // 64*2048
  int b = idx >> 11, o = idx & 2047;
  const float* xr = x + b * 100;
  const float* wr = w + o * 100;
  float acc = bias[o];
#pragma unroll 4
  for (int k = 0; k < 100; ++k) acc += xr[k] * wr[k];
  float hv = fmaxf(acc, 0.f);
  h[idx] = hv;
  if (writeE) {
    float e[9];
    expand9(hv, e);
    uint32_t* p = E + (size_t)idx * 9;
#pragma unroll
    for (int v = 0; v < 9; ++v) p[v] = packsplit(e[v]);
  }
}

// ---------------------------------------------------------------------------
// Pack expanded weights into MFMA layout:
// Bg[kc][plane(hi=0,lo=1)][v(9)][n(N)][fl(16)]  (bf16)
// ---------------------------------------------------------------------------
template <int F, int N>
__global__ __launch_bounds__(256) void prep_bpack(
    const float* __restrict__ bw, const float* __restrict__ sw,
    const float* __restrict__ ss, unsigned short* __restrict__ Bg) {
  int idx = blockIdx.x * 256 + threadIdx.x;  // over (F/16)*9*N*16
  int fl = idx & 15;
  int n = (idx >> 4) & (N - 1);
  int rest = idx >> 4;
  rest /= N;
  int v = rest % 9;
  int kc = rest / 9;
  int f = kc * 16 + fl;
  size_t src = (size_t)n * F + f;
  float wv = (v == 0) ? bw[src] : sw[src * 8 + (v - 1)] * ss[src];
  unsigned short hi = f2bf(wv);
  unsigned short lo = f2bf(wv - bf2f(hi));
  size_t base = ((size_t)kc * 2 * 9 + v) * N * 16 + (size_t)n * 16 + fl;
  Bg[base] = hi;                          // plane 0
  Bg[base + (size_t)9 * N * 16] = lo;     // plane 1
}

// ---------------------------------------------------------------------------
// Split-bf16 MFMA GEMM, round 13: A staged in LDS (round-10 proven pattern);
// B read DIRECTLY from global in the v-loop — Bg's layout makes each lane's
// 16B fragment a coalesced global_load_dwordx4 (the wave touches a
// contiguous 1KB region; wm-duplicate waves hit L1; Bg is L3-resident).
// This removes the B LDS write AND B LDS reads: LDS traffic per chunk drops
// 220KB -> 110KB (the kernel was LDS-BW-bound), and LDS shrinks to 36.9KB
// so 3 blocks/CU fit (launch_bounds(256,3)) to hide B-load latency.
// ---------------------------------------------------------------------------
template <int CIN, int COUT, int HO, int WO, int SK>
__global__ __launch_bounds__(256, 3) void gemm_mfma(
    const uint32_t* __restrict__ E, const unsigned short* __restrict__ Bg,
    float* __restrict__ part) {
  constexpr int F = CIN * 9;
  constexpr int NKC = F / 16;
  constexpr int HI = HO / 2, WI = WO / 2;
  constexpr int M = BATCH * HO * WO;
  constexpr int CPB = NKC / SK;
  static_assert(NKC % SK == 0, "sk");

  __shared__ __align__(16) unsigned short lds[2 * 9216];  // A hi, A lo

  const int t = threadIdx.x;
  const int mbase = blockIdx.x * 64;
  const int nb = blockIdx.y;
  const int kc0 = blockIdx.z * CPB;

  uint32_t ez[9];
  {
    float e0[9];
    expand9(0.f, e0);
#pragma unroll
    for (int v = 0; v < 9; ++v) ez[v] = packsplit(e0[v]);
  }

  const int lane = t & 63, wv_ = t >> 6;
  const int wm = wv_ >> 1, wn = wv_ & 1;
  const int frow = lane & 31, fkg = lane >> 5;
  const int aoff = ((wm * 32 + frow) * 16 + fkg * 8) * 2;  // bytes

  // B column base for this lane (ushort units); per (kc, pl, v) add strides.
  const unsigned short* bcol =
      Bg + (size_t)(nb * 64 + wn * 32 + frow) * 16 + fkg * 8;

  f32x16 acc;
#pragma unroll
  for (int i = 0; i < 16; ++i) acc[i] = 0.f;

  for (int ci = 0; ci < CPB; ++ci) {
    const int kc = kc0 + ci;
    __syncthreads();

    // ---- stage A: 64 m x 16 fl (round-10 proven pattern) ----
#pragma unroll
    for (int i = 0; i < 4; ++i) {
      int task = i * 256 + t;
      int ml = task >> 4, fl = task & 15;
      int f = kc * 16 + fl;
      int c = f / 9, r = f - 9 * c;
      int kh = r / 3, kw = r - kh * 3;
      int m = mbase + ml;
      int b = m / (HO * WO), hw2 = m % (HO * WO);
      int hh = hw2 / WO, ww = hw2 % WO;
      int hp = hh + kh - 1, wp = ww + kw - 1;
      bool ok = (unsigned)hp < (unsigned)HO && (unsigned)wp < (unsigned)WO;
      uint32_t uv[9];
      if (ok) {
        const uint32_t* ep =
            E + (size_t)(((b * CIN + c) * HI + (hp >> 1)) * WI + (wp >> 1)) * 9;
#pragma unroll
        for (int v = 0; v < 9; ++v) uv[v] = ep[v];
      } else {
#pragma unroll
        for (int v = 0; v < 9; ++v) uv[v] = ez[v];
      }
      int base = ml * 16 + fl;
#pragma unroll
      for (int v = 0; v < 9; ++v) {
        lds[v * 1024 + base] = (unsigned short)(uv[v] & 0xffffu);
        lds[9216 + v * 1024 + base] = (unsigned short)(uv[v] >> 16);
      }
    }
    __syncthreads();

    // ---- compute: 9 v-steps x 3 split-products; B direct from global ----
    const unsigned short* bk = bcol + (size_t)kc * (2 * 9 * COUT * 16);
#pragma unroll
    for (int v = 0; v < 9; ++v) {
      const char* lbc = reinterpret_cast<const char*>(lds);
      bf16x8 ah = *reinterpret_cast<const bf16x8*>(lbc + v * 2048 + aoff);
      bf16x8 al =
          *reinterpret_cast<const bf16x8*>(lbc + 18432 + v * 2048 + aoff);
      bf16x8 bh = *reinterpret_cast<const bf16x8*>(bk + (size_t)v * COUT * 16);
      bf16x8 bl =
          *reinterpret_cast<const bf16x8*>(bk + (size_t)(9 + v) * COUT * 16);
      acc = __builtin_amdgcn_mfma_f32_32x32x16_bf16(ah, bh, acc, 0, 0, 0);
      acc = __builtin_amdgcn_mfma_f32_32x32x16_bf16(ah, bl, acc, 0, 0, 0);
      acc = __builtin_amdgcn_mfma_f32_32x32x16_bf16(al, bh, acc, 0, 0, 0);
    }
  }

  // ---- epilogue: C/D layout col=lane&31, row=(reg&3)+8*(reg>>2)+4*(lane>>5)
  float* p = part + (size_t)blockIdx.z * M * COUT;
  const int gn = nb * 64 + wn * 32 + frow;
#pragma unroll
  for (int r = 0; r < 16; ++r) {
    int mlocal = (r & 3) + 8 * (r >> 2) + 4 * fkg;
    int gm = mbase + wm * 32 + mlocal;
    p[(size_t)gm * COUT + gn] = acc[r];
  }
}

// ---------------------------------------------------------------------------
template <int COUT, int HO, int WO>
__global__ __launch_bounds__(256) void reduce_pe_pack(
    const float* __restrict__ part, uint32_t* __restrict__ E, int SK) {
  constexpr int M = BATCH * HO * WO;
  int idx = blockIdx.x * 256 + threadIdx.x;
  int ww = idx % WO;
  int tmp = idx / WO;
  int hh = tmp % HO;
  tmp /= HO;
  int o = tmp % COUT;
  int b = tmp / COUT;
  int m = (b * HO + hh) * WO + ww;
  float s = 0.f;
  for (int k = 0; k < SK; ++k) s += part[((size_t)k * M + m) * COUT + o];
  float e[9];
  expand9(s, e);
  uint32_t* p = E + (size_t)idx * 9;
#pragma unroll
  for (int v = 0; v < 9; ++v) p[v] = packsplit(e[v]);
}

template <int COUT, int HO, int WO>
__global__ __launch_bounds__(256) void reduce_p(
    const float* __restrict__ part, float* __restrict__ act, int SK) {
  constexpr int M = BATCH * HO * WO;
  int idx = blockIdx.x * 256 + threadIdx.x;
  int ww = idx % WO;
  int tmp = idx / WO;
  int hh = tmp % HO;
  tmp /= HO;
  int o = tmp % COUT;
  int b = tmp / COUT;
  int m = (b * HO + hh) * WO + ww;
  float s = 0.f;
  for (int k = 0; k < SK; ++k) s += part[((size_t)k * M + m) * COUT + o];
  act[idx] = s;
}

// ---------------------------------------------------------------------------
// L4 weights, neighbor-pre-summed:
// Wn[c][pc][nb][v][o] = sum over taps mapping to neighbor nb under parity pc.
// ---------------------------------------------------------------------------
__global__ __launch_bounds__(256) void prep_wnl4(
    const float* __restrict__ bw, const float* __restrict__ sw,
    const float* __restrict__ ss, float* __restrict__ Wn) {
  int idx = blockIdx.x * 256 + threadIdx.x;  // 64*4*4*27 = 27648
  if (idx >= 27648) return;
  int u = idx % 27;
  int o = u % 3, v = u / 3;
  int rest = idx / 27;
  int nb = rest & 3;
  rest >>= 2;
  int pc = rest & 3;
  rest >>= 2;
  int c = rest;  // 0..63
  int PH = pc >> 1, PW = pc & 1;
  int a = nb >> 1, b2 = nb & 1;
  float s = 0.f;
#pragma unroll
  for (int kh = 0; kh < 3; ++kh) {
    if (((kh > PH) ? 1 : 0) != a) continue;
#pragma unroll
    for (int kw = 0; kw < 3; ++kw) {
      if (((kw > PW) ? 1 : 0) != b2) continue;
      int f = c * 9 + kh * 3 + kw;
      float wv = (v == 0)
                     ? bw[o * 576 + f]
                     : sw[((size_t)(o * 576 + f)) * 8 + (v - 1)] * ss[o * 576 + f];
      s += wv;
    }
  }
  Wn[idx] = s;
}

// ---------------------------------------------------------------------------
// L4 v7 (round-10 proven): spill-free skeleton + pre-summed weights.
// ---------------------------------------------------------------------------
template <int PH, int PW>
__device__ void l4v7_wave(const float* __restrict__ eLds,
                          const float* __restrict__ WnB,
                          const float* __restrict__ ez, int lane, int bb,
                          int cs, float* __restrict__ p4) {
  constexpr int PC = PH * 2 + PW;
  const int j = lane & 15;
  const int i0 = (lane >> 4) << 2;
#pragma unroll 1
  for (int q = 0; q < 4; ++q) {
    const int i = i0 + q;
    float acc[3] = {0.f, 0.f, 0.f};
#pragma unroll
    for (int a = 0; a < 2; ++a) {
      const int gi = i + PH - 1 + a;
      const bool vr = (unsigned)gi < 16u;
#pragma unroll
      for (int b2 = 0; b2 < 2; ++b2) {
        const int gj = j + PW - 1 + b2;
        const bool ok = vr && ((unsigned)gj < 16u);
        const int pp = ok ? (gi * 16 + gj) : 0;  // clamped safe address
        const int nbi = a * 2 + b2;
#pragma unroll
        for (int cl = 0; cl < 4; ++cl) {
          const float* ep = eLds + cl * 2304 + pp * 9;
          float en[9];
#pragma unroll
          for (int v = 0; v < 9; ++v) en[v] = ok ? ep[v] : ez[v];
          const float* wp = WnB + ((cl * 4 + PC) * 4 + nbi) * 27;
#pragma unroll
          for (int v = 0; v < 9; ++v) {
            acc[0] = fmaf(en[v], wp[v * 3 + 0], acc[0]);
            acc[1] = fmaf(en[v], wp[v * 3 + 1], acc[1]);
            acc[2] = fmaf(en[v], wp[v * 3 + 2], acc[2]);
          }
        }
      }
    }
    const int h = (i << 1) + PH, w = (j << 1) + PW;
#pragma unroll
    for (int o = 0; o < 3; ++o)
      p4[(size_t)cs * 196608 + ((bb * 3 + o) << 10) + (h << 5) + w] = acc[o];
  }
}

__global__ __launch_bounds__(256) void kan_l4_v7(
    const float* __restrict__ a3, const float* __restrict__ Wn,
    float* __restrict__ p4) {
  __shared__ float eLds[4 * 256 * 9];  // 36.9 KB
  const int bid = blockIdx.x;          // 64 bb x 16 cs
  const int bb = bid >> 4, cs = bid & 15;
  const int t = threadIdx.x;
  float ez[9];
  expand9(0.f, ez);
#pragma unroll
  for (int cl = 0; cl < 4; ++cl) {
    float x = a3[(size_t)(bb * 64 + cs * 4 + cl) * 256 + t];
    float ev[9];
    expand9(x, ev);
#pragma unroll
    for (int v = 0; v < 9; ++v) eLds[(cl * 256 + t) * 9 + v] = ev[v];
  }
  __syncthreads();
  const int wv_ = t >> 6, lane = t & 63;
  const float* WnB = Wn + (size_t)cs * 4 * (4 * 4 * 27);
  if (wv_ == 0)
    l4v7_wave<0, 0>(eLds, WnB, ez, lane, bb, cs, p4);
  else if (wv_ == 1)
    l4v7_wave<0, 1>(eLds, WnB, ez, lane, bb, cs, p4);
  else if (wv_ == 2)
    l4v7_wave<1, 0>(eLds, WnB, ez, lane, bb, cs, p4);
  else
    l4v7_wave<1, 1>(eLds, WnB, ez, lane, bb, cs, p4);
}

__global__ __launch_bounds__(256) void reduce_tanh_l4_16(
    const float* __restrict__ p4, float* __restrict__ out) {
  int i = blockIdx.x * 256 + threadIdx.x;  // 196608
  float s = 0.f;
#pragma unroll
  for (int k = 0; k < 16; ++k) s += p4[(size_t)k * 196608 + i];
  out[i] = tanhf(s);
}

__global__ __launch_bounds__(256) void reduce_tanh_l4(
    const float* __restrict__ p4, float* __restrict__ out) {
  int i = blockIdx.x * 256 + threadIdx.x;
  float s = p4[i] + p4[i + 196608] + p4[i + 2 * 196608] + p4[i + 3 * 196608];
  out[i] = tanhf(s);
}

// ---------------------------------------------------------------------------
// Fallback path (round-1 proven) for small workspace
// ---------------------------------------------------------------------------
template <int CIN, int COUT, int HO, int WO, int BN, int SK>
__global__ __launch_bounds__(256) void kan_gemm(
    const float* __restrict__ in, const float* __restrict__ bw,
    const float* __restrict__ sw, const float* __restrict__ ss,
    float* __restrict__ outp) {
  constexpr int BM = 64, TM = 4, TN = 4, FC = 16;
  constexpr int F = CIN * 9;
  constexpr int HI = HO / 2, WI = WO / 2;
  constexpr int M = BATCH * HO * WO;
  constexpr int FPB = F / SK;

  __shared__ float Ae[FC * 9][BM];

  const int t = threadIdx.x;
  const int mbase = blockIdx.x * BM;
  const int obase = blockIdx.y * BN;
  const int f0 = blockIdx.z * FPB;

  const int cg = t & (BN / TN - 1);
  const int rg = t / (BN / TN);
  const int m0 = rg * TM;
  const int o0 = obase + cg * TN;

  float acc[TM][TN] = {};

  for (int fc = f0; fc < f0 + FPB; fc += FC) {
#pragma unroll
    for (int j = 0; j < BM * FC / 256; ++j) {
      int p = j * 256 + t;
      int ml = p & (BM - 1);
      int df = p >> 6;
      int f = fc + df;
      int c = f / 9;
      int r = f - c * 9;
      int kh = r / 3, kw = r - kh * 3;
      int m = mbase + ml;
      int bb = m / (HO * WO);
      int rem = m % (HO * WO);
      int hh = rem / WO, ww = rem % WO;
      int hp = hh + kh - 1, wp = ww + kw - 1;
      float val = 0.f;
      if (hp >= 0 && hp < HO && wp >= 0 && wp < WO)
        val = in[((bb * CIN + c) * HI + (hp >> 1)) * WI + (wp >> 1)];
      float e[9];
      expand9(val, e);
#pragma unroll
      for (int v = 0; v < 9; ++v) Ae[df * 9 + v][ml] = e[v];
    }
    __syncthreads();

#pragma unroll 2
    for (int df = 0; df < FC; ++df) {
      int f = fc + df;
      float wb[TN], wsv[TN][8];
#pragma unroll
      for (int tn = 0; tn < TN; ++tn) {
        int i = (o0 + tn) * F + f;
        wb[tn] = bw[i];
        float sc = ss[i];
        const float4* sp = reinterpret_cast<const float4*>(sw + (size_t)i * 8);
        float4 s0 = sp[0], s1 = sp[1];
        wsv[tn][0] = s0.x * sc; wsv[tn][1] = s0.y * sc;
        wsv[tn][2] = s0.z * sc; wsv[tn][3] = s0.w * sc;
        wsv[tn][4] = s1.x * sc; wsv[tn][5] = s1.y * sc;
        wsv[tn][6] = s1.z * sc; wsv[tn][7] = s1.w * sc;
      }
      float a[9][TM];
#pragma unroll
      for (int v = 0; v < 9; ++v) {
        float4 q = *reinterpret_cast<const float4*>(&Ae[df * 9 + v][m0]);
        a[v][0] = q.x; a[v][1] = q.y; a[v][2] = q.z; a[v][3] = q.w;
      }
#pragma unroll
      for (int tm = 0; tm < TM; ++tm)
#pragma unroll
        for (int tn = 0; tn < TN; ++tn) acc[tm][tn] += a[0][tm] * wb[tn];
#pragma unroll
      for (int v = 1; v < 9; ++v)
#pragma unroll
        for (int tm = 0; tm < TM; ++tm)
#pragma unroll
          for (int tn = 0; tn < TN; ++tn)
            acc[tm][tn] += a[v][tm] * wsv[tn][v - 1];
    }
    __syncthreads();
  }

  if constexpr (SK > 1) {
    float* p = outp + (size_t)blockIdx.z * M * COUT;
#pragma unroll
    for (int tm = 0; tm < TM; ++tm) {
      int m = mbase + m0 + tm;
#pragma unroll
      for (int tn = 0; tn < TN; ++tn)
        p[(size_t)m * COUT + (o0 + tn)] = acc[tm][tn];
    }
  } else {
#pragma unroll
    for (int tm = 0; tm < TM; ++tm) {
      int m = mbase + m0 + tm;
      int bb = m / (HO * WO);
      int rem = m % (HO * WO);
      int hh = rem / WO, ww = rem % WO;
#pragma unroll
      for (int tn = 0; tn < TN; ++tn) {
        int o = o0 + tn;
        outp[((bb * COUT + o) * HO + hh) * WO + ww] = acc[tm][tn];
      }
    }
  }
}

template <int COUT, int HO, int WO, int SK>
__global__ __launch_bounds__(256) void reduce_partials_old(
    const float* __restrict__ part, float* __restrict__ act) {
  constexpr int M = BATCH * HO * WO;
  int idx = blockIdx.x * 256 + threadIdx.x;
  if (idx >= M * COUT) return;
  float s = 0.f;
#pragma unroll
  for (int k = 0; k < SK; ++k) s += part[(size_t)k * M * COUT + idx];
  int m = idx / COUT, o = idx - (idx / COUT) * COUT;
  int bb = m / (HO * WO);
  int rem = m % (HO * WO);
  int hh = rem / WO, ww = rem % WO;
  act[((bb * COUT + o) * HO + hh) * WO + ww] = s;
}

__global__ __launch_bounds__(256) void kan_l4_split(
    const float* __restrict__ a3, const float* __restrict__ bw,
    const float* __restrict__ sw, const float* __restrict__ ss,
    float* __restrict__ p4) {
  int tid = blockIdx.x * 256 + threadIdx.x;
  int cs = tid >> 16, pix = tid & 65535;
  int b = pix >> 10, rem = pix & 1023, h = rem >> 5, w = rem & 31;
  float acc[3] = {0.f, 0.f, 0.f};
  for (int c = cs * 16; c < cs * 16 + 16; ++c) {
#pragma unroll
    for (int kh = 0; kh < 3; ++kh) {
#pragma unroll
      for (int kw = 0; kw < 3; ++kw) {
        int f = (c * 3 + kh) * 3 + kw;
        int hp = h + kh - 1, wp = w + kw - 1;
        float x = 0.f;
        if ((unsigned)hp < 32u && (unsigned)wp < 32u)
          x = a3[((b * 64 + c) * 16 + (hp >> 1)) * 16 + (wp >> 1)];
        float e[9];
        expand9(x, e);
#pragma unroll
        for (int o = 0; o < 3; ++o) {
          int i = o * 576 + f;
          float d = e[1] * sw[i * 8 + 0];
#pragma unroll
          for (int v = 1; v < 8; ++v) d += e[v + 1] * sw[i * 8 + v];
          acc[o] += e[0] * bw[i] + d * ss[i];
        }
      }
    }
  }
#pragma unroll
  for (int o = 0; o < 3; ++o)
    p4[cs * 196608 + ((b * 3 + o) << 10) + (h << 5) + w] = acc[o];
}

// ---------------------------------------------------------------------------
extern "C" void kernel_launch(void* const* d_in, const int* in_sizes, int n_in,
                              void* d_out, int out_size, void* d_ws,
                              size_t ws_size, hipStream_t stream) {
  const float* x     = (const float*)d_in[0];
  const float* lin_w = (const float*)d_in[1];
  const float* lin_b = (const float*)d_in[2];
  const float* bw1 = (const float*)d_in[3];
  const float* sw1 = (const float*)d_in[4];
  const float* ss1 = (const float*)d_in[5];
  const float* bw2 = (const float*)d_in[6];
  const float* sw2 = (const float*)d_in[7];
  const float* ss2 = (const float*)d_in[8];
  const float* bw3 = (const float*)d_in[9];
  const float* sw3 = (const float*)d_in[10];
  const float* ss3 = (const float*)d_in[11];
  const float* bw4 = (const float*)d_in[12];
  const float* sw4 = (const float*)d_in[13];
  const float* ss4 = (const float*)d_in[14];

  float* wsf = (float*)d_ws;
  float* h  = wsf;                        // 131072
  float* a1 = h + 131072;                 // 262144 (fallback only)
  float* a2 = a1 + 262144;                // 524288 (fallback only)
  float* a3 = a2 + 524288;                // 1048576, ends at 1966080
  // main-path regions
  unsigned short* Bg = (unsigned short*)(wsf + 1966080);  // 10,616,832 float-slots
  float* part = wsf + 1966080 + 10616832;                 // 2,097,152
  uint32_t* Eg = (uint32_t*)(wsf + 14680064);             // 4,718,592
  float* wl4 = h;                    // h dead on main path after linear (27648 floats)
  float* p4  = wsf + 1966080;        // 16*196608 = 3.1M, reuses Bg (dead post-L3)

  const size_t baseFloats = 1966080;
  size_t availFloats = ws_size / 4 > baseFloats ? ws_size / 4 - baseFloats : 0;
  const size_t mainNeed = 10616832ull + 2097152ull + 4718592ull;  // 17.4M

  if (availFloats >= mainNeed) {
    linear_pack_kernel<<<512, 256, 0, stream>>>(x, lin_w, lin_b, h, Eg, 1);

    // L1: CIN=512 COUT=256 4x4, SK=8
    prep_bpack<4608, 256><<<41472, 256, 0, stream>>>(bw1, sw1, ss1, Bg);
    gemm_mfma<512, 256, 4, 4, 8>
        <<<dim3(16, 4, 8), 256, 0, stream>>>(Eg, Bg, part);
    reduce_pe_pack<256, 4, 4><<<1024, 256, 0, stream>>>(part, Eg, 8);

    // L2: CIN=256 COUT=128 8x8, SK=4
    prep_bpack<2304, 128><<<10368, 256, 0, stream>>>(bw2, sw2, ss2, Bg);
    gemm_mfma<256, 128, 8, 8, 4>
        <<<dim3(64, 2, 4), 256, 0, stream>>>(Eg, Bg, part);
    reduce_pe_pack<128, 8, 8><<<2048, 256, 0, stream>>>(part, Eg, 4);

    // L3: CIN=128 COUT=64 16x16, SK=2
    prep_bpack<1152, 64><<<2592, 256, 0, stream>>>(bw3, sw3, ss3, Bg);
    gemm_mfma<128, 64, 16, 16, 2>
        <<<dim3(256, 1, 2), 256, 0, stream>>>(Eg, Bg, part);
    reduce_p<64, 16, 16><<<4096, 256, 0, stream>>>(part, a3, 2);

    // L4: fused LDS expansion + pre-summed weights (round-10 proven)
    prep_wnl4<<<108, 256, 0, stream>>>(bw4, sw4, ss4, wl4);
    kan_l4_v7<<<1024, 256, 0, stream>>>(a3, wl4, p4);
    reduce_tanh_l4_16<<<768, 256, 0, stream>>>(p4, (float*)d_out);
  } else {
    // round-1 proven fallback (needs ~16.3 MB)
    float* partOld = a3 + 1048576;
    linear_pack_kernel<<<512, 256, 0, stream>>>(x, lin_w, lin_b, h, nullptr, 0);
    kan_gemm<512, 256, 4, 4, 64, 8>
        <<<dim3(16, 4, 8), 256, 0, stream>>>(h, bw1, sw1, ss1, partOld);
    reduce_partials_old<256, 4, 4, 8><<<1024, 256, 0, stream>>>(partOld, a1);
    kan_gemm<256, 128, 8, 8, 64, 2>
        <<<dim3(64, 2, 2), 256, 0, stream>>>(a1, bw2, sw2, ss2, partOld);
    reduce_partials_old<128, 8, 8, 2><<<2048, 256, 0, stream>>>(partOld, a2);
    kan_gemm<128, 64, 16, 16, 64, 1>
        <<<dim3(256, 1, 1), 256, 0, stream>>>(a2, bw3, sw3, ss3, a3);
    kan_l4_split<<<1024, 256, 0, stream>>>(a3, bw4, sw4, ss4, partOld);
    reduce_tanh_l4<<<768, 256, 0, stream>>>(partOld, (float*)d_out);
  }
}

// Round 14
// 478.053 us; speedup vs baseline: 1.9301x; 1.2029x over previous
//
#include <hip/hip_runtime.h>
#include <cstdint>
#include <cmath>

#define BATCH 64

typedef __attribute__((ext_vector_type(8))) __bf16 bf16x8;
typedef __attribute__((ext_vector_type(16))) float f32x16;

// ---------------------------------------------------------------------------
// Spline + silu expansion: x -> [silu(x), B_0(x) .. B_7(x)]
// ---------------------------------------------------------------------------
__device__ __forceinline__ void expand9(float x, float* e) {
  float t = __expf(-x);
  e[0] = __fdividef(x, 1.f + t);  // silu
  float b[11];
#pragma unroll
  for (int j = 0; j < 11; ++j) {
    float gj  = 0.4f * (float)j - 2.2f;
    float gj1 = 0.4f * (float)(j + 1) - 2.2f;
    b[j] = (x >= gj && x < gj1) ? 1.f : 0.f;
  }
#pragma unroll
  for (int k = 1; k <= 3; ++k) {
    float inv = 1.f / (0.4f * (float)k);
#pragma unroll
    for (int j = 0; j < 11 - k; ++j) {
      float gj   = 0.4f * (float)j - 2.2f;
      float gjk1 = 0.4f * (float)(j + k + 1) - 2.2f;
      b[j] = ((x - gj) * b[j] + (gjk1 - x) * b[j + 1]) * inv;
    }
  }
#pragma unroll
  for (int v = 0; v < 8; ++v) e[v + 1] = b[v];
}

// bf16 split helpers (round-to-nearest-even)
__device__ __forceinline__ unsigned short f2bf(float x) {
  uint32_t u = __float_as_uint(x);
  uint32_t r = u + 0x7fffu + ((u >> 16) & 1u);
  return (unsigned short)(r >> 16);
}
__device__ __forceinline__ float bf2f(unsigned short h) {
  return __uint_as_float(((uint32_t)h) << 16);
}
__device__ __forceinline__ uint32_t packsplit(float x) {
  unsigned short hi = f2bf(x);
  unsigned short lo = f2bf(x - bf2f(hi));
  return (uint32_t)hi | ((uint32_t)lo << 16);
}

// ---------------------------------------------------------------------------
// h = relu(x @ lin_w^T + lin_b); also writes packed expansion E (main path)
// ---------------------------------------------------------------------------
__global__ __launch_bounds__(256) void linear_pack_kernel(
    const float* __restrict__ x, const float* __restrict__ w,
    const float* __restrict__ bias, float* __restrict__ h,
    uint32_t* __restrict__ E, int writeE) {
  int idx = blockIdx.x * 256 + threadIdx.x;  // 64*2048
  int b = idx >> 11, o = idx & 2047;
  const float* xr = x + b * 100;
  const float* wr = w + o * 100;
  float acc = bias[o];
#pragma unroll 4
  for (int k = 0; k < 100; ++k) acc += xr[k] * wr[k];
  float hv = fmaxf(acc, 0.f);
  h[idx] = hv;
  if (writeE) {
    float e[9];
    expand9(hv, e);
    uint32_t* p = E + (size_t)idx * 9;
#pragma unroll
    for (int v = 0; v < 9; ++v) p[v] = packsplit(e[v]);
  }
}

// ---------------------------------------------------------------------------
// Pack expanded weights into MFMA-staging layout:
// Bg[kc][plane(hi=0,lo=1)][v(9)][n(N)][fl(16)]  (bf16)
// ---------------------------------------------------------------------------
template <int F, int N>
__global__ __launch_bounds__(256) void prep_bpack(
    const float* __restrict__ bw, const float* __restrict__ sw,
    const float* __restrict__ ss, unsigned short* __restrict__ Bg) {
  int idx = blockIdx.x * 256 + threadIdx.x;  // over (F/16)*9*N*16
  int fl = idx & 15;
  int n = (idx >> 4) & (N - 1);
  int rest = idx >> 4;
  rest /= N;
  int v = rest % 9;
  int kc = rest / 9;
  int f = kc * 16 + fl;
  size_t src = (size_t)n * F + f;
  float wv = (v == 0) ? bw[src] : sw[src * 8 + (v - 1)] * ss[src];
  unsigned short hi = f2bf(wv);
  unsigned short lo = f2bf(wv - bf2f(hi));
  size_t base = ((size_t)kc * 2 * 9 + v) * N * 16 + (size_t)n * 16 + fl;
  Bg[base] = hi;                          // plane 0
  Bg[base + (size_t)9 * N * 16] = lo;     // plane 1
}

// ---------------------------------------------------------------------------
// Split-bf16 MFMA GEMM — round-10 proven structure. Round-14 change (ONLY):
// A-staging task = (ml = t>>2, 4 consecutive fl); bulk ok-predicated loads
// into phase-local named arrays; pack hi/lo pairs -> 18 ds_write_b64 per
// thread per chunk (was 72 ds_write_u16). Write addresses are lane-contiguous
// (512B/wave-instr) — data-limited, no conflicts. Pack arithmetic proven
// correct in round 12's passing bench. Everything else byte-identical.
// ---------------------------------------------------------------------------
template <int CIN, int COUT, int HO, int WO, int SK>
__global__ __launch_bounds__(256, 2) void gemm_mfma(
    const uint32_t* __restrict__ E, const unsigned short* __restrict__ Bg,
    float* __restrict__ part) {
  constexpr int F = CIN * 9;
  constexpr int NKC = F / 16;
  constexpr int HI = HO / 2, WI = WO / 2;
  constexpr int M = BATCH * HO * WO;
  constexpr int CPB = NKC / SK;
  static_assert(NKC % SK == 0, "sk");

  __shared__ __align__(16) unsigned short lds[4 * 9216];

  const int t = threadIdx.x;
  const int mbase = blockIdx.x * 64;
  const int nb = blockIdx.y;
  const int kc0 = blockIdx.z * CPB;

  uint32_t ez[9];
  {
    float e0[9];
    expand9(0.f, e0);
#pragma unroll
    for (int v = 0; v < 9; ++v) ez[v] = packsplit(e0[v]);
  }

  const int lane = t & 63, wv_ = t >> 6;
  const int wm = wv_ >> 1, wn = wv_ & 1;
  const int frow = lane & 31, fkg = lane >> 5;
  const int aoff = ((wm * 32 + frow) * 16 + fkg * 8) * 2;  // bytes
  const int boff = ((wn * 32 + frow) * 16 + fkg * 8) * 2;

  // A-staging geometry (round-14): thread covers row aml, fl = flq*4..+3
  const int aml = t >> 2, flq = t & 3;
  const int am = mbase + aml;
  const int ab = am / (HO * WO), ahw = am % (HO * WO);
  const int ahh = ahw / WO, aww = ahw % WO;

  f32x16 acc;
#pragma unroll
  for (int i = 0; i < 16; ++i) acc[i] = 0.f;

  for (int ci = 0; ci < CPB; ++ci) {
    const int kc = kc0 + ci;
    __syncthreads();

    // ---- stage A: 4 consecutive fl per thread, 18 b64 writes ----
    {
      uint32_t w0[9], w1[9], w2[9], w3[9];
#define LDTAP(IDX, DST)                                                       \
  {                                                                           \
    int f = kc * 16 + flq * 4 + IDX;                                          \
    int c = f / 9, r = f - 9 * c;                                             \
    int kh = r / 3, kw = r - kh * 3;                                          \
    int hp = ahh + kh - 1, wp = aww + kw - 1;                                 \
    if ((unsigned)hp < (unsigned)HO && (unsigned)wp < (unsigned)WO) {         \
      const uint32_t* ep =                                                    \
          E + (size_t)(((ab * CIN + c) * HI + (hp >> 1)) * WI + (wp >> 1)) *  \
                  9;                                                          \
      _Pragma("unroll") for (int v = 0; v < 9; ++v) DST[v] = ep[v];           \
    } else {                                                                  \
      _Pragma("unroll") for (int v = 0; v < 9; ++v) DST[v] = ez[v];           \
    }                                                                         \
  }
      LDTAP(0, w0)
      LDTAP(1, w1)
      LDTAP(2, w2)
      LDTAP(3, w3)
#undef LDTAP
      char* lb = reinterpret_cast<char*>(lds);
#pragma unroll
      for (int v = 0; v < 9; ++v) {
        uint32_t hi01 = (w0[v] & 0xffffu) | (w1[v] << 16);
        uint32_t hi23 = (w2[v] & 0xffffu) | (w3[v] << 16);
        uint32_t lo01 = (w0[v] >> 16) | (w1[v] & 0xffff0000u);
        uint32_t lo23 = (w2[v] >> 16) | (w3[v] & 0xffff0000u);
        *reinterpret_cast<uint2*>(lb + v * 2048 + aml * 32 + flq * 8) =
            make_uint2(hi01, hi23);
        *reinterpret_cast<uint2*>(lb + 18432 + v * 2048 + aml * 32 + flq * 8) =
            make_uint2(lo01, lo23);
      }
    }

    // ---- stage B: linear copy (round-10 proven) ----
    {
      const unsigned short* bsrc = Bg + (size_t)kc * (2 * 9 * COUT * 16);
#pragma unroll
      for (int g = 0; g < 9; ++g) {
        int u = g * 256 + t;
        int pl = (u >= 1152) ? 1 : 0;
        int rr = u - pl * 1152;
        int v = rr >> 7, q = rr & 127;
        int nl = q >> 1, half = q & 1;
        size_t srcE = (size_t)pl * (9 * COUT * 16) + (size_t)v * (COUT * 16) +
                      (size_t)(nb * 64 + nl) * 16 + half * 8;
        int dst = (2 + pl) * 9216 + v * 1024 + nl * 16 + half * 8;
        *reinterpret_cast<float4*>(&lds[dst]) =
            *reinterpret_cast<const float4*>(&bsrc[srcE]);
      }
    }
    __syncthreads();

    // ---- compute: 9 v-steps x 3 split-products ----
#pragma unroll
    for (int v = 0; v < 9; ++v) {
      const char* lbc = reinterpret_cast<const char*>(lds);
      bf16x8 ah = *reinterpret_cast<const bf16x8*>(lbc + v * 2048 + aoff);
      bf16x8 al =
          *reinterpret_cast<const bf16x8*>(lbc + 18432 + v * 2048 + aoff);
      bf16x8 bh =
          *reinterpret_cast<const bf16x8*>(lbc + 36864 + v * 2048 + boff);
      bf16x8 bl =
          *reinterpret_cast<const bf16x8*>(lbc + 55296 + v * 2048 + boff);
      acc = __builtin_amdgcn_mfma_f32_32x32x16_bf16(ah, bh, acc, 0, 0, 0);
      acc = __builtin_amdgcn_mfma_f32_32x32x16_bf16(ah, bl, acc, 0, 0, 0);
      acc = __builtin_amdgcn_mfma_f32_32x32x16_bf16(al, bh, acc, 0, 0, 0);
    }
  }

  // ---- epilogue: C/D layout col=lane&31, row=(reg&3)+8*(reg>>2)+4*(lane>>5)
  float* p = part + (size_t)blockIdx.z * M * COUT;
  const int gn = nb * 64 + wn * 32 + frow;
#pragma unroll
  for (int r = 0; r < 16; ++r) {
    int mlocal = (r & 3) + 8 * (r >> 2) + 4 * fkg;
    int gm = mbase + wm * 32 + mlocal;
    p[(size_t)gm * COUT + gn] = acc[r];
  }
}

// ---------------------------------------------------------------------------
template <int COUT, int HO, int WO>
__global__ __launch_bounds__(256) void reduce_pe_pack(
    const float* __restrict__ part, uint32_t* __restrict__ E, int SK) {
  constexpr int M = BATCH * HO * WO;
  int idx = blockIdx.x * 256 + threadIdx.x;
  int ww = idx % WO;
  int tmp = idx / WO;
  int hh = tmp % HO;
  tmp /= HO;
  int o = tmp % COUT;
  int b = tmp / COUT;
  int m = (b * HO + hh) * WO + ww;
  float s = 0.f;
  for (int k = 0; k < SK; ++k) s += part[((size_t)k * M + m) * COUT + o];
  float e[9];
  expand9(s, e);
  uint32_t* p = E + (size_t)idx * 9;
#pragma unroll
  for (int v = 0; v < 9; ++v) p[v] = packsplit(e[v]);
}

template <int COUT, int HO, int WO>
__global__ __launch_bounds__(256) void reduce_p(
    const float* __restrict__ part, float* __restrict__ act, int SK) {
  constexpr int M = BATCH * HO * WO;
  int idx = blockIdx.x * 256 + threadIdx.x;
  int ww = idx % WO;
  int tmp = idx / WO;
  int hh = tmp % HO;
  tmp /= HO;
  int o = tmp % COUT;
  int b = tmp / COUT;
  int m = (b * HO + hh) * WO + ww;
  float s = 0.f;
  for (int k = 0; k < SK; ++k) s += part[((size_t)k * M + m) * COUT + o];
  act[idx] = s;
}

// ---------------------------------------------------------------------------
// L4 weights, neighbor-pre-summed:
// Wn[c][pc][nb][v][o] = sum over taps mapping to neighbor nb under parity pc.
// ---------------------------------------------------------------------------
__global__ __launch_bounds__(256) void prep_wnl4(
    const float* __restrict__ bw, const float* __restrict__ sw,
    const float* __restrict__ ss, float* __restrict__ Wn) {
  int idx = blockIdx.x * 256 + threadIdx.x;  // 64*4*4*27 = 27648
  if (idx >= 27648) return;
  int u = idx % 27;
  int o = u % 3, v = u / 3;
  int rest = idx / 27;
  int nb = rest & 3;
  rest >>= 2;
  int pc = rest & 3;
  rest >>= 2;
  int c = rest;  // 0..63
  int PH = pc >> 1, PW = pc & 1;
  int a = nb >> 1, b2 = nb & 1;
  float s = 0.f;
#pragma unroll
  for (int kh = 0; kh < 3; ++kh) {
    if (((kh > PH) ? 1 : 0) != a) continue;
#pragma unroll
    for (int kw = 0; kw < 3; ++kw) {
      if (((kw > PW) ? 1 : 0) != b2) continue;
      int f = c * 9 + kh * 3 + kw;
      float wv = (v == 0)
                     ? bw[o * 576 + f]
                     : sw[((size_t)(o * 576 + f)) * 8 + (v - 1)] * ss[o * 576 + f];
      s += wv;
    }
  }
  Wn[idx] = s;
}

// ---------------------------------------------------------------------------
// L4 v7 (round-10 proven): spill-free skeleton + pre-summed weights.
// ---------------------------------------------------------------------------
template <int PH, int PW>
__device__ void l4v7_wave(const float* __restrict__ eLds,
                          const float* __restrict__ WnB,
                          const float* __restrict__ ez, int lane, int bb,
                          int cs, float* __restrict__ p4) {
  constexpr int PC = PH * 2 + PW;
  const int j = lane & 15;
  const int i0 = (lane >> 4) << 2;
#pragma unroll 1
  for (int q = 0; q < 4; ++q) {
    const int i = i0 + q;
    float acc[3] = {0.f, 0.f, 0.f};
#pragma unroll
    for (int a = 0; a < 2; ++a) {
      const int gi = i + PH - 1 + a;
      const bool vr = (unsigned)gi < 16u;
#pragma unroll
      for (int b2 = 0; b2 < 2; ++b2) {
        const int gj = j + PW - 1 + b2;
        const bool ok = vr && ((unsigned)gj < 16u);
        const int pp = ok ? (gi * 16 + gj) : 0;  // clamped safe address
        const int nbi = a * 2 + b2;
#pragma unroll
        for (int cl = 0; cl < 4; ++cl) {
          const float* ep = eLds + cl * 2304 + pp * 9;
          float en[9];
#pragma unroll
          for (int v = 0; v < 9; ++v) en[v] = ok ? ep[v] : ez[v];
          const float* wp = WnB + ((cl * 4 + PC) * 4 + nbi) * 27;
#pragma unroll
          for (int v = 0; v < 9; ++v) {
            acc[0] = fmaf(en[v], wp[v * 3 + 0], acc[0]);
            acc[1] = fmaf(en[v], wp[v * 3 + 1], acc[1]);
            acc[2] = fmaf(en[v], wp[v * 3 + 2], acc[2]);
          }
        }
      }
    }
    const int h = (i << 1) + PH, w = (j << 1) + PW;
#pragma unroll
    for (int o = 0; o < 3; ++o)
      p4[(size_t)cs * 196608 + ((bb * 3 + o) << 10) + (h << 5) + w] = acc[o];
  }
}

__global__ __launch_bounds__(256) void kan_l4_v7(
    const float* __restrict__ a3, const float* __restrict__ Wn,
    float* __restrict__ p4) {
  __shared__ float eLds[4 * 256 * 9];  // 36.9 KB
  const int bid = blockIdx.x;          // 64 bb x 16 cs
  const int bb = bid >> 4, cs = bid & 15;
  const int t = threadIdx.x;
  float ez[9];
  expand9(0.f, ez);
#pragma unroll
  for (int cl = 0; cl < 4; ++cl) {
    float x = a3[(size_t)(bb * 64 + cs * 4 + cl) * 256 + t];
    float ev[9];
    expand9(x, ev);
#pragma unroll
    for (int v = 0; v < 9; ++v) eLds[(cl * 256 + t) * 9 + v] = ev[v];
  }
  __syncthreads();
  const int wv_ = t >> 6, lane = t & 63;
  const float* WnB = Wn + (size_t)cs * 4 * (4 * 4 * 27);
  if (wv_ == 0)
    l4v7_wave<0, 0>(eLds, WnB, ez, lane, bb, cs, p4);
  else if (wv_ == 1)
    l4v7_wave<0, 1>(eLds, WnB, ez, lane, bb, cs, p4);
  else if (wv_ == 2)
    l4v7_wave<1, 0>(eLds, WnB, ez, lane, bb, cs, p4);
  else
    l4v7_wave<1, 1>(eLds, WnB, ez, lane, bb, cs, p4);
}

__global__ __launch_bounds__(256) void reduce_tanh_l4_16(
    const float* __restrict__ p4, float* __restrict__ out) {
  int i = blockIdx.x * 256 + threadIdx.x;  // 196608
  float s = 0.f;
#pragma unroll
  for (int k = 0; k < 16; ++k) s += p4[(size_t)k * 196608 + i];
  out[i] = tanhf(s);
}

__global__ __launch_bounds__(256) void reduce_tanh_l4(
    const float* __restrict__ p4, float* __restrict__ out) {
  int i = blockIdx.x * 256 + threadIdx.x;
  float s = p4[i] + p4[i + 196608] + p4[i + 2 * 196608] + p4[i + 3 * 196608];
  out[i] = tanhf(s);
}

// ---------------------------------------------------------------------------
// Fallback path (round-1 proven) for small workspace
// ---------------------------------------------------------------------------
template <int CIN, int COUT, int HO, int WO, int BN, int SK>
__global__ __launch_bounds__(256) void kan_gemm(
    const float* __restrict__ in, const float* __restrict__ bw,
    const float* __restrict__ sw, const float* __restrict__ ss,
    float* __restrict__ outp) {
  constexpr int BM = 64, TM = 4, TN = 4, FC = 16;
  constexpr int F = CIN * 9;
  constexpr int HI = HO / 2, WI = WO / 2;
  constexpr int M = BATCH * HO * WO;
  constexpr int FPB = F / SK;

  __shared__ float Ae[FC * 9][BM];

  const int t = threadIdx.x;
  const int mbase = blockIdx.x * BM;
  const int obase = blockIdx.y * BN;
  const int f0 = blockIdx.z * FPB;

  const int cg = t & (BN / TN - 1);
  const int rg = t / (BN / TN);
  const int m0 = rg * TM;
  const int o0 = obase + cg * TN;

  float acc[TM][TN] = {};

  for (int fc = f0; fc < f0 + FPB; fc += FC) {
#pragma unroll
    for (int j = 0; j < BM * FC / 256; ++j) {
      int p = j * 256 + t;
      int ml = p & (BM - 1);
      int df = p >> 6;
      int f = fc + df;
      int c = f / 9;
      int r = f - c * 9;
      int kh = r / 3, kw = r - kh * 3;
      int m = mbase + ml;
      int bb = m / (HO * WO);
      int rem = m % (HO * WO);
      int hh = rem / WO, ww = rem % WO;
      int hp = hh + kh - 1, wp = ww + kw - 1;
      float val = 0.f;
      if (hp >= 0 && hp < HO && wp >= 0 && wp < WO)
        val = in[((bb * CIN + c) * HI + (hp >> 1)) * WI + (wp >> 1)];
      float e[9];
      expand9(val, e);
#pragma unroll
      for (int v = 0; v < 9; ++v) Ae[df * 9 + v][ml] = e[v];
    }
    __syncthreads();

#pragma unroll 2
    for (int df = 0; df < FC; ++df) {
      int f = fc + df;
      float wb[TN], wsv[TN][8];
#pragma unroll
      for (int tn = 0; tn < TN; ++tn) {
        int i = (o0 + tn) * F + f;
        wb[tn] = bw[i];
        float sc = ss[i];
        const float4* sp = reinterpret_cast<const float4*>(sw + (size_t)i * 8);
        float4 s0 = sp[0], s1 = sp[1];
        wsv[tn][0] = s0.x * sc; wsv[tn][1] = s0.y * sc;
        wsv[tn][2] = s0.z * sc; wsv[tn][3] = s0.w * sc;
        wsv[tn][4] = s1.x * sc; wsv[tn][5] = s1.y * sc;
        wsv[tn][6] = s1.z * sc; wsv[tn][7] = s1.w * sc;
      }
      float a[9][TM];
#pragma unroll
      for (int v = 0; v < 9; ++v) {
        float4 q = *reinterpret_cast<const float4*>(&Ae[df * 9 + v][m0]);
        a[v][0] = q.x; a[v][1] = q.y; a[v][2] = q.z; a[v][3] = q.w;
      }
#pragma unroll
      for (int tm = 0; tm < TM; ++tm)
#pragma unroll
        for (int tn = 0; tn < TN; ++tn) acc[tm][tn] += a[0][tm] * wb[tn];
#pragma unroll
      for (int v = 1; v < 9; ++v)
#pragma unroll
        for (int tm = 0; tm < TM; ++tm)
#pragma unroll
          for (int tn = 0; tn < TN; ++tn)
            acc[tm][tn] += a[v][tm] * wsv[tn][v - 1];
    }
    __syncthreads();
  }

  if constexpr (SK > 1) {
    float* p = outp + (size_t)blockIdx.z * M * COUT;
#pragma unroll
    for (int tm = 0; tm < TM; ++tm) {
      int m = mbase + m0 + tm;
#pragma unroll
      for (int tn = 0; tn < TN; ++tn)
        p[(size_t)m * COUT + (o0 + tn)] = acc[tm][tn];
    }
  } else {
#pragma unroll
    for (int tm = 0; tm < TM; ++tm) {
      int m = mbase + m0 + tm;
      int bb = m / (HO * WO);
      int rem = m % (HO * WO);
      int hh = rem / WO, ww = rem % WO;
#pragma unroll
      for (int tn = 0; tn < TN; ++tn) {
        int o = o0 + tn;
        outp[((bb * COUT + o) * HO + hh) * WO + ww] = acc[tm][tn];
      }
    }
  }
}

template <int COUT, int HO, int WO, int SK>
__global__ __launch_bounds__(256) void reduce_partials_old(
    const float* __restrict__ part, float* __restrict__ act) {
  constexpr int M = BATCH * HO * WO;
  int idx = blockIdx.x * 256 + threadIdx.x;
  if (idx >= M * COUT) return;
  float s = 0.f;
#pragma unroll
  for (int k = 0; k < SK; ++k) s += part[(size_t)k * M * COUT + idx];
  int m = idx / COUT, o = idx - (idx / COUT) * COUT;
  int bb = m / (HO * WO);
  int rem = m % (HO * WO);
  int hh = rem / WO, ww = rem % WO;
  act[((bb * COUT + o) * HO + hh) * WO + ww] = s;
}

__global__ __launch_bounds__(256) void kan_l4_split(
    const float* __restrict__ a3, const float* __restrict__ bw,
    const float* __restrict__ sw, const float* __restrict__ ss,
    float* __restrict__ p4) {
  int tid = blockIdx.x * 256 + threadIdx.x;
  int cs = tid >> 16, pix = tid & 65535;
  int b = pix >> 10, rem = pix & 1023, h = rem >> 5, w = rem & 31;
  float acc[3] = {0.f, 0.f, 0.f};
  for (int c = cs * 16; c < cs * 16 + 16; ++c) {
#pragma unroll
    for (int kh = 0; kh < 3; ++kh) {
#pragma unroll
      for (int kw = 0; kw < 3; ++kw) {
        int f = (c * 3 + kh) * 3 + kw;
        int hp = h + kh - 1, wp = w + kw - 1;
        float x = 0.f;
        if ((unsigned)hp < 32u && (unsigned)wp < 32u)
          x = a3[((b * 64 + c) * 16 + (hp >> 1)) * 16 + (wp >> 1)];
        float e[9];
        expand9(x, e);
#pragma unroll
        for (int o = 0; o < 3; ++o) {
          int i = o * 576 + f;
          float d = e[1] * sw[i * 8 + 0];
#pragma unroll
          for (int v = 1; v < 8; ++v) d += e[v + 1] * sw[i * 8 + v];
          acc[o] += e[0] * bw[i] + d * ss[i];
        }
      }
    }
  }
#pragma unroll
  for (int o = 0; o < 3; ++o)
    p4[cs * 196608 + ((b * 3 + o) << 10) + (h << 5) + w] = acc[o];
}

// ---------------------------------------------------------------------------
extern "C" void kernel_launch(void* const* d_in, const int* in_sizes, int n_in,
                              void* d_out, int out_size, void* d_ws,
                              size_t ws_size, hipStream_t stream) {
  const float* x     = (const float*)d_in[0];
  const float* lin_w = (const float*)d_in[1];
  const float* lin_b = (const float*)d_in[2];
  const float* bw1 = (const float*)d_in[3];
  const float* sw1 = (const float*)d_in[4];
  const float* ss1 = (const float*)d_in[5];
  const float* bw2 = (const float*)d_in[6];
  const float* sw2 = (const float*)d_in[7];
  const float* ss2 = (const float*)d_in[8];
  const float* bw3 = (const float*)d_in[9];
  const float* sw3 = (const float*)d_in[10];
  const float* ss3 = (const float*)d_in[11];
  const float* bw4 = (const float*)d_in[12];
  const float* sw4 = (const float*)d_in[13];
  const float* ss4 = (const float*)d_in[14];

  float* wsf = (float*)d_ws;
  float* h  = wsf;                        // 131072
  float* a1 = h + 131072;                 // 262144 (fallback only)
  float* a2 = a1 + 262144;                // 524288 (fallback only)
  float* a3 = a2 + 524288;                // 1048576, ends at 1966080
  // main-path regions
  unsigned short* Bg = (unsigned short*)(wsf + 1966080);  // 10,616,832 float-slots
  float* part = wsf + 1966080 + 10616832;                 // 2,097,152
  uint32_t* Eg = (uint32_t*)(wsf + 14680064);             // 4,718,592
  float* wl4 = h;                    // h dead on main path after linear (27648 floats)
  float* p4  = wsf + 1966080;        // 16*196608 = 3.1M, reuses Bg (dead post-L3)

  const size_t baseFloats = 1966080;
  size_t availFloats = ws_size / 4 > baseFloats ? ws_size / 4 - baseFloats : 0;
  const size_t mainNeed = 10616832ull + 2097152ull + 4718592ull;  // 17.4M

  if (availFloats >= mainNeed) {
    linear_pack_kernel<<<512, 256, 0, stream>>>(x, lin_w, lin_b, h, Eg, 1);

    // L1: CIN=512 COUT=256 4x4, SK=8
    prep_bpack<4608, 256><<<41472, 256, 0, stream>>>(bw1, sw1, ss1, Bg);
    gemm_mfma<512, 256, 4, 4, 8>
        <<<dim3(16, 4, 8), 256, 0, stream>>>(Eg, Bg, part);
    reduce_pe_pack<256, 4, 4><<<1024, 256, 0, stream>>>(part, Eg, 8);

    // L2: CIN=256 COUT=128 8x8, SK=4
    prep_bpack<2304, 128><<<10368, 256, 0, stream>>>(bw2, sw2, ss2, Bg);
    gemm_mfma<256, 128, 8, 8, 4>
        <<<dim3(64, 2, 4), 256, 0, stream>>>(Eg, Bg, part);
    reduce_pe_pack<128, 8, 8><<<2048, 256, 0, stream>>>(part, Eg, 4);

    // L3: CIN=128 COUT=64 16x16, SK=2
    prep_bpack<1152, 64><<<2592, 256, 0, stream>>>(bw3, sw3, ss3, Bg);
    gemm_mfma<128, 64, 16, 16, 2>
        <<<dim3(256, 1, 2), 256, 0, stream>>>(Eg, Bg, part);
    reduce_p<64, 16, 16><<<4096, 256, 0, stream>>>(part, a3, 2);

    // L4: fused LDS expansion + pre-summed weights (round-10 proven)
    prep_wnl4<<<108, 256, 0, stream>>>(bw4, sw4, ss4, wl4);
    kan_l4_v7<<<1024, 256, 0, stream>>>(a3, wl4, p4);
    reduce_tanh_l4_16<<<768, 256, 0, stream>>>(p4, (float*)d_out);
  } else {
    // round-1 proven fallback (needs ~16.3 MB)
    float* partOld = a3 + 1048576;
    linear_pack_kernel<<<512, 256, 0, stream>>>(x, lin_w, lin_b, h, nullptr, 0);
    kan_gemm<512, 256, 4, 4, 64, 8>
        <<<dim3(16, 4, 8), 256, 0, stream>>>(h, bw1, sw1, ss1, partOld);
    reduce_partials_old<256, 4, 4, 8><<<1024, 256, 0, stream>>>(partOld, a1);
    kan_gemm<256, 128, 8, 8, 64, 2>
        <<<dim3(64, 2, 2), 256, 0, stream>>>(a1, bw2, sw2, ss2, partOld);
    reduce_partials_old<128, 8, 8, 2><<<2048, 256, 0, stream>>>(partOld, a2);
    kan_gemm<128, 64, 16, 16, 64, 1>
        <<<dim3(256, 1, 1), 256, 0, stream>>>(a2, bw3, sw3, ss3, a3);
    kan_l4_split<<<1024, 256, 0, stream>>>(a3, bw4, sw4, ss4, partOld);
    reduce_tanh_l4<<<768, 256, 0, stream>>>(partOld, (float*)d_out);
  }
}

// Round 15
// 477.991 us; speedup vs baseline: 1.9304x; 1.0001x over previous
//
#include <hip/hip_runtime.h>
#include <cstdint>
#include <cmath>

#define BATCH 64

typedef __attribute__((ext_vector_type(8))) __bf16 bf16x8;
typedef __attribute__((ext_vector_type(16))) float f32x16;

// ---------------------------------------------------------------------------
// Spline + silu expansion: x -> [silu(x), B_0(x) .. B_7(x)]
// ---------------------------------------------------------------------------
__device__ __forceinline__ void expand9(float x, float* e) {
  float t = __expf(-x);
  e[0] = __fdividef(x, 1.f + t);  // silu
  float b[11];
#pragma unroll
  for (int j = 0; j < 11; ++j) {
    float gj  = 0.4f * (float)j - 2.2f;
    float gj1 = 0.4f * (float)(j + 1) - 2.2f;
    b[j] = (x >= gj && x < gj1) ? 1.f : 0.f;
  }
#pragma unroll
  for (int k = 1; k <= 3; ++k) {
    float inv = 1.f / (0.4f * (float)k);
#pragma unroll
    for (int j = 0; j < 11 - k; ++j) {
      float gj   = 0.4f * (float)j - 2.2f;
      float gjk1 = 0.4f * (float)(j + k + 1) - 2.2f;
      b[j] = ((x - gj) * b[j] + (gjk1 - x) * b[j + 1]) * inv;
    }
  }
#pragma unroll
  for (int v = 0; v < 8; ++v) e[v + 1] = b[v];
}

// bf16 split helpers (round-to-nearest-even)
__device__ __forceinline__ unsigned short f2bf(float x) {
  uint32_t u = __float_as_uint(x);
  uint32_t r = u + 0x7fffu + ((u >> 16) & 1u);
  return (unsigned short)(r >> 16);
}
__device__ __forceinline__ float bf2f(unsigned short h) {
  return __uint_as_float(((uint32_t)h) << 16);
}
__device__ __forceinline__ uint32_t packsplit(float x) {
  unsigned short hi = f2bf(x);
  unsigned short lo = f2bf(x - bf2f(hi));
  return (uint32_t)hi | ((uint32_t)lo << 16);
}

// ---------------------------------------------------------------------------
// h = relu(x @ lin_w^T + lin_b); also writes packed expansion E (main path)
// ---------------------------------------------------------------------------
__global__ __launch_bounds__(256) void linear_pack_kernel(
    const float* __restrict__ x, const float* __restrict__ w,
    const float* __restrict__ bias, float* __restrict__ h,
    uint32_t* __restrict__ E, int writeE) {
  int idx = blockIdx.x * 256 + threadIdx.x;  // 64*2048
  int b = idx >> 11, o = idx & 2047;
  const float* xr = x + b * 100;
  const float* wr = w + o * 100;
  float acc = bias[o];
#pragma unroll 4
  for (int k = 0; k < 100; ++k) acc += xr[k] * wr[k];
  float hv = fmaxf(acc, 0.f);
  h[idx] = hv;
  if (writeE) {
    float e[9];
    expand9(hv, e);
    uint32_t* p = E + (size_t)idx * 9;
#pragma unroll
    for (int v = 0; v < 9; ++v) p[v] = packsplit(e[v]);
  }
}

// ---------------------------------------------------------------------------
// Pack expanded weights into MFMA-staging layout:
// Bg[kc][plane(hi=0,lo=1)][v(9)][n(N)][fl(16)]  (bf16)
// ---------------------------------------------------------------------------
template <int F, int N>
__global__ __launch_bounds__(256) void prep_bpack(
    const float* __restrict__ bw, const float* __restrict__ sw,
    const float* __restrict__ ss, unsigned short* __restrict__ Bg) {
  int idx = blockIdx.x * 256 + threadIdx.x;  // over (F/16)*9*N*16
  int fl = idx & 15;
  int n = (idx >> 4) & (N - 1);
  int rest = idx >> 4;
  rest /= N;
  int v = rest % 9;
  int kc = rest / 9;
  int f = kc * 16 + fl;
  size_t src = (size_t)n * F + f;
  float wv = (v == 0) ? bw[src] : sw[src * 8 + (v - 1)] * ss[src];
  unsigned short hi = f2bf(wv);
  unsigned short lo = f2bf(wv - bf2f(hi));
  size_t base = ((size_t)kc * 2 * 9 + v) * N * 16 + (size_t)n * 16 + fl;
  Bg[base] = hi;                          // plane 0
  Bg[base + (size_t)9 * N * 16] = lo;     // plane 1
}

// ---------------------------------------------------------------------------
// Split-bf16 MFMA GEMM — round-14 proven structure. Round-15 change (ONLY):
// XOR bank-swizzle on the fragment planes: byte_addr ^= ((row>>2)&1)<<4.
// Frag reads (ds_read_b128, row stride 32B) previously hit only 16 banks
// with 8-way aliasing (bank-group = (row&3)*8 + fkg*4). XOR-ing the 16B
// slot bit with row-bit-2 doubles slot-classes -> full 32-bank coverage,
// 4-way = the b128 hardware floor. Applied on BOTH sides (G21): A-writes
// fold it into the thread-constant awz; B-copy XORs the half slot; reads
// XOR fkg with (frow>>2)&1 (also thread-constant -> zero loop overhead).
// ---------------------------------------------------------------------------
template <int CIN, int COUT, int HO, int WO, int SK>
__global__ __launch_bounds__(256, 2) void gemm_mfma(
    const uint32_t* __restrict__ E, const unsigned short* __restrict__ Bg,
    float* __restrict__ part) {
  constexpr int F = CIN * 9;
  constexpr int NKC = F / 16;
  constexpr int HI = HO / 2, WI = WO / 2;
  constexpr int M = BATCH * HO * WO;
  constexpr int CPB = NKC / SK;
  static_assert(NKC % SK == 0, "sk");

  __shared__ __align__(16) unsigned short lds[4 * 9216];

  const int t = threadIdx.x;
  const int mbase = blockIdx.x * 64;
  const int nb = blockIdx.y;
  const int kc0 = blockIdx.z * CPB;

  uint32_t ez[9];
  {
    float e0[9];
    expand9(0.f, e0);
#pragma unroll
    for (int v = 0; v < 9; ++v) ez[v] = packsplit(e0[v]);
  }

  const int lane = t & 63, wv_ = t >> 6;
  const int wm = wv_ >> 1, wn = wv_ & 1;
  const int frow = lane & 31, fkg = lane >> 5;
  // swizzled fragment offsets (bytes): row*32 + (fkg ^ row-bit2)*16
  const int fsw = (frow >> 2) & 1;
  const int aoff = (wm * 32 + frow) * 32 + ((fkg ^ fsw) << 4);
  const int boff = (wn * 32 + frow) * 32 + ((fkg ^ fsw) << 4);

  // A-staging geometry: thread covers row aml, fl = flq*4..+3
  const int aml = t >> 2, flq = t & 3;
  const int am = mbase + aml;
  const int ab = am / (HO * WO), ahw = am % (HO * WO);
  const int ahh = ahw / WO, aww = ahw % WO;
  // swizzled A-write byte offset within a v-plane (thread-constant)
  const int awz = aml * 32 + ((flq * 8) ^ (((aml >> 2) & 1) << 4));

  f32x16 acc;
#pragma unroll
  for (int i = 0; i < 16; ++i) acc[i] = 0.f;

  for (int ci = 0; ci < CPB; ++ci) {
    const int kc = kc0 + ci;
    __syncthreads();

    // ---- stage A: 4 consecutive fl per thread, 18 b64 writes (swizzled) ----
    {
      uint32_t w0[9], w1[9], w2[9], w3[9];
#define LDTAP(IDX, DST)                                                       \
  {                                                                           \
    int f = kc * 16 + flq * 4 + IDX;                                          \
    int c = f / 9, r = f - 9 * c;                                             \
    int kh = r / 3, kw = r - kh * 3;                                          \
    int hp = ahh + kh - 1, wp = aww + kw - 1;                                 \
    if ((unsigned)hp < (unsigned)HO && (unsigned)wp < (unsigned)WO) {         \
      const uint32_t* ep =                                                    \
          E + (size_t)(((ab * CIN + c) * HI + (hp >> 1)) * WI + (wp >> 1)) *  \
                  9;                                                          \
      _Pragma("unroll") for (int v = 0; v < 9; ++v) DST[v] = ep[v];           \
    } else {                                                                  \
      _Pragma("unroll") for (int v = 0; v < 9; ++v) DST[v] = ez[v];           \
    }                                                                         \
  }
      LDTAP(0, w0)
      LDTAP(1, w1)
      LDTAP(2, w2)
      LDTAP(3, w3)
#undef LDTAP
      char* lb = reinterpret_cast<char*>(lds);
#pragma unroll
      for (int v = 0; v < 9; ++v) {
        uint32_t hi01 = (w0[v] & 0xffffu) | (w1[v] << 16);
        uint32_t hi23 = (w2[v] & 0xffffu) | (w3[v] << 16);
        uint32_t lo01 = (w0[v] >> 16) | (w1[v] & 0xffff0000u);
        uint32_t lo23 = (w2[v] >> 16) | (w3[v] & 0xffff0000u);
        *reinterpret_cast<uint2*>(lb + v * 2048 + awz) = make_uint2(hi01, hi23);
        *reinterpret_cast<uint2*>(lb + 18432 + v * 2048 + awz) =
            make_uint2(lo01, lo23);
      }
    }

    // ---- stage B: linear copy (swizzled half-slot) ----
    {
      const unsigned short* bsrc = Bg + (size_t)kc * (2 * 9 * COUT * 16);
#pragma unroll
      for (int g = 0; g < 9; ++g) {
        int u = g * 256 + t;
        int pl = (u >= 1152) ? 1 : 0;
        int rr = u - pl * 1152;
        int v = rr >> 7, q = rr & 127;
        int nl = q >> 1, half = q & 1;
        size_t srcE = (size_t)pl * (9 * COUT * 16) + (size_t)v * (COUT * 16) +
                      (size_t)(nb * 64 + nl) * 16 + half * 8;
        int dst = (2 + pl) * 9216 + v * 1024 + nl * 16 +
                  ((half * 8) ^ (((nl >> 2) & 1) << 3));
        *reinterpret_cast<float4*>(&lds[dst]) =
            *reinterpret_cast<const float4*>(&bsrc[srcE]);
      }
    }
    __syncthreads();

    // ---- compute: 9 v-steps x 3 split-products ----
#pragma unroll
    for (int v = 0; v < 9; ++v) {
      const char* lbc = reinterpret_cast<const char*>(lds);
      bf16x8 ah = *reinterpret_cast<const bf16x8*>(lbc + v * 2048 + aoff);
      bf16x8 al =
          *reinterpret_cast<const bf16x8*>(lbc + 18432 + v * 2048 + aoff);
      bf16x8 bh =
          *reinterpret_cast<const bf16x8*>(lbc + 36864 + v * 2048 + boff);
      bf16x8 bl =
          *reinterpret_cast<const bf16x8*>(lbc + 55296 + v * 2048 + boff);
      acc = __builtin_amdgcn_mfma_f32_32x32x16_bf16(ah, bh, acc, 0, 0, 0);
      acc = __builtin_amdgcn_mfma_f32_32x32x16_bf16(ah, bl, acc, 0, 0, 0);
      acc = __builtin_amdgcn_mfma_f32_32x32x16_bf16(al, bh, acc, 0, 0, 0);
    }
  }

  // ---- epilogue: C/D layout col=lane&31, row=(reg&3)+8*(reg>>2)+4*(lane>>5)
  float* p = part + (size_t)blockIdx.z * M * COUT;
  const int gn = nb * 64 + wn * 32 + frow;
#pragma unroll
  for (int r = 0; r < 16; ++r) {
    int mlocal = (r & 3) + 8 * (r >> 2) + 4 * fkg;
    int gm = mbase + wm * 32 + mlocal;
    p[(size_t)gm * COUT + gn] = acc[r];
  }
}

// ---------------------------------------------------------------------------
template <int COUT, int HO, int WO>
__global__ __launch_bounds__(256) void reduce_pe_pack(
    const float* __restrict__ part, uint32_t* __restrict__ E, int SK) {
  constexpr int M = BATCH * HO * WO;
  int idx = blockIdx.x * 256 + threadIdx.x;
  int ww = idx % WO;
  int tmp = idx / WO;
  int hh = tmp % HO;
  tmp /= HO;
  int o = tmp % COUT;
  int b = tmp / COUT;
  int m = (b * HO + hh) * WO + ww;
  float s = 0.f;
  for (int k = 0; k < SK; ++k) s += part[((size_t)k * M + m) * COUT + o];
  float e[9];
  expand9(s, e);
  uint32_t* p = E + (size_t)idx * 9;
#pragma unroll
  for (int v = 0; v < 9; ++v) p[v] = packsplit(e[v]);
}

template <int COUT, int HO, int WO>
__global__ __launch_bounds__(256) void reduce_p(
    const float* __restrict__ part, float* __restrict__ act, int SK) {
  constexpr int M = BATCH * HO * WO;
  int idx = blockIdx.x * 256 + threadIdx.x;
  int ww = idx % WO;
  int tmp = idx / WO;
  int hh = tmp % HO;
  tmp /= HO;
  int o = tmp % COUT;
  int b = tmp / COUT;
  int m = (b * HO + hh) * WO + ww;
  float s = 0.f;
  for (int k = 0; k < SK; ++k) s += part[((size_t)k * M + m) * COUT + o];
  act[idx] = s;
}

// ---------------------------------------------------------------------------
// L4 weights, neighbor-pre-summed:
// Wn[c][pc][nb][v][o] = sum over taps mapping to neighbor nb under parity pc.
// ---------------------------------------------------------------------------
__global__ __launch_bounds__(256) void prep_wnl4(
    const float* __restrict__ bw, const float* __restrict__ sw,
    const float* __restrict__ ss, float* __restrict__ Wn) {
  int idx = blockIdx.x * 256 + threadIdx.x;  // 64*4*4*27 = 27648
  if (idx >= 27648) return;
  int u = idx % 27;
  int o = u % 3, v = u / 3;
  int rest = idx / 27;
  int nb = rest & 3;
  rest >>= 2;
  int pc = rest & 3;
  rest >>= 2;
  int c = rest;  // 0..63
  int PH = pc >> 1, PW = pc & 1;
  int a = nb >> 1, b2 = nb & 1;
  float s = 0.f;
#pragma unroll
  for (int kh = 0; kh < 3; ++kh) {
    if (((kh > PH) ? 1 : 0) != a) continue;
#pragma unroll
    for (int kw = 0; kw < 3; ++kw) {
      if (((kw > PW) ? 1 : 0) != b2) continue;
      int f = c * 9 + kh * 3 + kw;
      float wv = (v == 0)
                     ? bw[o * 576 + f]
                     : sw[((size_t)(o * 576 + f)) * 8 + (v - 1)] * ss[o * 576 + f];
      s += wv;
    }
  }
  Wn[idx] = s;
}

// ---------------------------------------------------------------------------
// L4 v7 (round-10 proven): spill-free skeleton + pre-summed weights.
// ---------------------------------------------------------------------------
template <int PH, int PW>
__device__ void l4v7_wave(const float* __restrict__ eLds,
                          const float* __restrict__ WnB,
                          const float* __restrict__ ez, int lane, int bb,
                          int cs, float* __restrict__ p4) {
  constexpr int PC = PH * 2 + PW;
  const int j = lane & 15;
  const int i0 = (lane >> 4) << 2;
#pragma unroll 1
  for (int q = 0; q < 4; ++q) {
    const int i = i0 + q;
    float acc[3] = {0.f, 0.f, 0.f};
#pragma unroll
    for (int a = 0; a < 2; ++a) {
      const int gi = i + PH - 1 + a;
      const bool vr = (unsigned)gi < 16u;
#pragma unroll
      for (int b2 = 0; b2 < 2; ++b2) {
        const int gj = j + PW - 1 + b2;
        const bool ok = vr && ((unsigned)gj < 16u);
        const int pp = ok ? (gi * 16 + gj) : 0;  // clamped safe address
        const int nbi = a * 2 + b2;
#pragma unroll
        for (int cl = 0; cl < 4; ++cl) {
          const float* ep = eLds + cl * 2304 + pp * 9;
          float en[9];
#pragma unroll
          for (int v = 0; v < 9; ++v) en[v] = ok ? ep[v] : ez[v];
          const float* wp = WnB + ((cl * 4 + PC) * 4 + nbi) * 27;
#pragma unroll
          for (int v = 0; v < 9; ++v) {
            acc[0] = fmaf(en[v], wp[v * 3 + 0], acc[0]);
            acc[1] = fmaf(en[v], wp[v * 3 + 1], acc[1]);
            acc[2] = fmaf(en[v], wp[v * 3 + 2], acc[2]);
          }
        }
      }
    }
    const int h = (i << 1) + PH, w = (j << 1) + PW;
#pragma unroll
    for (int o = 0; o < 3; ++o)
      p4[(size_t)cs * 196608 + ((bb * 3 + o) << 10) + (h << 5) + w] = acc[o];
  }
}

__global__ __launch_bounds__(256) void kan_l4_v7(
    const float* __restrict__ a3, const float* __restrict__ Wn,
    float* __restrict__ p4) {
  __shared__ float eLds[4 * 256 * 9];  // 36.9 KB
  const int bid = blockIdx.x;          // 64 bb x 16 cs
  const int bb = bid >> 4, cs = bid & 15;
  const int t = threadIdx.x;
  float ez[9];
  expand9(0.f, ez);
#pragma unroll
  for (int cl = 0; cl < 4; ++cl) {
    float x = a3[(size_t)(bb * 64 + cs * 4 + cl) * 256 + t];
    float ev[9];
    expand9(x, ev);
#pragma unroll
    for (int v = 0; v < 9; ++v) eLds[(cl * 256 + t) * 9 + v] = ev[v];
  }
  __syncthreads();
  const int wv_ = t >> 6, lane = t & 63;
  const float* WnB = Wn + (size_t)cs * 4 * (4 * 4 * 27);
  if (wv_ == 0)
    l4v7_wave<0, 0>(eLds, WnB, ez, lane, bb, cs, p4);
  else if (wv_ == 1)
    l4v7_wave<0, 1>(eLds, WnB, ez, lane, bb, cs, p4);
  else if (wv_ == 2)
    l4v7_wave<1, 0>(eLds, WnB, ez, lane, bb, cs, p4);
  else
    l4v7_wave<1, 1>(eLds, WnB, ez, lane, bb, cs, p4);
}

__global__ __launch_bounds__(256) void reduce_tanh_l4_16(
    const float* __restrict__ p4, float* __restrict__ out) {
  int i = blockIdx.x * 256 + threadIdx.x;  // 196608
  float s = 0.f;
#pragma unroll
  for (int k = 0; k < 16; ++k) s += p4[(size_t)k * 196608 + i];
  out[i] = tanhf(s);
}

__global__ __launch_bounds__(256) void reduce_tanh_l4(
    const float* __restrict__ p4, float* __restrict__ out) {
  int i = blockIdx.x * 256 + threadIdx.x;
  float s = p4[i] + p4[i + 196608] + p4[i + 2 * 196608] + p4[i + 3 * 196608];
  out[i] = tanhf(s);
}

// ---------------------------------------------------------------------------
// Fallback path (round-1 proven) for small workspace
// ---------------------------------------------------------------------------
template <int CIN, int COUT, int HO, int WO, int BN, int SK>
__global__ __launch_bounds__(256) void kan_gemm(
    const float* __restrict__ in, const float* __restrict__ bw,
    const float* __restrict__ sw, const float* __restrict__ ss,
    float* __restrict__ outp) {
  constexpr int BM = 64, TM = 4, TN = 4, FC = 16;
  constexpr int F = CIN * 9;
  constexpr int HI = HO / 2, WI = WO / 2;
  constexpr int M = BATCH * HO * WO;
  constexpr int FPB = F / SK;

  __shared__ float Ae[FC * 9][BM];

  const int t = threadIdx.x;
  const int mbase = blockIdx.x * BM;
  const int obase = blockIdx.y * BN;
  const int f0 = blockIdx.z * FPB;

  const int cg = t & (BN / TN - 1);
  const int rg = t / (BN / TN);
  const int m0 = rg * TM;
  const int o0 = obase + cg * TN;

  float acc[TM][TN] = {};

  for (int fc = f0; fc < f0 + FPB; fc += FC) {
#pragma unroll
    for (int j = 0; j < BM * FC / 256; ++j) {
      int p = j * 256 + t;
      int ml = p & (BM - 1);
      int df = p >> 6;
      int f = fc + df;
      int c = f / 9;
      int r = f - c * 9;
      int kh = r / 3, kw = r - kh * 3;
      int m = mbase + ml;
      int bb = m / (HO * WO);
      int rem = m % (HO * WO);
      int hh = rem / WO, ww = rem % WO;
      int hp = hh + kh - 1, wp = ww + kw - 1;
      float val = 0.f;
      if (hp >= 0 && hp < HO && wp >= 0 && wp < WO)
        val = in[((bb * CIN + c) * HI + (hp >> 1)) * WI + (wp >> 1)];
      float e[9];
      expand9(val, e);
#pragma unroll
      for (int v = 0; v < 9; ++v) Ae[df * 9 + v][ml] = e[v];
    }
    __syncthreads();

#pragma unroll 2
    for (int df = 0; df < FC; ++df) {
      int f = fc + df;
      float wb[TN], wsv[TN][8];
#pragma unroll
      for (int tn = 0; tn < TN; ++tn) {
        int i = (o0 + tn) * F + f;
        wb[tn] = bw[i];
        float sc = ss[i];
        const float4* sp = reinterpret_cast<const float4*>(sw + (size_t)i * 8);
        float4 s0 = sp[0], s1 = sp[1];
        wsv[tn][0] = s0.x * sc; wsv[tn][1] = s0.y * sc;
        wsv[tn][2] = s0.z * sc; wsv[tn][3] = s0.w * sc;
        wsv[tn][4] = s1.x * sc; wsv[tn][5] = s1.y * sc;
        wsv[tn][6] = s1.z * sc; wsv[tn][7] = s1.w * sc;
      }
      float a[9][TM];
#pragma unroll
      for (int v = 0; v < 9; ++v) {
        float4 q = *reinterpret_cast<const float4*>(&Ae[df * 9 + v][m0]);
        a[v][0] = q.x; a[v][1] = q.y; a[v][2] = q.z; a[v][3] = q.w;
      }
#pragma unroll
      for (int tm = 0; tm < TM; ++tm)
#pragma unroll
        for (int tn = 0; tn < TN; ++tn) acc[tm][tn] += a[0][tm] * wb[tn];
#pragma unroll
      for (int v = 1; v < 9; ++v)
#pragma unroll
        for (int tm = 0; tm < TM; ++tm)
#pragma unroll
          for (int tn = 0; tn < TN; ++tn)
            acc[tm][tn] += a[v][tm] * wsv[tn][v - 1];
    }
    __syncthreads();
  }

  if constexpr (SK > 1) {
    float* p = outp + (size_t)blockIdx.z * M * COUT;
#pragma unroll
    for (int tm = 0; tm < TM; ++tm) {
      int m = mbase + m0 + tm;
#pragma unroll
      for (int tn = 0; tn < TN; ++tn)
        p[(size_t)m * COUT + (o0 + tn)] = acc[tm][tn];
    }
  } else {
#pragma unroll
    for (int tm = 0; tm < TM; ++tm) {
      int m = mbase + m0 + tm;
      int bb = m / (HO * WO);
      int rem = m % (HO * WO);
      int hh = rem / WO, ww = rem % WO;
#pragma unroll
      for (int tn = 0; tn < TN; ++tn) {
        int o = o0 + tn;
        outp[((bb * COUT + o) * HO + hh) * WO + ww] = acc[tm][tn];
      }
    }
  }
}

template <int COUT, int HO, int WO, int SK>
__global__ __launch_bounds__(256) void reduce_partials_old(
    const float* __restrict__ part, float* __restrict__ act) {
  constexpr int M = BATCH * HO * WO;
  int idx = blockIdx.x * 256 + threadIdx.x;
  if (idx >= M * COUT) return;
  float s = 0.f;
#pragma unroll
  for (int k = 0; k < SK; ++k) s += part[(size_t)k * M * COUT + idx];
  int m = idx / COUT, o = idx - (idx / COUT) * COUT;
  int bb = m / (HO * WO);
  int rem = m % (HO * WO);
  int hh = rem / WO, ww = rem % WO;
  act[((bb * COUT + o) * HO + hh) * WO + ww] = s;
}

__global__ __launch_bounds__(256) void kan_l4_split(
    const float* __restrict__ a3, const float* __restrict__ bw,
    const float* __restrict__ sw, const float* __restrict__ ss,
    float* __restrict__ p4) {
  int tid = blockIdx.x * 256 + threadIdx.x;
  int cs = tid >> 16, pix = tid & 65535;
  int b = pix >> 10, rem = pix & 1023, h = rem >> 5, w = rem & 31;
  float acc[3] = {0.f, 0.f, 0.f};
  for (int c = cs * 16; c < cs * 16 + 16; ++c) {
#pragma unroll
    for (int kh = 0; kh < 3; ++kh) {
#pragma unroll
      for (int kw = 0; kw < 3; ++kw) {
        int f = (c * 3 + kh) * 3 + kw;
        int hp = h + kh - 1, wp = w + kw - 1;
        float x = 0.f;
        if ((unsigned)hp < 32u && (unsigned)wp < 32u)
          x = a3[((b * 64 + c) * 16 + (hp >> 1)) * 16 + (wp >> 1)];
        float e[9];
        expand9(x, e);
#pragma unroll
        for (int o = 0; o < 3; ++o) {
          int i = o * 576 + f;
          float d = e[1] * sw[i * 8 + 0];
#pragma unroll
          for (int v = 1; v < 8; ++v) d += e[v + 1] * sw[i * 8 + v];
          acc[o] += e[0] * bw[i] + d * ss[i];
        }
      }
    }
  }
#pragma unroll
  for (int o = 0; o < 3; ++o)
    p4[cs * 196608 + ((b * 3 + o) << 10) + (h << 5) + w] = acc[o];
}

// ---------------------------------------------------------------------------
extern "C" void kernel_launch(void* const* d_in, const int* in_sizes, int n_in,
                              void* d_out, int out_size, void* d_ws,
                              size_t ws_size, hipStream_t stream) {
  const float* x     = (const float*)d_in[0];
  const float* lin_w = (const float*)d_in[1];
  const float* lin_b = (const float*)d_in[2];
  const float* bw1 = (const float*)d_in[3];
  const float* sw1 = (const float*)d_in[4];
  const float* ss1 = (const float*)d_in[5];
  const float* bw2 = (const float*)d_in[6];
  const float* sw2 = (const float*)d_in[7];
  const float* ss2 = (const float*)d_in[8];
  const float* bw3 = (const float*)d_in[9];
  const float* sw3 = (const float*)d_in[10];
  const float* ss3 = (const float*)d_in[11];
  const float* bw4 = (const float*)d_in[12];
  const float* sw4 = (const float*)d_in[13];
  const float* ss4 = (const float*)d_in[14];

  float* wsf = (float*)d_ws;
  float* h  = wsf;                        // 131072
  float* a1 = h + 131072;                 // 262144 (fallback only)
  float* a2 = a1 + 262144;                // 524288 (fallback only)
  float* a3 = a2 + 524288;                // 1048576, ends at 1966080
  // main-path regions
  unsigned short* Bg = (unsigned short*)(wsf + 1966080);  // 10,616,832 float-slots
  float* part = wsf + 1966080 + 10616832;                 // 2,097,152
  uint32_t* Eg = (uint32_t*)(wsf + 14680064);             // 4,718,592
  float* wl4 = h;                    // h dead on main path after linear (27648 floats)
  float* p4  = wsf + 1966080;        // 16*196608 = 3.1M, reuses Bg (dead post-L3)

  const size_t baseFloats = 1966080;
  size_t availFloats = ws_size / 4 > baseFloats ? ws_size / 4 - baseFloats : 0;
  const size_t mainNeed = 10616832ull + 2097152ull + 4718592ull;  // 17.4M

  if (availFloats >= mainNeed) {
    linear_pack_kernel<<<512, 256, 0, stream>>>(x, lin_w, lin_b, h, Eg, 1);

    // L1: CIN=512 COUT=256 4x4, SK=8
    prep_bpack<4608, 256><<<41472, 256, 0, stream>>>(bw1, sw1, ss1, Bg);
    gemm_mfma<512, 256, 4, 4, 8>
        <<<dim3(16, 4, 8), 256, 0, stream>>>(Eg, Bg, part);
    reduce_pe_pack<256, 4, 4><<<1024, 256, 0, stream>>>(part, Eg, 8);

    // L2: CIN=256 COUT=128 8x8, SK=4
    prep_bpack<2304, 128><<<10368, 256, 0, stream>>>(bw2, sw2, ss2, Bg);
    gemm_mfma<256, 128, 8, 8, 4>
        <<<dim3(64, 2, 4), 256, 0, stream>>>(Eg, Bg, part);
    reduce_pe_pack<128, 8, 8><<<2048, 256, 0, stream>>>(part, Eg, 4);

    // L3: CIN=128 COUT=64 16x16, SK=2
    prep_bpack<1152, 64><<<2592, 256, 0, stream>>>(bw3, sw3, ss3, Bg);
    gemm_mfma<128, 64, 16, 16, 2>
        <<<dim3(256, 1, 2), 256, 0, stream>>>(Eg, Bg, part);
    reduce_p<64, 16, 16><<<4096, 256, 0, stream>>>(part, a3, 2);

    // L4: fused LDS expansion + pre-summed weights (round-10 proven)
    prep_wnl4<<<108, 256, 0, stream>>>(bw4, sw4, ss4, wl4);
    kan_l4_v7<<<1024, 256, 0, stream>>>(a3, wl4, p4);
    reduce_tanh_l4_16<<<768, 256, 0, stream>>>(p4, (float*)d_out);
  } else {
    // round-1 proven fallback (needs ~16.3 MB)
    float* partOld = a3 + 1048576;
    linear_pack_kernel<<<512, 256, 0, stream>>>(x, lin_w, lin_b, h, nullptr, 0);
    kan_gemm<512, 256, 4, 4, 64, 8>
        <<<dim3(16, 4, 8), 256, 0, stream>>>(h, bw1, sw1, ss1, partOld);
    reduce_partials_old<256, 4, 4, 8><<<1024, 256, 0, stream>>>(partOld, a1);
    kan_gemm<256, 128, 8, 8, 64, 2>
        <<<dim3(64, 2, 2), 256, 0, stream>>>(a1, bw2, sw2, ss2, partOld);
    reduce_partials_old<128, 8, 8, 2><<<2048, 256, 0, stream>>>(partOld, a2);
    kan_gemm<128, 64, 16, 16, 64, 1>
        <<<dim3(256, 1, 1), 256, 0, stream>>>(a2, bw3, sw3, ss3, a3);
    kan_l4_split<<<1024, 256, 0, stream>>>(a3, bw4, sw4, ss4, partOld);
    reduce_tanh_l4<<<768, 256, 0, stream>>>(partOld, (float*)d_out);
  }
}

// Round 16
// 408.533 us; speedup vs baseline: 2.2586x; 1.1700x over previous
//
#include <hip/hip_runtime.h>
#include <cstdint>
#include <cmath>

#define BATCH 64

typedef __attribute__((ext_vector_type(8))) __bf16 bf16x8;
typedef __attribute__((ext_vector_type(16))) float f32x16;

// ---------------------------------------------------------------------------
// Spline + silu expansion: x -> [silu(x), B_0(x) .. B_7(x)]
// ---------------------------------------------------------------------------
__device__ __forceinline__ void expand9(float x, float* e) {
  float t = __expf(-x);
  e[0] = __fdividef(x, 1.f + t);  // silu
  float b[11];
#pragma unroll
  for (int j = 0; j < 11; ++j) {
    float gj  = 0.4f * (float)j - 2.2f;
    float gj1 = 0.4f * (float)(j + 1) - 2.2f;
    b[j] = (x >= gj && x < gj1) ? 1.f : 0.f;
  }
#pragma unroll
  for (int k = 1; k <= 3; ++k) {
    float inv = 1.f / (0.4f * (float)k);
#pragma unroll
    for (int j = 0; j < 11 - k; ++j) {
      float gj   = 0.4f * (float)j - 2.2f;
      float gjk1 = 0.4f * (float)(j + k + 1) - 2.2f;
      b[j] = ((x - gj) * b[j] + (gjk1 - x) * b[j + 1]) * inv;
    }
  }
#pragma unroll
  for (int v = 0; v < 8; ++v) e[v + 1] = b[v];
}

// bf16 split helpers (round-to-nearest-even)
__device__ __forceinline__ unsigned short f2bf(float x) {
  uint32_t u = __float_as_uint(x);
  uint32_t r = u + 0x7fffu + ((u >> 16) & 1u);
  return (unsigned short)(r >> 16);
}
__device__ __forceinline__ float bf2f(unsigned short h) {
  return __uint_as_float(((uint32_t)h) << 16);
}
__device__ __forceinline__ uint32_t packsplit(float x) {
  unsigned short hi = f2bf(x);
  unsigned short lo = f2bf(x - bf2f(hi));
  return (uint32_t)hi | ((uint32_t)lo << 16);
}

// ---------------------------------------------------------------------------
// h = relu(x @ lin_w^T + lin_b); also writes packed expansion E (main path)
// ---------------------------------------------------------------------------
__global__ __launch_bounds__(256) void linear_pack_kernel(
    const float* __restrict__ x, const float* __restrict__ w,
    const float* __restrict__ bias, float* __restrict__ h,
    uint32_t* __restrict__ E, int writeE) {
  int idx = blockIdx.x * 256 + threadIdx.x;  // 64*2048
  int b = idx >> 11, o = idx & 2047;
  const float* xr = x + b * 100;
  const float* wr = w + o * 100;
  float acc = bias[o];
#pragma unroll 4
  for (int k = 0; k < 100; ++k) acc += xr[k] * wr[k];
  float hv = fmaxf(acc, 0.f);
  h[idx] = hv;
  if (writeE) {
    float e[9];
    expand9(hv, e);
    uint32_t* p = E + (size_t)idx * 9;
#pragma unroll
    for (int v = 0; v < 9; ++v) p[v] = packsplit(e[v]);
  }
}

// ---------------------------------------------------------------------------
// Pack expanded weights into MFMA-staging layout:
// Bg[kc][plane(hi=0,lo=1)][v(9)][n(N)][fl(16)]  (bf16)
// ---------------------------------------------------------------------------
template <int F, int N>
__global__ __launch_bounds__(256) void prep_bpack(
    const float* __restrict__ bw, const float* __restrict__ sw,
    const float* __restrict__ ss, unsigned short* __restrict__ Bg) {
  int idx = blockIdx.x * 256 + threadIdx.x;  // over (F/16)*9*N*16
  int fl = idx & 15;
  int n = (idx >> 4) & (N - 1);
  int rest = idx >> 4;
  rest /= N;
  int v = rest % 9;
  int kc = rest / 9;
  int f = kc * 16 + fl;
  size_t src = (size_t)n * F + f;
  float wv = (v == 0) ? bw[src] : sw[src * 8 + (v - 1)] * ss[src];
  unsigned short hi = f2bf(wv);
  unsigned short lo = f2bf(wv - bf2f(hi));
  size_t base = ((size_t)kc * 2 * 9 + v) * N * 16 + (size_t)n * 16 + fl;
  Bg[base] = hi;                          // plane 0
  Bg[base + (size_t)9 * N * 16] = lo;     // plane 1
}

// ---------------------------------------------------------------------------
// Split-bf16 MFMA GEMM — round-14 proven structure. Round-16 change (ONLY):
// drop the al*bh split-product. B stays full-precision (bh+bl = b to 2^-17)
// but A is truncated to bf16-hi: C = sum ah*(bh+bl). Per chunk per wave this
// cuts MFMA 27->18, frag reads 36->27, A-writes 18->9 b64, LDS 73.7->55.3KB.
// Error: dropped sum_k al*b, |al|<=2^-9|a|, random signs over K -> ~1e-3
// per layer; final absmax est. 3-4e-3 < 9.9e-3 threshold (L4 fp32-exact).
// ---------------------------------------------------------------------------
template <int CIN, int COUT, int HO, int WO, int SK>
__global__ __launch_bounds__(256, 2) void gemm_mfma(
    const uint32_t* __restrict__ E, const unsigned short* __restrict__ Bg,
    float* __restrict__ part) {
  constexpr int F = CIN * 9;
  constexpr int NKC = F / 16;
  constexpr int HI = HO / 2, WI = WO / 2;
  constexpr int M = BATCH * HO * WO;
  constexpr int CPB = NKC / SK;
  static_assert(NKC % SK == 0, "sk");

  // plane 0: A-hi [9][64][16]; planes 1,2: B-hi, B-lo
  __shared__ __align__(16) unsigned short lds[3 * 9216];

  const int t = threadIdx.x;
  const int mbase = blockIdx.x * 64;
  const int nb = blockIdx.y;
  const int kc0 = blockIdx.z * CPB;

  uint32_t ez[9];
  {
    float e0[9];
    expand9(0.f, e0);
#pragma unroll
    for (int v = 0; v < 9; ++v) ez[v] = packsplit(e0[v]);
  }

  const int lane = t & 63, wv_ = t >> 6;
  const int wm = wv_ >> 1, wn = wv_ & 1;
  const int frow = lane & 31, fkg = lane >> 5;
  const int aoff = ((wm * 32 + frow) * 16 + fkg * 8) * 2;  // bytes
  const int boff = ((wn * 32 + frow) * 16 + fkg * 8) * 2;

  // A-staging geometry: thread covers row aml, fl = flq*4..+3
  const int aml = t >> 2, flq = t & 3;
  const int am = mbase + aml;
  const int ab = am / (HO * WO), ahw = am % (HO * WO);
  const int ahh = ahw / WO, aww = ahw % WO;

  f32x16 acc;
#pragma unroll
  for (int i = 0; i < 16; ++i) acc[i] = 0.f;

  for (int ci = 0; ci < CPB; ++ci) {
    const int kc = kc0 + ci;
    __syncthreads();

    // ---- stage A (hi only): 4 consecutive fl per thread, 9 b64 writes ----
    {
      uint32_t w0[9], w1[9], w2[9], w3[9];
#define LDTAP(IDX, DST)                                                       \
  {                                                                           \
    int f = kc * 16 + flq * 4 + IDX;                                          \
    int c = f / 9, r = f - 9 * c;                                             \
    int kh = r / 3, kw = r - kh * 3;                                          \
    int hp = ahh + kh - 1, wp = aww + kw - 1;                                 \
    if ((unsigned)hp < (unsigned)HO && (unsigned)wp < (unsigned)WO) {         \
      const uint32_t* ep =                                                    \
          E + (size_t)(((ab * CIN + c) * HI + (hp >> 1)) * WI + (wp >> 1)) *  \
                  9;                                                          \
      _Pragma("unroll") for (int v = 0; v < 9; ++v) DST[v] = ep[v];           \
    } else {                                                                  \
      _Pragma("unroll") for (int v = 0; v < 9; ++v) DST[v] = ez[v];           \
    }                                                                         \
  }
      LDTAP(0, w0)
      LDTAP(1, w1)
      LDTAP(2, w2)
      LDTAP(3, w3)
#undef LDTAP
      char* lb = reinterpret_cast<char*>(lds);
#pragma unroll
      for (int v = 0; v < 9; ++v) {
        uint32_t hi01 = (w0[v] & 0xffffu) | (w1[v] << 16);
        uint32_t hi23 = (w2[v] & 0xffffu) | (w3[v] << 16);
        *reinterpret_cast<uint2*>(lb + v * 2048 + aml * 32 + flq * 8) =
            make_uint2(hi01, hi23);
      }
    }

    // ---- stage B: linear copy (both planes, round-10 proven) ----
    {
      const unsigned short* bsrc = Bg + (size_t)kc * (2 * 9 * COUT * 16);
#pragma unroll
      for (int g = 0; g < 9; ++g) {
        int u = g * 256 + t;
        int pl = (u >= 1152) ? 1 : 0;
        int rr = u - pl * 1152;
        int v = rr >> 7, q = rr & 127;
        int nl = q >> 1, half = q & 1;
        size_t srcE = (size_t)pl * (9 * COUT * 16) + (size_t)v * (COUT * 16) +
                      (size_t)(nb * 64 + nl) * 16 + half * 8;
        int dst = (1 + pl) * 9216 + v * 1024 + nl * 16 + half * 8;
        *reinterpret_cast<float4*>(&lds[dst]) =
            *reinterpret_cast<const float4*>(&bsrc[srcE]);
      }
    }
    __syncthreads();

    // ---- compute: 9 v-steps x 2 products (ah*bh + ah*bl) ----
#pragma unroll
    for (int v = 0; v < 9; ++v) {
      const char* lbc = reinterpret_cast<const char*>(lds);
      bf16x8 ah = *reinterpret_cast<const bf16x8*>(lbc + v * 2048 + aoff);
      bf16x8 bh =
          *reinterpret_cast<const bf16x8*>(lbc + 18432 + v * 2048 + boff);
      bf16x8 bl =
          *reinterpret_cast<const bf16x8*>(lbc + 36864 + v * 2048 + boff);
      acc = __builtin_amdgcn_mfma_f32_32x32x16_bf16(ah, bh, acc, 0, 0, 0);
      acc = __builtin_amdgcn_mfma_f32_32x32x16_bf16(ah, bl, acc, 0, 0, 0);
    }
  }

  // ---- epilogue: C/D layout col=lane&31, row=(reg&3)+8*(reg>>2)+4*(lane>>5)
  float* p = part + (size_t)blockIdx.z * M * COUT;
  const int gn = nb * 64 + wn * 32 + frow;
#pragma unroll
  for (int r = 0; r < 16; ++r) {
    int mlocal = (r & 3) + 8 * (r >> 2) + 4 * fkg;
    int gm = mbase + wm * 32 + mlocal;
    p[(size_t)gm * COUT + gn] = acc[r];
  }
}

// ---------------------------------------------------------------------------
template <int COUT, int HO, int WO>
__global__ __launch_bounds__(256) void reduce_pe_pack(
    const float* __restrict__ part, uint32_t* __restrict__ E, int SK) {
  constexpr int M = BATCH * HO * WO;
  int idx = blockIdx.x * 256 + threadIdx.x;
  int ww = idx % WO;
  int tmp = idx / WO;
  int hh = tmp % HO;
  tmp /= HO;
  int o = tmp % COUT;
  int b = tmp / COUT;
  int m = (b * HO + hh) * WO + ww;
  float s = 0.f;
  for (int k = 0; k < SK; ++k) s += part[((size_t)k * M + m) * COUT + o];
  float e[9];
  expand9(s, e);
  uint32_t* p = E + (size_t)idx * 9;
#pragma unroll
  for (int v = 0; v < 9; ++v) p[v] = packsplit(e[v]);
}

template <int COUT, int HO, int WO>
__global__ __launch_bounds__(256) void reduce_p(
    const float* __restrict__ part, float* __restrict__ act, int SK) {
  constexpr int M = BATCH * HO * WO;
  int idx = blockIdx.x * 256 + threadIdx.x;
  int ww = idx % WO;
  int tmp = idx / WO;
  int hh = tmp % HO;
  tmp /= HO;
  int o = tmp % COUT;
  int b = tmp / COUT;
  int m = (b * HO + hh) * WO + ww;
  float s = 0.f;
  for (int k = 0; k < SK; ++k) s += part[((size_t)k * M + m) * COUT + o];
  act[idx] = s;
}

// ---------------------------------------------------------------------------
// L4 weights, neighbor-pre-summed:
// Wn[c][pc][nb][v][o] = sum over taps mapping to neighbor nb under parity pc.
// ---------------------------------------------------------------------------
__global__ __launch_bounds__(256) void prep_wnl4(
    const float* __restrict__ bw, const float* __restrict__ sw,
    const float* __restrict__ ss, float* __restrict__ Wn) {
  int idx = blockIdx.x * 256 + threadIdx.x;  // 64*4*4*27 = 27648
  if (idx >= 27648) return;
  int u = idx % 27;
  int o = u % 3, v = u / 3;
  int rest = idx / 27;
  int nb = rest & 3;
  rest >>= 2;
  int pc = rest & 3;
  rest >>= 2;
  int c = rest;  // 0..63
  int PH = pc >> 1, PW = pc & 1;
  int a = nb >> 1, b2 = nb & 1;
  float s = 0.f;
#pragma unroll
  for (int kh = 0; kh < 3; ++kh) {
    if (((kh > PH) ? 1 : 0) != a) continue;
#pragma unroll
    for (int kw = 0; kw < 3; ++kw) {
      if (((kw > PW) ? 1 : 0) != b2) continue;
      int f = c * 9 + kh * 3 + kw;
      float wv = (v == 0)
                     ? bw[o * 576 + f]
                     : sw[((size_t)(o * 576 + f)) * 8 + (v - 1)] * ss[o * 576 + f];
      s += wv;
    }
  }
  Wn[idx] = s;
}

// ---------------------------------------------------------------------------
// L4 v7 (round-10 proven): spill-free skeleton + pre-summed weights.
// ---------------------------------------------------------------------------
template <int PH, int PW>
__device__ void l4v7_wave(const float* __restrict__ eLds,
                          const float* __restrict__ WnB,
                          const float* __restrict__ ez, int lane, int bb,
                          int cs, float* __restrict__ p4) {
  constexpr int PC = PH * 2 + PW;
  const int j = lane & 15;
  const int i0 = (lane >> 4) << 2;
#pragma unroll 1
  for (int q = 0; q < 4; ++q) {
    const int i = i0 + q;
    float acc[3] = {0.f, 0.f, 0.f};
#pragma unroll
    for (int a = 0; a < 2; ++a) {
      const int gi = i + PH - 1 + a;
      const bool vr = (unsigned)gi < 16u;
#pragma unroll
      for (int b2 = 0; b2 < 2; ++b2) {
        const int gj = j + PW - 1 + b2;
        const bool ok = vr && ((unsigned)gj < 16u);
        const int pp = ok ? (gi * 16 + gj) : 0;  // clamped safe address
        const int nbi = a * 2 + b2;
#pragma unroll
        for (int cl = 0; cl < 4; ++cl) {
          const float* ep = eLds + cl * 2304 + pp * 9;
          float en[9];
#pragma unroll
          for (int v = 0; v < 9; ++v) en[v] = ok ? ep[v] : ez[v];
          const float* wp = WnB + ((cl * 4 + PC) * 4 + nbi) * 27;
#pragma unroll
          for (int v = 0; v < 9; ++v) {
            acc[0] = fmaf(en[v], wp[v * 3 + 0], acc[0]);
            acc[1] = fmaf(en[v], wp[v * 3 + 1], acc[1]);
            acc[2] = fmaf(en[v], wp[v * 3 + 2], acc[2]);
          }
        }
      }
    }
    const int h = (i << 1) + PH, w = (j << 1) + PW;
#pragma unroll
    for (int o = 0; o < 3; ++o)
      p4[(size_t)cs * 196608 + ((bb * 3 + o) << 10) + (h << 5) + w] = acc[o];
  }
}

__global__ __launch_bounds__(256) void kan_l4_v7(
    const float* __restrict__ a3, const float* __restrict__ Wn,
    float* __restrict__ p4) {
  __shared__ float eLds[4 * 256 * 9];  // 36.9 KB
  const int bid = blockIdx.x;          // 64 bb x 16 cs
  const int bb = bid >> 4, cs = bid & 15;
  const int t = threadIdx.x;
  float ez[9];
  expand9(0.f, ez);
#pragma unroll
  for (int cl = 0; cl < 4; ++cl) {
    float x = a3[(size_t)(bb * 64 + cs * 4 + cl) * 256 + t];
    float ev[9];
    expand9(x, ev);
#pragma unroll
    for (int v = 0; v < 9; ++v) eLds[(cl * 256 + t) * 9 + v] = ev[v];
  }
  __syncthreads();
  const int wv_ = t >> 6, lane = t & 63;
  const float* WnB = Wn + (size_t)cs * 4 * (4 * 4 * 27);
  if (wv_ == 0)
    l4v7_wave<0, 0>(eLds, WnB, ez, lane, bb, cs, p4);
  else if (wv_ == 1)
    l4v7_wave<0, 1>(eLds, WnB, ez, lane, bb, cs, p4);
  else if (wv_ == 2)
    l4v7_wave<1, 0>(eLds, WnB, ez, lane, bb, cs, p4);
  else
    l4v7_wave<1, 1>(eLds, WnB, ez, lane, bb, cs, p4);
}

__global__ __launch_bounds__(256) void reduce_tanh_l4_16(
    const float* __restrict__ p4, float* __restrict__ out) {
  int i = blockIdx.x * 256 + threadIdx.x;  // 196608
  float s = 0.f;
#pragma unroll
  for (int k = 0; k < 16; ++k) s += p4[(size_t)k * 196608 + i];
  out[i] = tanhf(s);
}

__global__ __launch_bounds__(256) void reduce_tanh_l4(
    const float* __restrict__ p4, float* __restrict__ out) {
  int i = blockIdx.x * 256 + threadIdx.x;
  float s = p4[i] + p4[i + 196608] + p4[i + 2 * 196608] + p4[i + 3 * 196608];
  out[i] = tanhf(s);
}

// ---------------------------------------------------------------------------
// Fallback path (round-1 proven) for small workspace
// ---------------------------------------------------------------------------
template <int CIN, int COUT, int HO, int WO, int BN, int SK>
__global__ __launch_bounds__(256) void kan_gemm(
    const float* __restrict__ in, const float* __restrict__ bw,
    const float* __restrict__ sw, const float* __restrict__ ss,
    float* __restrict__ outp) {
  constexpr int BM = 64, TM = 4, TN = 4, FC = 16;
  constexpr int F = CIN * 9;
  constexpr int HI = HO / 2, WI = WO / 2;
  constexpr int M = BATCH * HO * WO;
  constexpr int FPB = F / SK;

  __shared__ float Ae[FC * 9][BM];

  const int t = threadIdx.x;
  const int mbase = blockIdx.x * BM;
  const int obase = blockIdx.y * BN;
  const int f0 = blockIdx.z * FPB;

  const int cg = t & (BN / TN - 1);
  const int rg = t / (BN / TN);
  const int m0 = rg * TM;
  const int o0 = obase + cg * TN;

  float acc[TM][TN] = {};

  for (int fc = f0; fc < f0 + FPB; fc += FC) {
#pragma unroll
    for (int j = 0; j < BM * FC / 256; ++j) {
      int p = j * 256 + t;
      int ml = p & (BM - 1);
      int df = p >> 6;
      int f = fc + df;
      int c = f / 9;
      int r = f - c * 9;
      int kh = r / 3, kw = r - kh * 3;
      int m = mbase + ml;
      int bb = m / (HO * WO);
      int rem = m % (HO * WO);
      int hh = rem / WO, ww = rem % WO;
      int hp = hh + kh - 1, wp = ww + kw - 1;
      float val = 0.f;
      if (hp >= 0 && hp < HO && wp >= 0 && wp < WO)
        val = in[((bb * CIN + c) * HI + (hp >> 1)) * WI + (wp >> 1)];
      float e[9];
      expand9(val, e);
#pragma unroll
      for (int v = 0; v < 9; ++v) Ae[df * 9 + v][ml] = e[v];
    }
    __syncthreads();

#pragma unroll 2
    for (int df = 0; df < FC; ++df) {
      int f = fc + df;
      float wb[TN], wsv[TN][8];
#pragma unroll
      for (int tn = 0; tn < TN; ++tn) {
        int i = (o0 + tn) * F + f;
        wb[tn] = bw[i];
        float sc = ss[i];
        const float4* sp = reinterpret_cast<const float4*>(sw + (size_t)i * 8);
        float4 s0 = sp[0], s1 = sp[1];
        wsv[tn][0] = s0.x * sc; wsv[tn][1] = s0.y * sc;
        wsv[tn][2] = s0.z * sc; wsv[tn][3] = s0.w * sc;
        wsv[tn][4] = s1.x * sc; wsv[tn][5] = s1.y * sc;
        wsv[tn][6] = s1.z * sc; wsv[tn][7] = s1.w * sc;
      }
      float a[9][TM];
#pragma unroll
      for (int v = 0; v < 9; ++v) {
        float4 q = *reinterpret_cast<const float4*>(&Ae[df * 9 + v][m0]);
        a[v][0] = q.x; a[v][1] = q.y; a[v][2] = q.z; a[v][3] = q.w;
      }
#pragma unroll
      for (int tm = 0; tm < TM; ++tm)
#pragma unroll
        for (int tn = 0; tn < TN; ++tn) acc[tm][tn] += a[0][tm] * wb[tn];
#pragma unroll
      for (int v = 1; v < 9; ++v)
#pragma unroll
        for (int tm = 0; tm < TM; ++tm)
#pragma unroll
          for (int tn = 0; tn < TN; ++tn)
            acc[tm][tn] += a[v][tm] * wsv[tn][v - 1];
    }
    __syncthreads();
  }

  if constexpr (SK > 1) {
    float* p = outp + (size_t)blockIdx.z * M * COUT;
#pragma unroll
    for (int tm = 0; tm < TM; ++tm) {
      int m = mbase + m0 + tm;
#pragma unroll
      for (int tn = 0; tn < TN; ++tn)
        p[(size_t)m * COUT + (o0 + tn)] = acc[tm][tn];
    }
  } else {
#pragma unroll
    for (int tm = 0; tm < TM; ++tm) {
      int m = mbase + m0 + tm;
      int bb = m / (HO * WO);
      int rem = m % (HO * WO);
      int hh = rem / WO, ww = rem % WO;
#pragma unroll
      for (int tn = 0; tn < TN; ++tn) {
        int o = o0 + tn;
        outp[((bb * COUT + o) * HO + hh) * WO + ww] = acc[tm][tn];
      }
    }
  }
}

template <int COUT, int HO, int WO, int SK>
__global__ __launch_bounds__(256) void reduce_partials_old(
    const float* __restrict__ part, float* __restrict__ act) {
  constexpr int M = BATCH * HO * WO;
  int idx = blockIdx.x * 256 + threadIdx.x;
  if (idx >= M * COUT) return;
  float s = 0.f;
#pragma unroll
  for (int k = 0; k < SK; ++k) s += part[(size_t)k * M * COUT + idx];
  int m = idx / COUT, o = idx - (idx / COUT) * COUT;
  int bb = m / (HO * WO);
  int rem = m % (HO * WO);
  int hh = rem / WO, ww = rem % WO;
  act[((bb * COUT + o) * HO + hh) * WO + ww] = s;
}

__global__ __launch_bounds__(256) void kan_l4_split(
    const float* __restrict__ a3, const float* __restrict__ bw,
    const float* __restrict__ sw, const float* __restrict__ ss,
    float* __restrict__ p4) {
  int tid = blockIdx.x * 256 + threadIdx.x;
  int cs = tid >> 16, pix = tid & 65535;
  int b = pix >> 10, rem = pix & 1023, h = rem >> 5, w = rem & 31;
  float acc[3] = {0.f, 0.f, 0.f};
  for (int c = cs * 16; c < cs * 16 + 16; ++c) {
#pragma unroll
    for (int kh = 0; kh < 3; ++kh) {
#pragma unroll
      for (int kw = 0; kw < 3; ++kw) {
        int f = (c * 3 + kh) * 3 + kw;
        int hp = h + kh - 1, wp = w + kw - 1;
        float x = 0.f;
        if ((unsigned)hp < 32u && (unsigned)wp < 32u)
          x = a3[((b * 64 + c) * 16 + (hp >> 1)) * 16 + (wp >> 1)];
        float e[9];
        expand9(x, e);
#pragma unroll
        for (int o = 0; o < 3; ++o) {
          int i = o * 576 + f;
          float d = e[1] * sw[i * 8 + 0];
#pragma unroll
          for (int v = 1; v < 8; ++v) d += e[v + 1] * sw[i * 8 + v];
          acc[o] += e[0] * bw[i] + d * ss[i];
        }
      }
    }
  }
#pragma unroll
  for (int o = 0; o < 3; ++o)
    p4[cs * 196608 + ((b * 3 + o) << 10) + (h << 5) + w] = acc[o];
}

// ---------------------------------------------------------------------------
extern "C" void kernel_launch(void* const* d_in, const int* in_sizes, int n_in,
                              void* d_out, int out_size, void* d_ws,
                              size_t ws_size, hipStream_t stream) {
  const float* x     = (const float*)d_in[0];
  const float* lin_w = (const float*)d_in[1];
  const float* lin_b = (const float*)d_in[2];
  const float* bw1 = (const float*)d_in[3];
  const float* sw1 = (const float*)d_in[4];
  const float* ss1 = (const float*)d_in[5];
  const float* bw2 = (const float*)d_in[6];
  const float* sw2 = (const float*)d_in[7];
  const float* ss2 = (const float*)d_in[8];
  const float* bw3 = (const float*)d_in[9];
  const float* sw3 = (const float*)d_in[10];
  const float* ss3 = (const float*)d_in[11];
  const float* bw4 = (const float*)d_in[12];
  const float* sw4 = (const float*)d_in[13];
  const float* ss4 = (const float*)d_in[14];

  float* wsf = (float*)d_ws;
  float* h  = wsf;                        // 131072
  float* a1 = h + 131072;                 // 262144 (fallback only)
  float* a2 = a1 + 262144;                // 524288 (fallback only)
  float* a3 = a2 + 524288;                // 1048576, ends at 1966080
  // main-path regions
  unsigned short* Bg = (unsigned short*)(wsf + 1966080);  // 10,616,832 float-slots
  float* part = wsf + 1966080 + 10616832;                 // 2,097,152
  uint32_t* Eg = (uint32_t*)(wsf + 14680064);             // 4,718,592
  float* wl4 = h;                    // h dead on main path after linear (27648 floats)
  float* p4  = wsf + 1966080;        // 16*196608 = 3.1M, reuses Bg (dead post-L3)

  const size_t baseFloats = 1966080;
  size_t availFloats = ws_size / 4 > baseFloats ? ws_size / 4 - baseFloats : 0;
  const size_t mainNeed = 10616832ull + 2097152ull + 4718592ull;  // 17.4M

  if (availFloats >= mainNeed) {
    linear_pack_kernel<<<512, 256, 0, stream>>>(x, lin_w, lin_b, h, Eg, 1);

    // L1: CIN=512 COUT=256 4x4, SK=8
    prep_bpack<4608, 256><<<41472, 256, 0, stream>>>(bw1, sw1, ss1, Bg);
    gemm_mfma<512, 256, 4, 4, 8>
        <<<dim3(16, 4, 8), 256, 0, stream>>>(Eg, Bg, part);
    reduce_pe_pack<256, 4, 4><<<1024, 256, 0, stream>>>(part, Eg, 8);

    // L2: CIN=256 COUT=128 8x8, SK=4
    prep_bpack<2304, 128><<<10368, 256, 0, stream>>>(bw2, sw2, ss2, Bg);
    gemm_mfma<256, 128, 8, 8, 4>
        <<<dim3(64, 2, 4), 256, 0, stream>>>(Eg, Bg, part);
    reduce_pe_pack<128, 8, 8><<<2048, 256, 0, stream>>>(part, Eg, 4);

    // L3: CIN=128 COUT=64 16x16, SK=2
    prep_bpack<1152, 64><<<2592, 256, 0, stream>>>(bw3, sw3, ss3, Bg);
    gemm_mfma<128, 64, 16, 16, 2>
        <<<dim3(256, 1, 2), 256, 0, stream>>>(Eg, Bg, part);
    reduce_p<64, 16, 16><<<4096, 256, 0, stream>>>(part, a3, 2);

    // L4: fused LDS expansion + pre-summed weights (round-10 proven)
    prep_wnl4<<<108, 256, 0, stream>>>(bw4, sw4, ss4, wl4);
    kan_l4_v7<<<1024, 256, 0, stream>>>(a3, wl4, p4);
    reduce_tanh_l4_16<<<768, 256, 0, stream>>>(p4, (float*)d_out);
  } else {
    // round-1 proven fallback (needs ~16.3 MB)
    float* partOld = a3 + 1048576;
    linear_pack_kernel<<<512, 256, 0, stream>>>(x, lin_w, lin_b, h, nullptr, 0);
    kan_gemm<512, 256, 4, 4, 64, 8>
        <<<dim3(16, 4, 8), 256, 0, stream>>>(h, bw1, sw1, ss1, partOld);
    reduce_partials_old<256, 4, 4, 8><<<1024, 256, 0, stream>>>(partOld, a1);
    kan_gemm<256, 128, 8, 8, 64, 2>
        <<<dim3(64, 2, 2), 256, 0, stream>>>(a1, bw2, sw2, ss2, partOld);
    reduce_partials_old<128, 8, 8, 2><<<2048, 256, 0, stream>>>(partOld, a2);
    kan_gemm<128, 64, 16, 16, 64, 1>
        <<<dim3(256, 1, 1), 256, 0, stream>>>(a2, bw3, sw3, ss3, a3);
    kan_l4_split<<<1024, 256, 0, stream>>>(a3, bw4, sw4, ss4, partOld);
    reduce_tanh_l4<<<768, 256, 0, stream>>>(partOld, (float*)d_out);
  }
}

// Round 17
// 395.977 us; speedup vs baseline: 2.3302x; 1.0317x over previous
//
#include <hip/hip_runtime.h>
#include <cstdint>
#include <cmath>

#define BATCH 64

typedef __attribute__((ext_vector_type(8))) __bf16 bf16x8;
typedef __attribute__((ext_vector_type(16))) float f32x16;

// ---------------------------------------------------------------------------
// Spline + silu expansion: x -> [silu(x), B_0(x) .. B_7(x)]
// ---------------------------------------------------------------------------
__device__ __forceinline__ void expand9(float x, float* e) {
  float t = __expf(-x);
  e[0] = __fdividef(x, 1.f + t);  // silu
  float b[11];
#pragma unroll
  for (int j = 0; j < 11; ++j) {
    float gj  = 0.4f * (float)j - 2.2f;
    float gj1 = 0.4f * (float)(j + 1) - 2.2f;
    b[j] = (x >= gj && x < gj1) ? 1.f : 0.f;
  }
#pragma unroll
  for (int k = 1; k <= 3; ++k) {
    float inv = 1.f / (0.4f * (float)k);
#pragma unroll
    for (int j = 0; j < 11 - k; ++j) {
      float gj   = 0.4f * (float)j - 2.2f;
      float gjk1 = 0.4f * (float)(j + k + 1) - 2.2f;
      b[j] = ((x - gj) * b[j] + (gjk1 - x) * b[j + 1]) * inv;
    }
  }
#pragma unroll
  for (int v = 0; v < 8; ++v) e[v + 1] = b[v];
}

// bf16 split helpers (round-to-nearest-even)
__device__ __forceinline__ unsigned short f2bf(float x) {
  uint32_t u = __float_as_uint(x);
  uint32_t r = u + 0x7fffu + ((u >> 16) & 1u);
  return (unsigned short)(r >> 16);
}
__device__ __forceinline__ float bf2f(unsigned short h) {
  return __uint_as_float(((uint32_t)h) << 16);
}
__device__ __forceinline__ uint32_t packsplit(float x) {
  unsigned short hi = f2bf(x);
  unsigned short lo = f2bf(x - bf2f(hi));
  return (uint32_t)hi | ((uint32_t)lo << 16);
}

// ---------------------------------------------------------------------------
// h = relu(x @ lin_w^T + lin_b); also writes packed expansion E (12-stride,
// 16B-aligned per pixel -> gemm gathers with 3 dwordx4 loads per tap).
// ---------------------------------------------------------------------------
__global__ __launch_bounds__(256) void linear_pack_kernel(
    const float* __restrict__ x, const float* __restrict__ w,
    const float* __restrict__ bias, float* __restrict__ h,
    uint32_t* __restrict__ E, int writeE) {
  int idx = blockIdx.x * 256 + threadIdx.x;  // 64*2048
  int b = idx >> 11, o = idx & 2047;
  const float* xr = x + b * 100;
  const float* wr = w + o * 100;
  float acc = bias[o];
#pragma unroll 4
  for (int k = 0; k < 100; ++k) acc += xr[k] * wr[k];
  float hv = fmaxf(acc, 0.f);
  h[idx] = hv;
  if (writeE) {
    float e[9];
    expand9(hv, e);
    uint32_t u0 = packsplit(e[0]), u1 = packsplit(e[1]), u2 = packsplit(e[2]);
    uint32_t u3 = packsplit(e[3]), u4 = packsplit(e[4]), u5 = packsplit(e[5]);
    uint32_t u6 = packsplit(e[6]), u7 = packsplit(e[7]), u8 = packsplit(e[8]);
    uint4* p = reinterpret_cast<uint4*>(E + (size_t)idx * 12);
    p[0] = make_uint4(u0, u1, u2, u3);
    p[1] = make_uint4(u4, u5, u6, u7);
    p[2] = make_uint4(u8, 0u, 0u, 0u);
  }
}

// ---------------------------------------------------------------------------
// Pack expanded weights (bf16-hi ONLY) into MFMA layout:
// Bg[kc][v(9)][n(N)][fl(16)]  (bf16)
// ---------------------------------------------------------------------------
template <int F, int N>
__global__ __launch_bounds__(256) void prep_bpack(
    const float* __restrict__ bw, const float* __restrict__ sw,
    const float* __restrict__ ss, unsigned short* __restrict__ Bg) {
  int idx = blockIdx.x * 256 + threadIdx.x;  // over (F/16)*9*N*16
  int fl = idx & 15;
  int n = (idx >> 4) & (N - 1);
  int rest = idx >> 4;
  rest /= N;
  int v = rest % 9;
  int kc = rest / 9;
  int f = kc * 16 + fl;
  size_t src = (size_t)n * F + f;
  float wv = (v == 0) ? bw[src] : sw[src * 8 + (v - 1)] * ss[src];
  Bg[((size_t)kc * 9 + v) * N * 16 + (size_t)n * 16 + fl] = f2bf(wv);
}

// ---------------------------------------------------------------------------
// bf16 MFMA GEMM (round 17): single product ah*bh (error budget measured:
// A-trunc added 1e-3 in round 16; B-trunc symmetric -> est absmax ~4e-3,
// threshold 9.9e-3). Per chunk: MFMA 18->9, frag reads 27->18, B-stage and
// Bg halve, LDS 55.3->36.9KB -> 3 blocks/CU. A-gather: E is 12-stride so
// each tap is 3 aligned dwordx4 loads (was 9 scalar dwords).
// ---------------------------------------------------------------------------
template <int CIN, int COUT, int HO, int WO, int SK>
__global__ __launch_bounds__(256, 3) void gemm_mfma(
    const uint32_t* __restrict__ E, const unsigned short* __restrict__ Bg,
    float* __restrict__ part) {
  constexpr int F = CIN * 9;
  constexpr int NKC = F / 16;
  constexpr int HI = HO / 2, WI = WO / 2;
  constexpr int M = BATCH * HO * WO;
  constexpr int CPB = NKC / SK;
  static_assert(NKC % SK == 0, "sk");

  // plane 0: A-hi [9][64][16]; plane 1: B-hi
  __shared__ __align__(16) unsigned short lds[2 * 9216];

  const int t = threadIdx.x;
  const int mbase = blockIdx.x * 64;
  const int nb = blockIdx.y;
  const int kc0 = blockIdx.z * CPB;

  uint32_t ez[9];
  {
    float e0[9];
    expand9(0.f, e0);
#pragma unroll
    for (int v = 0; v < 9; ++v) ez[v] = packsplit(e0[v]);
  }

  const int lane = t & 63, wv_ = t >> 6;
  const int wm = wv_ >> 1, wn = wv_ & 1;
  const int frow = lane & 31, fkg = lane >> 5;
  const int aoff = ((wm * 32 + frow) * 16 + fkg * 8) * 2;  // bytes
  const int boff = ((wn * 32 + frow) * 16 + fkg * 8) * 2;

  // A-staging geometry: thread covers row aml, fl = flq*4..+3
  const int aml = t >> 2, flq = t & 3;
  const int am = mbase + aml;
  const int ab = am / (HO * WO), ahw = am % (HO * WO);
  const int ahh = ahw / WO, aww = ahw % WO;

  f32x16 acc;
#pragma unroll
  for (int i = 0; i < 16; ++i) acc[i] = 0.f;

  for (int ci = 0; ci < CPB; ++ci) {
    const int kc = kc0 + ci;
    __syncthreads();

    // ---- stage A (hi only): 4 taps/thread, 3 dwordx4 loads per tap ----
    {
      uint32_t w0[9], w1[9], w2[9], w3[9];
#define LDTAP(IDX, DST)                                                       \
  {                                                                           \
    int f = kc * 16 + flq * 4 + IDX;                                          \
    int c = f / 9, r = f - 9 * c;                                             \
    int kh = r / 3, kw = r - kh * 3;                                          \
    int hp = ahh + kh - 1, wp = aww + kw - 1;                                 \
    if ((unsigned)hp < (unsigned)HO && (unsigned)wp < (unsigned)WO) {         \
      const uint4* ep4 = reinterpret_cast<const uint4*>(                      \
          E + (size_t)(((ab * CIN + c) * HI + (hp >> 1)) * WI + (wp >> 1)) *  \
                  12);                                                        \
      uint4 q0 = ep4[0], q1 = ep4[1], q2 = ep4[2];                            \
      DST[0] = q0.x; DST[1] = q0.y; DST[2] = q0.z; DST[3] = q0.w;             \
      DST[4] = q1.x; DST[5] = q1.y; DST[6] = q1.z; DST[7] = q1.w;             \
      DST[8] = q2.x;                                                          \
    } else {                                                                  \
      _Pragma("unroll") for (int v = 0; v < 9; ++v) DST[v] = ez[v];           \
    }                                                                         \
  }
      LDTAP(0, w0)
      LDTAP(1, w1)
      LDTAP(2, w2)
      LDTAP(3, w3)
#undef LDTAP
      char* lb = reinterpret_cast<char*>(lds);
#pragma unroll
      for (int v = 0; v < 9; ++v) {
        uint32_t hi01 = (w0[v] & 0xffffu) | (w1[v] << 16);
        uint32_t hi23 = (w2[v] & 0xffffu) | (w3[v] << 16);
        *reinterpret_cast<uint2*>(lb + v * 2048 + aml * 32 + flq * 8) =
            make_uint2(hi01, hi23);
      }
    }

    // ---- stage B: one plane, 1152 float4s over 256 threads ----
    {
      const unsigned short* bsrc = Bg + (size_t)kc * (9 * COUT * 16);
#define STAGEB(U)                                                             \
  {                                                                           \
    int u = (U);                                                              \
    int v = u >> 7, q = u & 127;                                              \
    int nl = q >> 1, half = q & 1;                                            \
    size_t srcE = (size_t)v * (COUT * 16) + (size_t)(nb * 64 + nl) * 16 +     \
                  half * 8;                                                   \
    int dst = 9216 + v * 1024 + nl * 16 + half * 8;                           \
    *reinterpret_cast<float4*>(&lds[dst]) =                                   \
        *reinterpret_cast<const float4*>(&bsrc[srcE]);                        \
  }
      STAGEB(t)
      STAGEB(256 + t)
      STAGEB(512 + t)
      STAGEB(768 + t)
      if (t < 128) STAGEB(1024 + t)
#undef STAGEB
    }
    __syncthreads();

    // ---- compute: 9 v-steps x 1 product ----
#pragma unroll
    for (int v = 0; v < 9; ++v) {
      const char* lbc = reinterpret_cast<const char*>(lds);
      bf16x8 ah = *reinterpret_cast<const bf16x8*>(lbc + v * 2048 + aoff);
      bf16x8 bh =
          *reinterpret_cast<const bf16x8*>(lbc + 18432 + v * 2048 + boff);
      acc = __builtin_amdgcn_mfma_f32_32x32x16_bf16(ah, bh, acc, 0, 0, 0);
    }
  }

  // ---- epilogue: C/D layout col=lane&31, row=(reg&3)+8*(reg>>2)+4*(lane>>5)
  float* p = part + (size_t)blockIdx.z * M * COUT;
  const int gn = nb * 64 + wn * 32 + frow;
#pragma unroll
  for (int r = 0; r < 16; ++r) {
    int mlocal = (r & 3) + 8 * (r >> 2) + 4 * fkg;
    int gm = mbase + wm * 32 + mlocal;
    p[(size_t)gm * COUT + gn] = acc[r];
  }
}

// ---------------------------------------------------------------------------
// Reduce split-K partials -> activation; write packed 12-stride expansion E.
// ---------------------------------------------------------------------------
template <int COUT, int HO, int WO>
__global__ __launch_bounds__(256) void reduce_pe_pack(
    const float* __restrict__ part, uint32_t* __restrict__ E, int SK) {
  constexpr int M = BATCH * HO * WO;
  int idx = blockIdx.x * 256 + threadIdx.x;
  int ww = idx % WO;
  int tmp = idx / WO;
  int hh = tmp % HO;
  tmp /= HO;
  int o = tmp % COUT;
  int b = tmp / COUT;
  int m = (b * HO + hh) * WO + ww;
  float s = 0.f;
  for (int k = 0; k < SK; ++k) s += part[((size_t)k * M + m) * COUT + o];
  float e[9];
  expand9(s, e);
  uint32_t u0 = packsplit(e[0]), u1 = packsplit(e[1]), u2 = packsplit(e[2]);
  uint32_t u3 = packsplit(e[3]), u4 = packsplit(e[4]), u5 = packsplit(e[5]);
  uint32_t u6 = packsplit(e[6]), u7 = packsplit(e[7]), u8 = packsplit(e[8]);
  uint4* p = reinterpret_cast<uint4*>(E + (size_t)idx * 12);
  p[0] = make_uint4(u0, u1, u2, u3);
  p[1] = make_uint4(u4, u5, u6, u7);
  p[2] = make_uint4(u8, 0u, 0u, 0u);
}

template <int COUT, int HO, int WO>
__global__ __launch_bounds__(256) void reduce_p(
    const float* __restrict__ part, float* __restrict__ act, int SK) {
  constexpr int M = BATCH * HO * WO;
  int idx = blockIdx.x * 256 + threadIdx.x;
  int ww = idx % WO;
  int tmp = idx / WO;
  int hh = tmp % HO;
  tmp /= HO;
  int o = tmp % COUT;
  int b = tmp / COUT;
  int m = (b * HO + hh) * WO + ww;
  float s = 0.f;
  for (int k = 0; k < SK; ++k) s += part[((size_t)k * M + m) * COUT + o];
  act[idx] = s;
}

// ---------------------------------------------------------------------------
// L4 weights, neighbor-pre-summed:
// Wn[c][pc][nb][v][o] = sum over taps mapping to neighbor nb under parity pc.
// ---------------------------------------------------------------------------
__global__ __launch_bounds__(256) void prep_wnl4(
    const float* __restrict__ bw, const float* __restrict__ sw,
    const float* __restrict__ ss, float* __restrict__ Wn) {
  int idx = blockIdx.x * 256 + threadIdx.x;  // 64*4*4*27 = 27648
  if (idx >= 27648) return;
  int u = idx % 27;
  int o = u % 3, v = u / 3;
  int rest = idx / 27;
  int nb = rest & 3;
  rest >>= 2;
  int pc = rest & 3;
  rest >>= 2;
  int c = rest;  // 0..63
  int PH = pc >> 1, PW = pc & 1;
  int a = nb >> 1, b2 = nb & 1;
  float s = 0.f;
#pragma unroll
  for (int kh = 0; kh < 3; ++kh) {
    if (((kh > PH) ? 1 : 0) != a) continue;
#pragma unroll
    for (int kw = 0; kw < 3; ++kw) {
      if (((kw > PW) ? 1 : 0) != b2) continue;
      int f = c * 9 + kh * 3 + kw;
      float wv = (v == 0)
                     ? bw[o * 576 + f]
                     : sw[((size_t)(o * 576 + f)) * 8 + (v - 1)] * ss[o * 576 + f];
      s += wv;
    }
  }
  Wn[idx] = s;
}

// ---------------------------------------------------------------------------
// L4 v7 (round-10 proven): spill-free skeleton + pre-summed weights.
// ---------------------------------------------------------------------------
template <int PH, int PW>
__device__ void l4v7_wave(const float* __restrict__ eLds,
                          const float* __restrict__ WnB,
                          const float* __restrict__ ez, int lane, int bb,
                          int cs, float* __restrict__ p4) {
  constexpr int PC = PH * 2 + PW;
  const int j = lane & 15;
  const int i0 = (lane >> 4) << 2;
#pragma unroll 1
  for (int q = 0; q < 4; ++q) {
    const int i = i0 + q;
    float acc[3] = {0.f, 0.f, 0.f};
#pragma unroll
    for (int a = 0; a < 2; ++a) {
      const int gi = i + PH - 1 + a;
      const bool vr = (unsigned)gi < 16u;
#pragma unroll
      for (int b2 = 0; b2 < 2; ++b2) {
        const int gj = j + PW - 1 + b2;
        const bool ok = vr && ((unsigned)gj < 16u);
        const int pp = ok ? (gi * 16 + gj) : 0;  // clamped safe address
        const int nbi = a * 2 + b2;
#pragma unroll
        for (int cl = 0; cl < 4; ++cl) {
          const float* ep = eLds + cl * 2304 + pp * 9;
          float en[9];
#pragma unroll
          for (int v = 0; v < 9; ++v) en[v] = ok ? ep[v] : ez[v];
          const float* wp = WnB + ((cl * 4 + PC) * 4 + nbi) * 27;
#pragma unroll
          for (int v = 0; v < 9; ++v) {
            acc[0] = fmaf(en[v], wp[v * 3 + 0], acc[0]);
            acc[1] = fmaf(en[v], wp[v * 3 + 1], acc[1]);
            acc[2] = fmaf(en[v], wp[v * 3 + 2], acc[2]);
          }
        }
      }
    }
    const int h = (i << 1) + PH, w = (j << 1) + PW;
#pragma unroll
    for (int o = 0; o < 3; ++o)
      p4[(size_t)cs * 196608 + ((bb * 3 + o) << 10) + (h << 5) + w] = acc[o];
  }
}

__global__ __launch_bounds__(256) void kan_l4_v7(
    const float* __restrict__ a3, const float* __restrict__ Wn,
    float* __restrict__ p4) {
  __shared__ float eLds[4 * 256 * 9];  // 36.9 KB
  const int bid = blockIdx.x;          // 64 bb x 16 cs
  const int bb = bid >> 4, cs = bid & 15;
  const int t = threadIdx.x;
  float ez[9];
  expand9(0.f, ez);
#pragma unroll
  for (int cl = 0; cl < 4; ++cl) {
    float x = a3[(size_t)(bb * 64 + cs * 4 + cl) * 256 + t];
    float ev[9];
    expand9(x, ev);
#pragma unroll
    for (int v = 0; v < 9; ++v) eLds[(cl * 256 + t) * 9 + v] = ev[v];
  }
  __syncthreads();
  const int wv_ = t >> 6, lane = t & 63;
  const float* WnB = Wn + (size_t)cs * 4 * (4 * 4 * 27);
  if (wv_ == 0)
    l4v7_wave<0, 0>(eLds, WnB, ez, lane, bb, cs, p4);
  else if (wv_ == 1)
    l4v7_wave<0, 1>(eLds, WnB, ez, lane, bb, cs, p4);
  else if (wv_ == 2)
    l4v7_wave<1, 0>(eLds, WnB, ez, lane, bb, cs, p4);
  else
    l4v7_wave<1, 1>(eLds, WnB, ez, lane, bb, cs, p4);
}

__global__ __launch_bounds__(256) void reduce_tanh_l4_16(
    const float* __restrict__ p4, float* __restrict__ out) {
  int i = blockIdx.x * 256 + threadIdx.x;  // 196608
  float s = 0.f;
#pragma unroll
  for (int k = 0; k < 16; ++k) s += p4[(size_t)k * 196608 + i];
  out[i] = tanhf(s);
}

__global__ __launch_bounds__(256) void reduce_tanh_l4(
    const float* __restrict__ p4, float* __restrict__ out) {
  int i = blockIdx.x * 256 + threadIdx.x;
  float s = p4[i] + p4[i + 196608] + p4[i + 2 * 196608] + p4[i + 3 * 196608];
  out[i] = tanhf(s);
}

// ---------------------------------------------------------------------------
// Fallback path (round-1 proven) for small workspace
// ---------------------------------------------------------------------------
template <int CIN, int COUT, int HO, int WO, int BN, int SK>
__global__ __launch_bounds__(256) void kan_gemm(
    const float* __restrict__ in, const float* __restrict__ bw,
    const float* __restrict__ sw, const float* __restrict__ ss,
    float* __restrict__ outp) {
  constexpr int BM = 64, TM = 4, TN = 4, FC = 16;
  constexpr int F = CIN * 9;
  constexpr int HI = HO / 2, WI = WO / 2;
  constexpr int M = BATCH * HO * WO;
  constexpr int FPB = F / SK;

  __shared__ float Ae[FC * 9][BM];

  const int t = threadIdx.x;
  const int mbase = blockIdx.x * BM;
  const int obase = blockIdx.y * BN;
  const int f0 = blockIdx.z * FPB;

  const int cg = t & (BN / TN - 1);
  const int rg = t / (BN / TN);
  const int m0 = rg * TM;
  const int o0 = obase + cg * TN;

  float acc[TM][TN] = {};

  for (int fc = f0; fc < f0 + FPB; fc += FC) {
#pragma unroll
    for (int j = 0; j < BM * FC / 256; ++j) {
      int p = j * 256 + t;
      int ml = p & (BM - 1);
      int df = p >> 6;
      int f = fc + df;
      int c = f / 9;
      int r = f - c * 9;
      int kh = r / 3, kw = r - kh * 3;
      int m = mbase + ml;
      int bb = m / (HO * WO);
      int rem = m % (HO * WO);
      int hh = rem / WO, ww = rem % WO;
      int hp = hh + kh - 1, wp = ww + kw - 1;
      float val = 0.f;
      if (hp >= 0 && hp < HO && wp >= 0 && wp < WO)
        val = in[((bb * CIN + c) * HI + (hp >> 1)) * WI + (wp >> 1)];
      float e[9];
      expand9(val, e);
#pragma unroll
      for (int v = 0; v < 9; ++v) Ae[df * 9 + v][ml] = e[v];
    }
    __syncthreads();

#pragma unroll 2
    for (int df = 0; df < FC; ++df) {
      int f = fc + df;
      float wb[TN], wsv[TN][8];
#pragma unroll
      for (int tn = 0; tn < TN; ++tn) {
        int i = (o0 + tn) * F + f;
        wb[tn] = bw[i];
        float sc = ss[i];
        const float4* sp = reinterpret_cast<const float4*>(sw + (size_t)i * 8);
        float4 s0 = sp[0], s1 = sp[1];
        wsv[tn][0] = s0.x * sc; wsv[tn][1] = s0.y * sc;
        wsv[tn][2] = s0.z * sc; wsv[tn][3] = s0.w * sc;
        wsv[tn][4] = s1.x * sc; wsv[tn][5] = s1.y * sc;
        wsv[tn][6] = s1.z * sc; wsv[tn][7] = s1.w * sc;
      }
      float a[9][TM];
#pragma unroll
      for (int v = 0; v < 9; ++v) {
        float4 q = *reinterpret_cast<const float4*>(&Ae[df * 9 + v][m0]);
        a[v][0] = q.x; a[v][1] = q.y; a[v][2] = q.z; a[v][3] = q.w;
      }
#pragma unroll
      for (int tm = 0; tm < TM; ++tm)
#pragma unroll
        for (int tn = 0; tn < TN; ++tn) acc[tm][tn] += a[0][tm] * wb[tn];
#pragma unroll
      for (int v = 1; v < 9; ++v)
#pragma unroll
        for (int tm = 0; tm < TM; ++tm)
#pragma unroll
          for (int tn = 0; tn < TN; ++tn)
            acc[tm][tn] += a[v][tm] * wsv[tn][v - 1];
    }
    __syncthreads();
  }

  if constexpr (SK > 1) {
    float* p = outp + (size_t)blockIdx.z * M * COUT;
#pragma unroll
    for (int tm = 0; tm < TM; ++tm) {
      int m = mbase + m0 + tm;
#pragma unroll
      for (int tn = 0; tn < TN; ++tn)
        p[(size_t)m * COUT + (o0 + tn)] = acc[tm][tn];
    }
  } else {
#pragma unroll
    for (int tm = 0; tm < TM; ++tm) {
      int m = mbase + m0 + tm;
      int bb = m / (HO * WO);
      int rem = m % (HO * WO);
      int hh = rem / WO, ww = rem % WO;
#pragma unroll
      for (int tn = 0; tn < TN; ++tn) {
        int o = o0 + tn;
        outp[((bb * COUT + o) * HO + hh) * WO + ww] = acc[tm][tn];
      }
    }
  }
}

template <int COUT, int HO, int WO, int SK>
__global__ __launch_bounds__(256) void reduce_partials_old(
    const float* __restrict__ part, float* __restrict__ act) {
  constexpr int M = BATCH * HO * WO;
  int idx = blockIdx.x * 256 + threadIdx.x;
  if (idx >= M * COUT) return;
  float s = 0.f;
#pragma unroll
  for (int k = 0; k < SK; ++k) s += part[(size_t)k * M * COUT + idx];
  int m = idx / COUT, o = idx - (idx / COUT) * COUT;
  int bb = m / (HO * WO);
  int rem = m % (HO * WO);
  int hh = rem / WO, ww = rem % WO;
  act[((bb * COUT + o) * HO + hh) * WO + ww] = s;
}

__global__ __launch_bounds__(256) void kan_l4_split(
    const float* __restrict__ a3, const float* __restrict__ bw,
    const float* __restrict__ sw, const float* __restrict__ ss,
    float* __restrict__ p4) {
  int tid = blockIdx.x * 256 + threadIdx.x;
  int cs = tid >> 16, pix = tid & 65535;
  int b = pix >> 10, rem = pix & 1023, h = rem >> 5, w = rem & 31;
  float acc[3] = {0.f, 0.f, 0.f};
  for (int c = cs * 16; c < cs * 16 + 16; ++c) {
#pragma unroll
    for (int kh = 0; kh < 3; ++kh) {
#pragma unroll
      for (int kw = 0; kw < 3; ++kw) {
        int f = (c * 3 + kh) * 3 + kw;
        int hp = h + kh - 1, wp = w + kw - 1;
        float x = 0.f;
        if ((unsigned)hp < 32u && (unsigned)wp < 32u)
          x = a3[((b * 64 + c) * 16 + (hp >> 1)) * 16 + (wp >> 1)];
        float e[9];
        expand9(x, e);
#pragma unroll
        for (int o = 0; o < 3; ++o) {
          int i = o * 576 + f;
          float d = e[1] * sw[i * 8 + 0];
#pragma unroll
          for (int v = 1; v < 8; ++v) d += e[v + 1] * sw[i * 8 + v];
          acc[o] += e[0] * bw[i] + d * ss[i];
        }
      }
    }
  }
#pragma unroll
  for (int o = 0; o < 3; ++o)
    p4[cs * 196608 + ((b * 3 + o) << 10) + (h << 5) + w] = acc[o];
}

// ---------------------------------------------------------------------------
extern "C" void kernel_launch(void* const* d_in, const int* in_sizes, int n_in,
                              void* d_out, int out_size, void* d_ws,
                              size_t ws_size, hipStream_t stream) {
  const float* x     = (const float*)d_in[0];
  const float* lin_w = (const float*)d_in[1];
  const float* lin_b = (const float*)d_in[2];
  const float* bw1 = (const float*)d_in[3];
  const float* sw1 = (const float*)d_in[4];
  const float* ss1 = (const float*)d_in[5];
  const float* bw2 = (const float*)d_in[6];
  const float* sw2 = (const float*)d_in[7];
  const float* ss2 = (const float*)d_in[8];
  const float* bw3 = (const float*)d_in[9];
  const float* sw3 = (const float*)d_in[10];
  const float* ss3 = (const float*)d_in[11];
  const float* bw4 = (const float*)d_in[12];
  const float* sw4 = (const float*)d_in[13];
  const float* ss4 = (const float*)d_in[14];

  float* wsf = (float*)d_ws;
  // ---- main-path layout (round 17): total 14,876,672 floats = 59.5 MB ----
  float* h    = wsf;                                       // 131072 (wl4 alias)
  float* a3   = wsf + 131072;                              // 1048576
  unsigned short* Bg = (unsigned short*)(wsf + 1179648);   // 5,308,416 floats
  float* part = wsf + 6488064;                             // 2,097,152
  uint32_t* Eg = (uint32_t*)(wsf + 8585216);               // 6,291,456 (12/pix)
  float* wl4 = h;
  float* p4  = wsf + 1179648;  // aliases Bg (dead post-L3), 3.1M floats

  const size_t mainNeed = 14876672ull;

  if (ws_size / 4 >= mainNeed) {
    linear_pack_kernel<<<512, 256, 0, stream>>>(x, lin_w, lin_b, h, Eg, 1);

    // L1: CIN=512 COUT=256 4x4, SK=8
    prep_bpack<4608, 256><<<41472, 256, 0, stream>>>(bw1, sw1, ss1, Bg);
    gemm_mfma<512, 256, 4, 4, 8>
        <<<dim3(16, 4, 8), 256, 0, stream>>>(Eg, Bg, part);
    reduce_pe_pack<256, 4, 4><<<1024, 256, 0, stream>>>(part, Eg, 8);

    // L2: CIN=256 COUT=128 8x8, SK=4
    prep_bpack<2304, 128><<<10368, 256, 0, stream>>>(bw2, sw2, ss2, Bg);
    gemm_mfma<256, 128, 8, 8, 4>
        <<<dim3(64, 2, 4), 256, 0, stream>>>(Eg, Bg, part);
    reduce_pe_pack<128, 8, 8><<<2048, 256, 0, stream>>>(part, Eg, 4);

    // L3: CIN=128 COUT=64 16x16, SK=2
    prep_bpack<1152, 64><<<2592, 256, 0, stream>>>(bw3, sw3, ss3, Bg);
    gemm_mfma<128, 64, 16, 16, 2>
        <<<dim3(256, 1, 2), 256, 0, stream>>>(Eg, Bg, part);
    reduce_p<64, 16, 16><<<4096, 256, 0, stream>>>(part, a3, 2);

    // L4: fused LDS expansion + pre-summed weights (round-10 proven)
    prep_wnl4<<<108, 256, 0, stream>>>(bw4, sw4, ss4, wl4);
    kan_l4_v7<<<1024, 256, 0, stream>>>(a3, wl4, p4);
    reduce_tanh_l4_16<<<768, 256, 0, stream>>>(p4, (float*)d_out);
  } else {
    // round-1 proven fallback (needs ~16.3 MB), original layout
    float* hF  = wsf;
    float* a1F = hF + 131072;
    float* a2F = a1F + 262144;
    float* a3F = a2F + 524288;
    float* partOld = a3F + 1048576;
    linear_pack_kernel<<<512, 256, 0, stream>>>(x, lin_w, lin_b, hF, nullptr, 0);
    kan_gemm<512, 256, 4, 4, 64, 8>
        <<<dim3(16, 4, 8), 256, 0, stream>>>(hF, bw1, sw1, ss1, partOld);
    reduce_partials_old<256, 4, 4, 8><<<1024, 256, 0, stream>>>(partOld, a1F);
    kan_gemm<256, 128, 8, 8, 64, 2>
        <<<dim3(64, 2, 2), 256, 0, stream>>>(a1F, bw2, sw2, ss2, partOld);
    reduce_partials_old<128, 8, 8, 2><<<2048, 256, 0, stream>>>(partOld, a2F);
    kan_gemm<128, 64, 16, 16, 64, 1>
        <<<dim3(256, 1, 1), 256, 0, stream>>>(a2F, bw3, sw3, ss3, a3F);
    kan_l4_split<<<1024, 256, 0, stream>>>(a3F, bw4, sw4, ss4, partOld);
    reduce_tanh_l4<<<768, 256, 0, stream>>>(partOld, (float*)d_out);
  }
}